// Round 3
// baseline (682.562 us; speedup 1.0000x reference)
//
#include <hip/hip_runtime.h>
#include <stdint.h>

// Problem constants (fixed by reference)
#define B_   16
#define S_   2048
#define DIN  512
#define DH   1024
#define DOUT 10

typedef unsigned short u16;
typedef unsigned int   u32;

typedef __bf16 bf16_t;
typedef bf16_t bf16x8 __attribute__((ext_vector_type(8)));
typedef float  f32x4  __attribute__((ext_vector_type(4)));

#define MASKVAL (-3.0e4f)
// Packed-P geometry: row-block mi holds r4 = ((mi>>2)+1)*4 tiles of 128 cols.
// Tile-offset of row-block mi: S4(mi) = 4*(g+1)*(mi-2g), g = mi>>2.
// Per-batch packed size = 160 tiles * 16384 u16 = 5 MiB.
#define PZ_U16 ((size_t)160 * 16384)

__device__ __forceinline__ float b2f(u16 u) {
    union { u32 i; float f; } v; v.i = ((u32)u) << 16; return v.f;
}
__device__ __forceinline__ u16 f2b(float f) {
    union { float f; u32 i; } v; v.f = f;
    u32 u = v.i;
    u32 r = (u + 0x7FFFu + ((u >> 16) & 1u)) >> 16;  // RNE
    return (u16)r;
}
__device__ __forceinline__ u32 pack2(float a, float b) {
    return (u32)f2b(a) | ((u32)f2b(b) << 16);
}

__device__ __forceinline__ f32x4 mfma16(bf16x8 a, bf16x8 b, f32x4 c) {
    return __builtin_amdgcn_mfma_f32_16x16x32_bf16(a, b, c, 0, 0, 0);
}

// async global->LDS, 16B per lane; LDS dest = wave-uniform base + lane*16
__device__ __forceinline__ void load_lds16(const u16* g, u16* l) {
    __builtin_amdgcn_global_load_lds(
        (__attribute__((address_space(1))) u32*)(g),
        (__attribute__((address_space(3))) u32*)(l), 16, 0, 0);
}

// load 8 contiguous elements at element-index eidx as packed bf16x8 (uint4)
template<bool F32>
__device__ __forceinline__ uint4 ld8(const void* base, size_t eidx) {
    if constexpr (F32) {
        const float* p = (const float*)base + eidx;
        float4 f0 = *(const float4*)p;
        float4 f1 = *(const float4*)(p + 4);
        uint4 r;
        r.x = pack2(f0.x, f0.y); r.y = pack2(f0.z, f0.w);
        r.z = pack2(f1.x, f1.y); r.w = pack2(f1.z, f1.w);
        return r;
    } else {
        return *(const uint4*)((const u16*)base + eidx);
    }
}

// ---------------------------------------------------------------------------
// f32 -> bf16 elementwise convert (8 elems/thread)
// ---------------------------------------------------------------------------
__global__ __launch_bounds__(256) void cvt_f32_bf16(
    const float* __restrict__ in, u16* __restrict__ out, int n8)
{
    int i = blockIdx.x * 256 + threadIdx.x;
    if (i >= n8) return;
    size_t e = (size_t)i * 8;
    float4 f0 = *(const float4*)(in + e);
    float4 f1 = *(const float4*)(in + e + 4);
    uint4 r;
    r.x = pack2(f0.x, f0.y); r.y = pack2(f0.z, f0.w);
    r.z = pack2(f1.x, f1.y); r.w = pack2(f1.z, f1.w);
    *(uint4*)(out + e) = r;
}

// ===========================================================================
// 8-phase 256x256 machinery (T2 swizzle + T3/T4 counted vmcnt + T5 setprio).
// LDS: AS/BS[2 dbuf][256 rows][64 cols] bf16. Load-unit = 64 rows x 64 cols.
// Swizzle: linear slot (row, c) holds data chunk c ^ (row&7) (16B chunks);
// write side pre-swizzles the global source chunk, read side XORs the chunk.
// ===========================================================================
template<int QR>
__device__ __forceinline__ void rda(bf16x8 (&a)[4][2], const u16* T,
                                    int arow, int quad) {
#pragma unroll
    for (int mf = 0; mf < 4; ++mf) {
        const int row = arow + QR * 64 + mf * 16;
        const int sw = row & 7;
#pragma unroll
        for (int ks = 0; ks < 2; ++ks)
            a[mf][ks] = *(const bf16x8*)(T + row * 64 + (((ks * 4 + quad) ^ sw) << 3));
    }
}

template<int QC>
__device__ __forceinline__ void rdb(bf16x8 (&b)[2][2], const u16* T,
                                    int brow, int quad) {
#pragma unroll
    for (int nf = 0; nf < 2; ++nf) {
        const int row = brow + QC * 128 + nf * 16;
        const int sw = row & 7;
#pragma unroll
        for (int ks = 0; ks < 2; ++ks)
            b[nf][ks] = *(const bf16x8*)(T + row * 64 + (((ks * 4 + quad) ^ sw) << 3));
    }
}

template<int QR, int QC>
__device__ __forceinline__ void mmq(f32x4 (&acc)[2][2][4][2],
                                    const bf16x8 (&a)[4][2],
                                    const bf16x8 (&b)[2][2]) {
#pragma unroll
    for (int ks = 0; ks < 2; ++ks)
#pragma unroll
        for (int mf = 0; mf < 4; ++mf)
#pragma unroll
            for (int nf = 0; nf < 2; ++nf)
                acc[QR][QC][mf][nf] = mfma16(a[mf][ks], b[nf][ks], acc[QR][QC][mf][nf]);
}

#define G8BAR()  __builtin_amdgcn_s_barrier()
#define G8LGKM() do { asm volatile("s_waitcnt lgkmcnt(0)" ::: "memory"); \
                      __builtin_amdgcn_sched_barrier(0); } while (0)
#define G8VMC4() asm volatile("s_waitcnt vmcnt(4)" ::: "memory")

// The 8-phase K-loop body, parameterized on staging macros STGA/STGB.
// Phases P1-P4 consume buf0 (quadrants (0,0),(0,1),(1,0),(1,1)), P5-P8 buf1.
// Stage stream (2 units/phase), each unit staged >=1 end-barrier after its
// last reader retired; vmcnt(4) ONLY at P4/P8 end.
#define G8_LOOP_BODY(NT_)                                                     \
    const int NI = (NT_) >> 1;                                                \
    for (int i = 0; i < NI; ++i) {                                            \
        const int t1 = 2 * i + 1, t2 = 2 * i + 2, t3 = 2 * i + 3;             \
        rda<0>(a, AS_[0], arow, quad); rdb<0>(b0r, BS_[0], brow, quad);       \
        STGB(1, 2, t1); STGB(1, 3, t1);                                       \
        G8BAR(); G8LGKM();                                                    \
        __builtin_amdgcn_s_setprio(1); mmq<0, 0>(acc, a, b0r);                \
        __builtin_amdgcn_s_setprio(0); G8BAR();                               \
        rdb<1>(b1r, BS_[0], brow, quad);                                      \
        STGA(1, 1, t1); STGA(1, 3, t1);                                       \
        G8BAR(); G8LGKM();                                                    \
        __builtin_amdgcn_s_setprio(1); mmq<0, 1>(acc, a, b1r);                \
        __builtin_amdgcn_s_setprio(0); G8BAR();                               \
        rda<1>(a, AS_[0], arow, quad);                                        \
        if (t2 < (NT_)) { STGA(0, 0, t2); STGA(0, 2, t2); }                   \
        G8BAR(); G8LGKM();                                                    \
        __builtin_amdgcn_s_setprio(1); mmq<1, 0>(acc, a, b0r);                \
        __builtin_amdgcn_s_setprio(0); G8BAR();                               \
        if (t2 < (NT_)) { STGB(0, 0, t2); STGB(0, 1, t2); }                   \
        G8BAR();                                                              \
        __builtin_amdgcn_s_setprio(1); mmq<1, 1>(acc, a, b1r);                \
        __builtin_amdgcn_s_setprio(0);                                        \
        G8VMC4(); G8BAR();                                                    \
        rda<0>(a, AS_[1], arow, quad); rdb<0>(b0r, BS_[1], brow, quad);       \
        if (t2 < (NT_)) { STGB(0, 2, t2); STGB(0, 3, t2); }                   \
        G8BAR(); G8LGKM();                                                    \
        __builtin_amdgcn_s_setprio(1); mmq<0, 0>(acc, a, b0r);                \
        __builtin_amdgcn_s_setprio(0); G8BAR();                               \
        rdb<1>(b1r, BS_[1], brow, quad);                                      \
        if (t2 < (NT_)) { STGA(0, 1, t2); STGA(0, 3, t2); }                   \
        G8BAR(); G8LGKM();                                                    \
        __builtin_amdgcn_s_setprio(1); mmq<0, 1>(acc, a, b1r);                \
        __builtin_amdgcn_s_setprio(0); G8BAR();                               \
        rda<1>(a, AS_[1], arow, quad);                                        \
        if (t3 < (NT_)) { STGA(1, 0, t3); STGA(1, 2, t3); }                   \
        G8BAR(); G8LGKM();                                                    \
        __builtin_amdgcn_s_setprio(1); mmq<1, 0>(acc, a, b0r);                \
        __builtin_amdgcn_s_setprio(0); G8BAR();                               \
        if (t3 < (NT_)) { STGB(1, 0, t3); STGB(1, 1, t3); }                   \
        G8BAR();                                                              \
        __builtin_amdgcn_s_setprio(1); mmq<1, 1>(acc, a, b1r);                \
        __builtin_amdgcn_s_setprio(0);                                        \
        G8VMC4(); G8BAR();                                                    \
    }

// ===========================================================================
// gemm8: C[M,N] = relu(A[M,K] @ Bt[N,K]^T + bias[N]), bf16.
// grid = (M/256, N/256), block = 512. Requires K % 128 == 0.
// ===========================================================================
__global__ __launch_bounds__(512, 2) void gemm8(
    const u16* __restrict__ A, const u16* __restrict__ Bt,
    const float* __restrict__ bias, u16* __restrict__ C,
    int N, int K, int do_relu)
{
    __shared__ __attribute__((aligned(16))) u16 AS_[2][16384];
    __shared__ __attribute__((aligned(16))) u16 BS_[2][16384];

    const int tid  = threadIdx.x;
    const int lane = tid & 63;
    const int w    = tid >> 6;
    const int wm   = w >> 2, wn = w & 3;
    const int quad = lane >> 4, l15 = lane & 15;
    const int m0 = blockIdx.x * 256, n0 = blockIdx.y * 256;

    // staging bases: row-in-unit = tid>>3, pre-swizzled 16B chunk
    const int rg = tid >> 3;
    const int ch = (lane & 7) ^ ((lane >> 3) & 7);
    const u16* gA = A  + (size_t)(m0 + rg) * K + ch * 8;
    const u16* gB = Bt + (size_t)(n0 + rg) * K + ch * 8;
    const int wslot = w * 512;  // u16 offset of wave's 8-row slice in a unit

#define STGA(BUF, U, T) load_lds16(gA + (size_t)(U) * 64 * K + (T) * 64, \
                                   &AS_[BUF][(U) * 4096 + wslot])
#define STGB(BUF, U, T) load_lds16(gB + (size_t)(U) * 64 * K + (T) * 64, \
                                   &BS_[BUF][(U) * 4096 + wslot])

    f32x4 acc[2][2][4][2];
#pragma unroll
    for (int p = 0; p < 2; ++p)
#pragma unroll
    for (int q = 0; q < 2; ++q)
#pragma unroll
    for (int m = 0; m < 4; ++m)
#pragma unroll
    for (int n = 0; n < 2; ++n) acc[p][q][m][n] = (f32x4){0.f, 0.f, 0.f, 0.f};

    bf16x8 a[4][2], b0r[2][2], b1r[2][2];

    const int NT = K >> 6;       // 64-wide K tiles (even: K % 128 == 0)

    // prologue: full tile0 -> buf0; tile1 A0,A2,B0,B1 -> buf1 (as-if P7,P8)
    STGA(0, 0, 0); STGA(0, 1, 0); STGA(0, 2, 0); STGA(0, 3, 0);
    STGB(0, 0, 0); STGB(0, 1, 0); STGB(0, 2, 0); STGB(0, 3, 0);
    STGA(1, 0, 1); STGA(1, 2, 1);
    STGB(1, 0, 1); STGB(1, 1, 1);
    G8VMC4(); G8BAR();

    const int arow = wm * 128 + l15;
    const int brow = wn * 32 + l15;
    G8_LOOP_BODY(NT)
#undef STGA
#undef STGB

    // epilogue: bias + relu + bf16 store
    const int r0 = quad * 4;
#pragma unroll
    for (int qc = 0; qc < 2; ++qc)
#pragma unroll
    for (int nf = 0; nf < 2; ++nf) {
        const int col = n0 + qc * 128 + wn * 32 + nf * 16 + l15;
        const float bv = bias[col];
#pragma unroll
        for (int qr = 0; qr < 2; ++qr)
#pragma unroll
        for (int mf = 0; mf < 4; ++mf) {
            const int rowb = m0 + wm * 128 + qr * 64 + mf * 16 + r0;
#pragma unroll
            for (int r = 0; r < 4; ++r) {
                float v = acc[qr][qc][mf][nf][r] + bv;
                if (do_relu) v = fmaxf(v, 0.f);
                C[(size_t)(rowb + r) * N + col] = f2b(v);
            }
        }
    }
}

// ===========================================================================
// score8: causal score GEMM on the 8-phase 256x256 template, writing packed P.
// grid.x = nb*38: z = idx/38, t = idx%38.
//   t < 36 : triangular (bi,bj), bj <= bi -> 256x256 score tile.
//   t >= 36: tiny pad block (p = t-36): MASKVAL-fills 8 of the 16 packed-P
//            pad tiles/batch not covered by diagonal score blocks:
//            (mi, ni) = (4g+{0,1}, 4g+{2,3}), g = 0..3. Rides the idle CUs
//            of the partial round (grid <= 256 requires nb <= 6).
// A = B = h[z] (2048 x 1024). K = DH (NT=16, same control flow as gemm8).
// Epilogue scatters the four 128x128 quadrants into packed-P; diagonal
// blocks (bi==bj) apply the causal mask (and thereby emit the (2bi,2bi+1)
// pad tile as all-MASKVAL).
// ===========================================================================
__global__ __launch_bounds__(512, 2) void score8(
    const u16* __restrict__ h, u16* __restrict__ P)
{
    __shared__ __attribute__((aligned(16))) u16 AS_[2][16384];
    __shared__ __attribute__((aligned(16))) u16 BS_[2][16384];

    const int z = blockIdx.x / 38;
    const int t = blockIdx.x % 38;

    if (t >= 36) {                               // merged pad-fill blocks
        const int p = t - 36;
        const u16 mb = f2b(MASKVAL);
        const u32 m2 = (u32)mb | ((u32)mb << 16);
        uint4 mv; mv.x = m2; mv.y = m2; mv.z = m2; mv.w = m2;
        u16* Pz0 = P + (size_t)z * PZ_U16;
#pragma unroll
        for (int i = 0; i < 8; ++i) {
            const int idx = p * 8 + i;
            const int g  = idx >> 2;
            const int mi = 4 * g + ((idx >> 1) & 1);
            const int ni = 4 * g + 2 + (idx & 1);
            u16* Pz = Pz0 + (size_t)(4 * (g + 1) * (mi - 2 * g)) * 16384;
            const size_t rstride = (size_t)(4 * (g + 1)) * 128;
            for (int q = threadIdx.x; q < 2048; q += 512) {
                int row = q >> 4, cl = (q & 15) * 8;
                *(uint4*)&Pz[(size_t)row * rstride + ni * 128 + cl] = mv;
            }
        }
        return;
    }

    int bi = 0;
    while ((bi + 1) * (bi + 2) / 2 <= t) ++bi;
    const int bj = t - bi * (bi + 1) / 2;
    const bool diag = (bi == bj);

    const int tid  = threadIdx.x;
    const int lane = tid & 63;
    const int w    = tid >> 6;
    const int wm   = w >> 2, wn = w & 3;
    const int quad = lane >> 4, l15 = lane & 15;
    const int m0 = bi * 256, n0 = bj * 256;

    const u16* hz = h + (size_t)z * S_ * DH;
    const int rg = tid >> 3;
    const int ch = (lane & 7) ^ ((lane >> 3) & 7);
    const u16* gA = hz + (size_t)(m0 + rg) * DH + ch * 8;
    const u16* gB = hz + (size_t)(n0 + rg) * DH + ch * 8;
    const int wslot = w * 512;

#define STGA(BUF, U, T) load_lds16(gA + (size_t)(U) * 64 * DH + (T) * 64, \
                                   &AS_[BUF][(U) * 4096 + wslot])
#define STGB(BUF, U, T) load_lds16(gB + (size_t)(U) * 64 * DH + (T) * 64, \
                                   &BS_[BUF][(U) * 4096 + wslot])

    f32x4 acc[2][2][4][2];
#pragma unroll
    for (int p = 0; p < 2; ++p)
#pragma unroll
    for (int q = 0; q < 2; ++q)
#pragma unroll
    for (int m = 0; m < 4; ++m)
#pragma unroll
    for (int n = 0; n < 2; ++n) acc[p][q][m][n] = (f32x4){0.f, 0.f, 0.f, 0.f};

    bf16x8 a[4][2], b0r[2][2], b1r[2][2];

    const int NT = DH >> 6;      // 16

    STGA(0, 0, 0); STGA(0, 1, 0); STGA(0, 2, 0); STGA(0, 3, 0);
    STGB(0, 0, 0); STGB(0, 1, 0); STGB(0, 2, 0); STGB(0, 3, 0);
    STGA(1, 0, 1); STGA(1, 2, 1);
    STGB(1, 0, 1); STGB(1, 1, 1);
    G8VMC4(); G8BAR();

    const int arow = wm * 128 + l15;
    const int brow = wn * 32 + l15;
    G8_LOOP_BODY(NT)
#undef STGA
#undef STGB

    // epilogue: scatter into packed P with causal mask on diagonal blocks.
    // This wave's rows all live in 128-half wm -> mi = 2*bi + wm (g shared
    // between the two halves since 2bi and 2bi+1 differ only in bit 0).
    const int mi = 2 * bi + wm;
    const int g  = mi >> 2;
    u16* Pz = P + (size_t)z * PZ_U16
                + (size_t)(4 * (g + 1) * (mi - 2 * g)) * 16384;
    const size_t rstride = (size_t)(4 * (g + 1)) * 128;

    const int r0 = quad * 4;
#pragma unroll
    for (int qc = 0; qc < 2; ++qc) {
        const int ni = 2 * bj + qc;
#pragma unroll
        for (int nf = 0; nf < 2; ++nf) {
            const int cl = wn * 32 + nf * 16 + l15;
            const int colg = n0 + qc * 128 + cl;
#pragma unroll
            for (int qr = 0; qr < 2; ++qr)
#pragma unroll
            for (int mf = 0; mf < 4; ++mf) {
                const int rl = qr * 64 + mf * 16 + r0;
                const int rowg = m0 + wm * 128 + rl;
#pragma unroll
                for (int r = 0; r < 4; ++r) {
                    float v = acc[qr][qc][mf][nf][r];
                    if (diag && colg > rowg + r) v = MASKVAL;
                    Pz[(size_t)(rl + r) * rstride + ni * 128 + cl] = f2b(v);
                }
            }
        }
    }
}

// ---------------------------------------------------------------------------
// ASYNC score GEMM into PACKED P (tier-C fallback): row-block mi = causal
// tiles ni<=mi, padded to r4 tiles; pad tiles get MASKVAL. grid (16, 16, nb).
// ---------------------------------------------------------------------------
__global__ __launch_bounds__(256) void score_a(
    const u16* __restrict__ h, u16* __restrict__ P)
{
    __shared__ __attribute__((aligned(16))) u16 As[128 * 32];
    __shared__ __attribute__((aligned(16))) u16 Bs[128 * 32];

    const int mi = 15 - blockIdx.x;              // LPT: heavy rows first
    const int ni = blockIdx.y;
    const int g  = mi >> 2;
    const int r4 = (g + 1) * 4;
    if (ni >= r4) return;

    const int tid = threadIdx.x;
    u16* Pz = P + (size_t)blockIdx.z * PZ_U16
                + (size_t)(4 * (g + 1) * (mi - 2 * g)) * 16384;
    const size_t rstride = (size_t)r4 * 128;

    if (ni > mi) {                               // pad tile: MASKVAL fill
        const u16 mb = f2b(MASKVAL);
        const u32 m2 = (u32)mb | ((u32)mb << 16);
        uint4 mv; mv.x = m2; mv.y = m2; mv.z = m2; mv.w = m2;
#pragma unroll
        for (int i = 0; i < 8; ++i) {
            int q = tid + i * 256;
            int row = q >> 4, cl = (q & 15) * 8;
            *(uint4*)&Pz[(size_t)row * rstride + ni * 128 + cl] = mv;
        }
        return;
    }

    const int m0 = mi * 128, n0 = ni * 128;
    const u16* A = h + (size_t)blockIdx.z * S_ * DH;

    const int lane = tid & 63;
    const int w    = tid >> 6;
    const int wm   = w >> 1, wn = w & 1;
    const int quad = lane >> 4, l15 = lane & 15;

    const int c0 = tid, c1 = tid + 256;
    const u16* gA0 = A + ((size_t)(m0 + (c0 >> 2)) * DH + (c0 & 3) * 8);
    const u16* gA1 = A + ((size_t)(m0 + (c1 >> 2)) * DH + (c1 & 3) * 8);
    const u16* gB0 = A + ((size_t)(n0 + (c0 >> 2)) * DH + (c0 & 3) * 8);
    const u16* gB1 = A + ((size_t)(n0 + (c1 >> 2)) * DH + (c1 & 3) * 8);
    u16* lA0 = &As[(w * 64) * 8];
    u16* lA1 = &As[(256 + w * 64) * 8];
    u16* lB0 = &Bs[(w * 64) * 8];
    u16* lB1 = &Bs[(256 + w * 64) * 8];

    f32x4 acc[4][4];
#pragma unroll
    for (int i = 0; i < 4; ++i)
#pragma unroll
        for (int j = 0; j < 4; ++j) acc[i][j] = (f32x4){0.f, 0.f, 0.f, 0.f};

    const int nk = DH >> 5;
    for (int kk = 0; kk < nk; ++kk) {
        load_lds16(gA0, lA0); load_lds16(gA1, lA1);
        load_lds16(gB0, lB0); load_lds16(gB1, lB1);
        gA0 += 32; gA1 += 32; gB0 += 32; gB1 += 32;
        __syncthreads();
        bf16x8 af[4], bfr[4];
#pragma unroll
        for (int i = 0; i < 4; ++i)
            af[i] = *(const bf16x8*)&As[(wm * 64 + i * 16 + l15) * 32 + quad * 8];
#pragma unroll
        for (int j = 0; j < 4; ++j)
            bfr[j] = *(const bf16x8*)&Bs[(wn * 64 + j * 16 + l15) * 32 + quad * 8];
#pragma unroll
        for (int i = 0; i < 4; ++i)
#pragma unroll
            for (int j = 0; j < 4; ++j)
                acc[i][j] = mfma16(af[i], bfr[j], acc[i][j]);
        __syncthreads();
    }

    const int r0 = quad * 4;
#pragma unroll
    for (int j = 0; j < 4; ++j) {
        int cl = wn * 64 + j * 16 + l15;
#pragma unroll
        for (int i = 0; i < 4; ++i) {
            int rl = wm * 64 + i * 16 + r0;
#pragma unroll
            for (int r = 0; r < 4; ++r) {
                int row = rl + r;
                float v = (n0 + cl <= m0 + row) ? acc[i][j][r] : MASKVAL;
                Pz[(size_t)row * rstride + ni * 128 + cl] = f2b(v);
            }
        }
    }
}

// ---------------------------------------------------------------------------
// softmax_rows: in-place row softmax of packed P. One wave per row.
// Row length = kb*512 cols (kb = (mi>>2)+1), includes MASKVAL padding.
// ---------------------------------------------------------------------------
__global__ __launch_bounds__(256) void softmax_rows(u16* __restrict__ P)
{
    const int tid = threadIdx.x;
    const int lane = tid & 63, w = tid >> 6;
    const size_t row = (size_t)blockIdx.x * 4 + w;
    const int z    = (int)(row >> 11);
    const int rloc = (int)(row & (S_ - 1));
    const int mi = rloc >> 7, g = mi >> 2;
    const int kb = g + 1;
    u16* p = P + (size_t)z * PZ_U16
               + (size_t)(4 * (g + 1) * (mi - 2 * g)) * 16384
               + (size_t)(rloc & 127) * ((g + 1) * 4 * 128);
    float v[32];
    float m = -1e30f;
    for (int k = 0; k < kb; ++k) {
        uint4 u = *(const uint4*)&p[k * 512 + lane * 8];
        const u32* uu = (const u32*)&u;
#pragma unroll
        for (int i = 0; i < 4; ++i) {
            float a = b2f((u16)(uu[i] & 0xFFFFu));
            float b = b2f((u16)(uu[i] >> 16));
            v[k * 8 + 2 * i] = a; v[k * 8 + 2 * i + 1] = b;
            m = fmaxf(m, fmaxf(a, b));
        }
    }
#pragma unroll
    for (int off = 32; off >= 1; off >>= 1) m = fmaxf(m, __shfl_xor(m, off, 64));
    float s = 0.f;
    for (int k = 0; k < kb; ++k)
#pragma unroll
        for (int i = 0; i < 8; ++i) {
            float e = __expf(v[k * 8 + i] - m);
            v[k * 8 + i] = e; s += e;
        }
#pragma unroll
    for (int off = 32; off >= 1; off >>= 1) s += __shfl_xor(s, off, 64);
    float inv = 1.0f / s;
    for (int k = 0; k < kb; ++k) {
        uint4 u; u32* uu = (u32*)&u;
#pragma unroll
        for (int i = 0; i < 4; ++i)
            uu[i] = pack2(v[k * 8 + 2 * i] * inv, v[k * 8 + 2 * i + 1] * inv);
        *(uint4*)&p[k * 512 + lane * 8] = u;
    }
}

// ---------------------------------------------------------------------------
// ASYNC pv GEMM, LPT 1D grid: ctx[z] = P[z] @ V[z]; A = packed P, Bt = hT.
// grid.x = 16*8*nb; idx -> mi = 15 - idx/(8*nb) (heavy blocks dispatch FIRST),
// sub = idx%(8*nb): n = sub&7, z = sub>>3. nk = (mi+1)*4.
// ---------------------------------------------------------------------------
__global__ __launch_bounds__(256) void pv_a(
    const u16* __restrict__ P, const u16* __restrict__ hT, u16* __restrict__ ctx,
    int nb)
{
    __shared__ __attribute__((aligned(16))) u16 As[128 * 32];
    __shared__ __attribute__((aligned(16))) u16 Bs[128 * 32];

    const int idx = blockIdx.x;
    const int per_mi = 8 * nb;
    const int mi = 15 - (idx / per_mi);          // LPT: heavy row-blocks first
    const int sub = idx % per_mi;
    const int nblk = sub & 7;
    const int z    = sub >> 3;
    const int g = mi >> 2;
    const int m0 = mi * 128;
    const int n0 = nblk * 128;
    const size_t rstride = (size_t)((g + 1) * 4) * 128;
    const u16* A  = P  + (size_t)z * PZ_U16
                       + (size_t)(4 * (g + 1) * (mi - 2 * g)) * 16384;
    const u16* Bt = hT + (size_t)z * DH * S_;
    u16*      C   = ctx + (size_t)z * S_ * DH;

    const int tid  = threadIdx.x;
    const int lane = tid & 63;
    const int w    = tid >> 6;
    const int wm   = w >> 1, wn = w & 1;
    const int quad = lane >> 4, l15 = lane & 15;

    const int c0 = tid, c1 = tid + 256;
    const u16* gA0 = A  + ((size_t)(c0 >> 2) * rstride + (c0 & 3) * 8);
    const u16* gA1 = A  + ((size_t)(c1 >> 2) * rstride + (c1 & 3) * 8);
    const u16* gB0 = Bt + ((size_t)(n0 + (c0 >> 2)) * S_ + (c0 & 3) * 8);
    const u16* gB1 = Bt + ((size_t)(n0 + (c1 >> 2)) * S_ + (c1 & 3) * 8);
    u16* lA0 = &As[(w * 64) * 8];
    u16* lA1 = &As[(256 + w * 64) * 8];
    u16* lB0 = &Bs[(w * 64) * 8];
    u16* lB1 = &Bs[(256 + w * 64) * 8];

    f32x4 acc[4][4];
#pragma unroll
    for (int i = 0; i < 4; ++i)
#pragma unroll
        for (int j = 0; j < 4; ++j) acc[i][j] = (f32x4){0.f, 0.f, 0.f, 0.f};

    const int nk = (mi + 1) * 4;
    for (int kk = 0; kk < nk; ++kk) {
        load_lds16(gA0, lA0); load_lds16(gA1, lA1);
        load_lds16(gB0, lB0); load_lds16(gB1, lB1);
        gA0 += 32; gA1 += 32; gB0 += 32; gB1 += 32;
        __syncthreads();
        bf16x8 af[4], bfr[4];
#pragma unroll
        for (int i = 0; i < 4; ++i)
            af[i] = *(const bf16x8*)&As[(wm * 64 + i * 16 + l15) * 32 + quad * 8];
#pragma unroll
        for (int j = 0; j < 4; ++j)
            bfr[j] = *(const bf16x8*)&Bs[(wn * 64 + j * 16 + l15) * 32 + quad * 8];
#pragma unroll
        for (int i = 0; i < 4; ++i)
#pragma unroll
            for (int j = 0; j < 4; ++j)
                acc[i][j] = mfma16(af[i], bfr[j], acc[i][j]);
        __syncthreads();
    }

    const int r0 = quad * 4;
#pragma unroll
    for (int j = 0; j < 4; ++j) {
        int col = n0 + wn * 64 + j * 16 + l15;
#pragma unroll
        for (int i = 0; i < 4; ++i) {
            int rowb = m0 + wm * 64 + i * 16 + r0;
#pragma unroll
            for (int r = 0; r < 4; ++r)
                C[(size_t)(rowb + r) * DH + col] = f2b(acc[i][j][r]);
        }
    }
}

// ---------------------------------------------------------------------------
// SYNC-staged GEMM (tier-C fallback only; A may be f32)
// ---------------------------------------------------------------------------
template<bool AF32>
__global__ __launch_bounds__(256) void gemm_bt_bias_relu(
    const void* __restrict__ A, const u16* __restrict__ Bt,
    const float* __restrict__ bias, u16* __restrict__ C,
    int M, int N, int K, int do_relu)
{
    __shared__ __attribute__((aligned(16))) u16 As[128 * 32];
    __shared__ __attribute__((aligned(16))) u16 Bs[128 * 32];

    const int tid  = threadIdx.x;
    const int lane = tid & 63;
    const int w    = tid >> 6;
    const int wm   = w >> 1, wn = w & 1;
    const int quad = lane >> 4, l15 = lane & 15;

    const int m0 = blockIdx.x * 128;
    const int n0 = blockIdx.y * 128;

    const int c0 = tid, c1 = tid + 256;
    size_t eA0 = (size_t)(m0 + (c0 >> 2)) * K + (c0 & 3) * 8;
    size_t eA1 = (size_t)(m0 + (c1 >> 2)) * K + (c1 & 3) * 8;
    size_t eB0 = (size_t)(n0 + (c0 >> 2)) * K + (c0 & 3) * 8;
    size_t eB1 = (size_t)(n0 + (c1 >> 2)) * K + (c1 & 3) * 8;

    f32x4 acc[4][4];
#pragma unroll
    for (int i = 0; i < 4; ++i)
#pragma unroll
        for (int j = 0; j < 4; ++j) acc[i][j] = (f32x4){0.f, 0.f, 0.f, 0.f};

    uint4 va0 = ld8<AF32>(A, eA0), va1 = ld8<AF32>(A, eA1);
    uint4 vb0 = ld8<false>(Bt, eB0), vb1 = ld8<false>(Bt, eB1);

    const int nk = K >> 5;
    for (int kk = 0; kk < nk; ++kk) {
        __syncthreads();
        *(uint4*)&As[c0 * 8] = va0;
        *(uint4*)&As[c1 * 8] = va1;
        *(uint4*)&Bs[c0 * 8] = vb0;
        *(uint4*)&Bs[c1 * 8] = vb1;
        if (kk + 1 < nk) {
            eA0 += 32; eA1 += 32; eB0 += 32; eB1 += 32;
            va0 = ld8<AF32>(A, eA0); va1 = ld8<AF32>(A, eA1);
            vb0 = ld8<false>(Bt, eB0); vb1 = ld8<false>(Bt, eB1);
        }
        __syncthreads();
        bf16x8 af[4], bfr[4];
#pragma unroll
        for (int i = 0; i < 4; ++i)
            af[i] = *(const bf16x8*)&As[(wm * 64 + i * 16 + l15) * 32 + quad * 8];
#pragma unroll
        for (int j = 0; j < 4; ++j)
            bfr[j] = *(const bf16x8*)&Bs[(wn * 64 + j * 16 + l15) * 32 + quad * 8];
#pragma unroll
        for (int i = 0; i < 4; ++i)
#pragma unroll
            for (int j = 0; j < 4; ++j)
                acc[i][j] = mfma16(af[i], bfr[j], acc[i][j]);
    }

    const int r0 = quad * 4;
#pragma unroll
    for (int j = 0; j < 4; ++j) {
        int col = n0 + wn * 64 + j * 16 + l15;
        float bv = bias[col];
#pragma unroll
        for (int i = 0; i < 4; ++i) {
            int rowb = m0 + wm * 64 + i * 16 + r0;
#pragma unroll
            for (int r = 0; r < 4; ++r) {
                float v = acc[i][j][r] + bv;
                if (do_relu) v = fmaxf(v, 0.f);
                C[(size_t)(rowb + r) * N + col] = f2b(v);
            }
        }
    }
}

// ---------------------------------------------------------------------------
// transpose + f32->bf16 convert: in f32 [R][C] -> out bf16 [C][R]. block (32,8)
// ---------------------------------------------------------------------------
__global__ __launch_bounds__(256) void transpose_cvt(
    const float* __restrict__ in, u16* __restrict__ out, int R, int C)
{
    __shared__ u16 t[32][33];
    int c0 = blockIdx.x * 32, r0 = blockIdx.y * 32;
    int tx = threadIdx.x, ty = threadIdx.y;
#pragma unroll
    for (int i = 0; i < 4; ++i)
        t[ty + i * 8][tx] = f2b(in[(size_t)(r0 + ty + i * 8) * C + c0 + tx]);
    __syncthreads();
#pragma unroll
    for (int i = 0; i < 4; ++i)
        out[(size_t)(c0 + ty + i * 8) * R + r0 + tx] = t[tx][ty + i * 8];
}

// batched bf16 transpose: in [z][R][C] -> out [z][C][R]. block (32,8)
__global__ __launch_bounds__(256) void transpose_b(
    const u16* __restrict__ in, u16* __restrict__ out, int R, int C)
{
    __shared__ u16 t[32][33];
    const u16* ip = in  + (size_t)blockIdx.z * R * C;
    u16*       op = out + (size_t)blockIdx.z * R * C;
    int c0 = blockIdx.x * 32, r0 = blockIdx.y * 32;
    int tx = threadIdx.x, ty = threadIdx.y;
#pragma unroll
    for (int i = 0; i < 4; ++i)
        t[ty + i * 8][tx] = ip[(size_t)(r0 + ty + i * 8) * C + c0 + tx];
    __syncthreads();
#pragma unroll
    for (int i = 0; i < 4; ++i)
        op[(size_t)(c0 + ty + i * 8) * R + r0 + tx] = t[tx][ty + i * 8];
}

// ---------------------------------------------------------------------------
// head: out[row,:] = log_softmax(o[row,:] @ W4 + b4). One wave per row.
// ---------------------------------------------------------------------------
__global__ __launch_bounds__(256) void head_logsoftmax(
    const u16* __restrict__ o, const float* __restrict__ W4,
    const float* __restrict__ b4, float* __restrict__ out)
{
    __shared__ float W4s[DIN * DOUT];
    __shared__ float b4s[DOUT];
    const int tid = threadIdx.x;
    for (int i = tid; i < DIN * DOUT; i += 256) W4s[i] = W4[i];
    if (tid < DOUT) b4s[tid] = b4[tid];
    __syncthreads();
    const int lane = tid & 63, w = tid >> 6;
    const size_t row = (size_t)blockIdx.x * 4 + w;
    const uint4 ov = *(const uint4*)&o[row * DIN + lane * 8];
    const u32* ou = (const u32*)&ov;
    float oc[8];
#pragma unroll
    for (int i = 0; i < 4; ++i) {
        oc[2*i]   = b2f((u16)(ou[i] & 0xFFFFu));
        oc[2*i+1] = b2f((u16)(ou[i] >> 16));
    }
    float acc[DOUT];
#pragma unroll
    for (int c = 0; c < DOUT; ++c) acc[c] = 0.f;
#pragma unroll
    for (int i = 0; i < 8; ++i) {
        int k = lane * 8 + i;
        float x = oc[i];
#pragma unroll
        for (int c = 0; c < DOUT; ++c) acc[c] += x * W4s[k * DOUT + c];
    }
#pragma unroll
    for (int off = 32; off >= 1; off >>= 1)
#pragma unroll
        for (int c = 0; c < DOUT; ++c) acc[c] += __shfl_xor(acc[c], off, 64);
    float mx = -1e30f;
#pragma unroll
    for (int c = 0; c < DOUT; ++c) { acc[c] += b4s[c]; mx = fmaxf(mx, acc[c]); }
    float sum = 0.f;
#pragma unroll
    for (int c = 0; c < DOUT; ++c) sum += __expf(acc[c] - mx);
    float lse = mx + logf(sum);
    if (lane == 0) {
#pragma unroll
        for (int c = 0; c < DOUT; ++c) out[row * DOUT + c] = acc[c] - lse;
    }
}

// ---------------------------------------------------------------------------
extern "C" void kernel_launch(void* const* d_in, const int* in_sizes, int n_in,
                              void* d_out, int out_size, void* d_ws, size_t ws_size,
                              hipStream_t stream) {
    const float* x  = (const float*)d_in[0];
    const float* gv = (const float*)d_in[1];
    const float* uv = (const float*)d_in[2];
    const float* W1 = (const float*)d_in[3];
    const float* b1 = (const float*)d_in[4];
    const float* W2 = (const float*)d_in[5];
    const float* b2 = (const float*)d_in[6];
    const float* W3 = (const float*)d_in[7];
    const float* b3 = (const float*)d_in[8];
    const float* W4 = (const float*)d_in[9];
    const float* b4 = (const float*)d_in[10];
    float* out = (float*)d_out;

    char* ws = (char*)d_ws;
    const size_t MB64 = (size_t)67108864;
    const size_t MiB  = (size_t)1048576;
    const size_t TIER_A2 = 2 * MB64 + 72 * MiB + 8 * MiB;   // 208 MiB gate
    const size_t TIER_B  = 3 * MB64 + 5 * MiB;              // 197 MiB

    if (ws_size >= TIER_A2) {
        u16* h1   = (u16*)(ws);
        u16* ctx  = h1;
        u16* h    = (u16*)(ws + MB64);
        u16* o    = h;
        u16* xb   = (u16*)(ws + 2 * MB64);
        u16* hT_c = xb;
        u16* P_c  = (u16*)(ws + 2 * MB64 + 32 * MiB);
        u16* W1t  = (u16*)(ws + 2 * MB64 + 72 * MiB);
        u16* W2t  = W1t + 512 * 1024;
        u16* W3t  = W2t + 1024 * 1024;

        cvt_f32_bf16<<<8192, 256, 0, stream>>>(x, xb, 2097152);
        transpose_cvt<<<dim3(32, 16), dim3(32, 8), 0, stream>>>(W1, W1t, 512, 1024);
        transpose_cvt<<<dim3(32, 32), dim3(32, 8), 0, stream>>>(W2, W2t, 1024, 1024);
        transpose_cvt<<<dim3(16, 32), dim3(32, 8), 0, stream>>>(W3, W3t, 1024, 512);

        gemm8<<<dim3(128, 4), 512, 0, stream>>>(xb, W1t, b1, h1, 1024, 512, 1);
        gemm8<<<dim3(128, 4), 512, 0, stream>>>(h1, W2t, b2, h,  1024, 1024, 1);

        // 3 chunks of {6,5,5} batches: score8 grids {228,190,190} <= 256
        // blocks -> exactly one scheduling round each (3T total vs 4T for
        // 2x288). Pad tiles ride as 2 tiny blocks/z inside score8.
        const int obs[4] = {0, 6, 11, 16};
        for (int c = 0; c < 3; ++c) {
            const int ob = obs[c], nb = obs[c + 1] - obs[c];
            const u16* hc  = h   + (size_t)ob * S_ * DH;
            u16*       cxc = ctx + (size_t)ob * S_ * DH;
            transpose_b<<<dim3(32, 64, nb), dim3(32, 8), 0, stream>>>(hc, hT_c, 2048, 1024);
            score8<<<38 * nb, 512, 0, stream>>>(hc, P_c);
            softmax_rows<<<nb * 512, 256, 0, stream>>>(P_c);
            pv_a<<<16 * 8 * nb, 256, 0, stream>>>(P_c, hT_c, cxc, nb);
        }

        gemm8<<<dim3(128, 2), 512, 0, stream>>>(ctx, W3t, b3, o, 512, 1024, 1);
        head_logsoftmax<<<8192, 256, 0, stream>>>(o, W4, b4, out);
    } else if (ws_size >= TIER_B) {
        u16* h1   = (u16*)(ws);
        u16* ctx  = h1;
        u16* h    = (u16*)(ws + MB64);
        u16* xb   = (u16*)(ws + 2 * MB64);
        u16* hT_c = xb;
        u16* P_c  = (u16*)(ws + 2 * MB64 + 16 * MiB);
        u16* o    = (u16*)(ws + 2 * MB64);
        u16* W1t  = (u16*)(ws + 3 * MB64);
        u16* W2t  = W1t + 512 * 1024;
        u16* W3t  = W2t + 1024 * 1024;

        cvt_f32_bf16<<<8192, 256, 0, stream>>>(x, xb, 2097152);
        transpose_cvt<<<dim3(32, 16), dim3(32, 8), 0, stream>>>(W1, W1t, 512, 1024);
        transpose_cvt<<<dim3(32, 32), dim3(32, 8), 0, stream>>>(W2, W2t, 1024, 1024);
        transpose_cvt<<<dim3(16, 32), dim3(32, 8), 0, stream>>>(W3, W3t, 1024, 512);

        gemm8<<<dim3(128, 4), 512, 0, stream>>>(xb, W1t, b1, h1, 1024, 512, 1);
        gemm8<<<dim3(128, 4), 512, 0, stream>>>(h1, W2t, b2, h,  1024, 1024, 1);

        for (int c = 0; c < 4; ++c) {
            const u16* hc  = h   + (size_t)c * 4 * S_ * DH;
            u16*       cxc = ctx + (size_t)c * 4 * S_ * DH;
            transpose_b<<<dim3(32, 64, 4), dim3(32, 8), 0, stream>>>(hc, hT_c, 2048, 1024);
            score8<<<38 * 4, 512, 0, stream>>>(hc, P_c);
            softmax_rows<<<2048, 256, 0, stream>>>(P_c);
            pv_a<<<16 * 8 * 4, 256, 0, stream>>>(P_c, hT_c, cxc, 4);
        }

        gemm8<<<dim3(128, 2), 512, 0, stream>>>(ctx, W3t, b3, o, 512, 1024, 1);
        head_logsoftmax<<<8192, 256, 0, stream>>>(o, W4, b4, out);
    } else {
        u16* h    = (u16*)(ws);
        u16* hT_b = (u16*)(ws + MB64);
        u16* P_b  = (u16*)(ws + MB64 + 4 * MiB);
        u16* ctx_b= (u16*)(ws + MB64 + 12 * MiB);
        u16* o_b  = (u16*)(ws + MB64 + 16 * MiB);
        u16* W1t  = (u16*)(ws + MB64 + 18 * MiB);
        u16* W2t  = W1t + 512 * 1024;
        u16* W3t  = W2t + 1024 * 1024;
        u16* h1_b = P_b;

        transpose_cvt<<<dim3(32, 16), dim3(32, 8), 0, stream>>>(W1, W1t, 512, 1024);
        transpose_cvt<<<dim3(32, 32), dim3(32, 8), 0, stream>>>(W2, W2t, 1024, 1024);
        transpose_cvt<<<dim3(16, 32), dim3(32, 8), 0, stream>>>(W3, W3t, 1024, 512);

        for (int c = 0; c < 8; ++c) {
            const float* xc = x + (size_t)c * 4096 * DIN;
            u16*         hc = h + (size_t)c * 4096 * DH;
            gemm_bt_bias_relu<true ><<<dim3(32, 8), 256, 0, stream>>>(xc, W1t, b1, h1_b,
                                                                      4096, 1024, 512, 1);
            gemm_bt_bias_relu<false><<<dim3(32, 8), 256, 0, stream>>>(h1_b, W2t, b2, hc,
                                                                      4096, 1024, 1024, 1);
        }
        for (int b = 0; b < B_; ++b) {
            const u16* hb = h + (size_t)b * S_ * DH;
            transpose_b<<<dim3(32, 64, 1), dim3(32, 8), 0, stream>>>(hb, hT_b, 2048, 1024);
            score_a<<<dim3(16, 16, 1), 256, 0, stream>>>(hb, P_b);
            softmax_rows<<<512, 256, 0, stream>>>(P_b);
            pv_a<<<16 * 8, 256, 0, stream>>>(P_b, hT_b, ctx_b, 1);
            gemm_bt_bias_relu<false><<<dim3(16, 4), 256, 0, stream>>>(ctx_b, W3t, b3, o_b,
                                                                      2048, 512, 1024, 1);
            head_logsoftmax<<<512, 256, 0, stream>>>(o_b, W4, b4,
                                                     out + (size_t)b * S_ * DOUT);
        }
    }

    // pass-throughs (f32)
    size_t n_gv = (size_t)in_sizes[1], n_uv = (size_t)in_sizes[2];
    size_t o0 = (size_t)out_size - n_gv - n_uv;
    hipMemcpyAsync(out + o0,        gv, n_gv * 4, hipMemcpyDeviceToDevice, stream);
    hipMemcpyAsync(out + o0 + n_gv, uv, n_uv * 4, hipMemcpyDeviceToDevice, stream);
}

// Round 4
// 588.449 us; speedup vs baseline: 1.1599x; 1.1599x over previous
//
#include <hip/hip_runtime.h>
#include <stdint.h>

// Problem constants (fixed by reference)
#define B_   16
#define S_   2048
#define DIN  512
#define DH   1024
#define DOUT 10

typedef unsigned short u16;
typedef unsigned int   u32;

typedef __bf16 bf16_t;
typedef bf16_t bf16x8 __attribute__((ext_vector_type(8)));
typedef float  f32x4  __attribute__((ext_vector_type(4)));

#define MASKVAL (-3.0e4f)
// Packed-P geometry: row-block mi holds r4 = ((mi>>2)+1)*4 tiles of 128 cols.
// Tile-offset of row-block mi: S4(mi) = 4*(g+1)*(mi-2g), g = mi>>2.
// Pair property: S4(2bi+1)-S4(2bi) = 4(g+1) tiles = 128 rows x rstride, and
// both halves share g => rows [bi*256, bi*256+256) are CONTIGUOUS with
// lda = r4*128. Per-batch packed size = 160 tiles * 16384 u16 = 5 MiB.
#define PZ_U16 ((size_t)160 * 16384)

__device__ __forceinline__ float b2f(u16 u) {
    union { u32 i; float f; } v; v.i = ((u32)u) << 16; return v.f;
}
__device__ __forceinline__ u16 f2b(float f) {
    union { float f; u32 i; } v; v.f = f;
    u32 u = v.i;
    u32 r = (u + 0x7FFFu + ((u >> 16) & 1u)) >> 16;  // RNE
    return (u16)r;
}
__device__ __forceinline__ u32 pack2(float a, float b) {
    return (u32)f2b(a) | ((u32)f2b(b) << 16);
}

__device__ __forceinline__ f32x4 mfma16(bf16x8 a, bf16x8 b, f32x4 c) {
    return __builtin_amdgcn_mfma_f32_16x16x32_bf16(a, b, c, 0, 0, 0);
}

// async global->LDS, 16B per lane; LDS dest = wave-uniform base + lane*16
__device__ __forceinline__ void load_lds16(const u16* g, u16* l) {
    __builtin_amdgcn_global_load_lds(
        (__attribute__((address_space(1))) u32*)(g),
        (__attribute__((address_space(3))) u32*)(l), 16, 0, 0);
}

// load 8 contiguous elements at element-index eidx as packed bf16x8 (uint4)
template<bool F32>
__device__ __forceinline__ uint4 ld8(const void* base, size_t eidx) {
    if constexpr (F32) {
        const float* p = (const float*)base + eidx;
        float4 f0 = *(const float4*)p;
        float4 f1 = *(const float4*)(p + 4);
        uint4 r;
        r.x = pack2(f0.x, f0.y); r.y = pack2(f0.z, f0.w);
        r.z = pack2(f1.x, f1.y); r.w = pack2(f1.z, f1.w);
        return r;
    } else {
        return *(const uint4*)((const u16*)base + eidx);
    }
}

// ---------------------------------------------------------------------------
// f32 -> bf16 elementwise convert (8 elems/thread)
// ---------------------------------------------------------------------------
__global__ __launch_bounds__(256) void cvt_f32_bf16(
    const float* __restrict__ in, u16* __restrict__ out, int n8)
{
    int i = blockIdx.x * 256 + threadIdx.x;
    if (i >= n8) return;
    size_t e = (size_t)i * 8;
    float4 f0 = *(const float4*)(in + e);
    float4 f1 = *(const float4*)(in + e + 4);
    uint4 r;
    r.x = pack2(f0.x, f0.y); r.y = pack2(f0.z, f0.w);
    r.z = pack2(f1.x, f1.y); r.w = pack2(f1.z, f1.w);
    *(uint4*)(out + e) = r;
}

// ===========================================================================
// 8-phase 256x256 machinery (T2 swizzle + T3/T4 counted vmcnt + T5 setprio).
// LDS: AS/BS[2 dbuf][256 rows][64 cols] bf16. Load-unit = 64 rows x 64 cols.
// Swizzle: linear slot (row, c) holds data chunk c ^ (row&7) (16B chunks);
// write side pre-swizzles the global source chunk, read side XORs the chunk.
// ===========================================================================
template<int QR>
__device__ __forceinline__ void rda(bf16x8 (&a)[4][2], const u16* T,
                                    int arow, int quad) {
#pragma unroll
    for (int mf = 0; mf < 4; ++mf) {
        const int row = arow + QR * 64 + mf * 16;
        const int sw = row & 7;
#pragma unroll
        for (int ks = 0; ks < 2; ++ks)
            a[mf][ks] = *(const bf16x8*)(T + row * 64 + (((ks * 4 + quad) ^ sw) << 3));
    }
}

template<int QC>
__device__ __forceinline__ void rdb(bf16x8 (&b)[2][2], const u16* T,
                                    int brow, int quad) {
#pragma unroll
    for (int nf = 0; nf < 2; ++nf) {
        const int row = brow + QC * 128 + nf * 16;
        const int sw = row & 7;
#pragma unroll
        for (int ks = 0; ks < 2; ++ks)
            b[nf][ks] = *(const bf16x8*)(T + row * 64 + (((ks * 4 + quad) ^ sw) << 3));
    }
}

template<int QR, int QC>
__device__ __forceinline__ void mmq(f32x4 (&acc)[2][2][4][2],
                                    const bf16x8 (&a)[4][2],
                                    const bf16x8 (&b)[2][2]) {
#pragma unroll
    for (int ks = 0; ks < 2; ++ks)
#pragma unroll
        for (int mf = 0; mf < 4; ++mf)
#pragma unroll
            for (int nf = 0; nf < 2; ++nf)
                acc[QR][QC][mf][nf] = mfma16(a[mf][ks], b[nf][ks], acc[QR][QC][mf][nf]);
}

#define G8BAR()  __builtin_amdgcn_s_barrier()
#define G8LGKM() do { asm volatile("s_waitcnt lgkmcnt(0)" ::: "memory"); \
                      __builtin_amdgcn_sched_barrier(0); } while (0)
#define G8VMC4() asm volatile("s_waitcnt vmcnt(4)" ::: "memory")

// The 8-phase K-loop body, parameterized on staging macros STGA/STGB.
// Phases P1-P4 consume buf0 (quadrants (0,0),(0,1),(1,0),(1,1)), P5-P8 buf1.
// Stage stream (2 units/phase), each unit staged >=1 end-barrier after its
// last reader retired; vmcnt(4) ONLY at P4/P8 end.
#define G8_LOOP_BODY(NT_)                                                     \
    const int NI = (NT_) >> 1;                                                \
    for (int i = 0; i < NI; ++i) {                                            \
        const int t1 = 2 * i + 1, t2 = 2 * i + 2, t3 = 2 * i + 3;             \
        rda<0>(a, AS_[0], arow, quad); rdb<0>(b0r, BS_[0], brow, quad);       \
        STGB(1, 2, t1); STGB(1, 3, t1);                                       \
        G8BAR(); G8LGKM();                                                    \
        __builtin_amdgcn_s_setprio(1); mmq<0, 0>(acc, a, b0r);                \
        __builtin_amdgcn_s_setprio(0); G8BAR();                               \
        rdb<1>(b1r, BS_[0], brow, quad);                                      \
        STGA(1, 1, t1); STGA(1, 3, t1);                                       \
        G8BAR(); G8LGKM();                                                    \
        __builtin_amdgcn_s_setprio(1); mmq<0, 1>(acc, a, b1r);                \
        __builtin_amdgcn_s_setprio(0); G8BAR();                               \
        rda<1>(a, AS_[0], arow, quad);                                        \
        if (t2 < (NT_)) { STGA(0, 0, t2); STGA(0, 2, t2); }                   \
        G8BAR(); G8LGKM();                                                    \
        __builtin_amdgcn_s_setprio(1); mmq<1, 0>(acc, a, b0r);                \
        __builtin_amdgcn_s_setprio(0); G8BAR();                               \
        if (t2 < (NT_)) { STGB(0, 0, t2); STGB(0, 1, t2); }                   \
        G8BAR();                                                              \
        __builtin_amdgcn_s_setprio(1); mmq<1, 1>(acc, a, b1r);                \
        __builtin_amdgcn_s_setprio(0);                                        \
        G8VMC4(); G8BAR();                                                    \
        rda<0>(a, AS_[1], arow, quad); rdb<0>(b0r, BS_[1], brow, quad);       \
        if (t2 < (NT_)) { STGB(0, 2, t2); STGB(0, 3, t2); }                   \
        G8BAR(); G8LGKM();                                                    \
        __builtin_amdgcn_s_setprio(1); mmq<0, 0>(acc, a, b0r);                \
        __builtin_amdgcn_s_setprio(0); G8BAR();                               \
        rdb<1>(b1r, BS_[1], brow, quad);                                      \
        if (t2 < (NT_)) { STGA(0, 1, t2); STGA(0, 3, t2); }                   \
        G8BAR(); G8LGKM();                                                    \
        __builtin_amdgcn_s_setprio(1); mmq<0, 1>(acc, a, b1r);                \
        __builtin_amdgcn_s_setprio(0); G8BAR();                               \
        rda<1>(a, AS_[1], arow, quad);                                        \
        if (t3 < (NT_)) { STGA(1, 0, t3); STGA(1, 2, t3); }                   \
        G8BAR(); G8LGKM();                                                    \
        __builtin_amdgcn_s_setprio(1); mmq<1, 0>(acc, a, b0r);                \
        __builtin_amdgcn_s_setprio(0); G8BAR();                               \
        if (t3 < (NT_)) { STGB(1, 0, t3); STGB(1, 1, t3); }                   \
        G8BAR();                                                              \
        __builtin_amdgcn_s_setprio(1); mmq<1, 1>(acc, a, b1r);                \
        __builtin_amdgcn_s_setprio(0);                                        \
        G8VMC4(); G8BAR();                                                    \
    }

// ===========================================================================
// gemm8: C[M,N] = relu(A[M,K] @ Bt[N,K]^T + bias[N]), bf16.
// grid = (M/256, N/256), block = 512. Requires K % 128 == 0.
// ===========================================================================
__global__ __launch_bounds__(512, 2) void gemm8(
    const u16* __restrict__ A, const u16* __restrict__ Bt,
    const float* __restrict__ bias, u16* __restrict__ C,
    int N, int K, int do_relu)
{
    __shared__ __attribute__((aligned(16))) u16 AS_[2][16384];
    __shared__ __attribute__((aligned(16))) u16 BS_[2][16384];

    const int tid  = threadIdx.x;
    const int lane = tid & 63;
    const int w    = tid >> 6;
    const int wm   = w >> 2, wn = w & 3;
    const int quad = lane >> 4, l15 = lane & 15;
    const int m0 = blockIdx.x * 256, n0 = blockIdx.y * 256;

    // staging bases: row-in-unit = tid>>3, pre-swizzled 16B chunk
    const int rg = tid >> 3;
    const int ch = (lane & 7) ^ ((lane >> 3) & 7);
    const u16* gA = A  + (size_t)(m0 + rg) * K + ch * 8;
    const u16* gB = Bt + (size_t)(n0 + rg) * K + ch * 8;
    const int wslot = w * 512;  // u16 offset of wave's 8-row slice in a unit

#define STGA(BUF, U, T) load_lds16(gA + (size_t)(U) * 64 * K + (T) * 64, \
                                   &AS_[BUF][(U) * 4096 + wslot])
#define STGB(BUF, U, T) load_lds16(gB + (size_t)(U) * 64 * K + (T) * 64, \
                                   &BS_[BUF][(U) * 4096 + wslot])

    f32x4 acc[2][2][4][2];
#pragma unroll
    for (int p = 0; p < 2; ++p)
#pragma unroll
    for (int q = 0; q < 2; ++q)
#pragma unroll
    for (int m = 0; m < 4; ++m)
#pragma unroll
    for (int n = 0; n < 2; ++n) acc[p][q][m][n] = (f32x4){0.f, 0.f, 0.f, 0.f};

    bf16x8 a[4][2], b0r[2][2], b1r[2][2];

    const int NT = K >> 6;       // 64-wide K tiles (even: K % 128 == 0)

    // prologue: full tile0 -> buf0; tile1 A0,A2,B0,B1 -> buf1 (as-if P7,P8)
    STGA(0, 0, 0); STGA(0, 1, 0); STGA(0, 2, 0); STGA(0, 3, 0);
    STGB(0, 0, 0); STGB(0, 1, 0); STGB(0, 2, 0); STGB(0, 3, 0);
    STGA(1, 0, 1); STGA(1, 2, 1);
    STGB(1, 0, 1); STGB(1, 1, 1);
    G8VMC4(); G8BAR();

    const int arow = wm * 128 + l15;
    const int brow = wn * 32 + l15;
    G8_LOOP_BODY(NT)
#undef STGA
#undef STGB

    // epilogue: bias + relu + bf16 store
    const int r0 = quad * 4;
#pragma unroll
    for (int qc = 0; qc < 2; ++qc)
#pragma unroll
    for (int nf = 0; nf < 2; ++nf) {
        const int col = n0 + qc * 128 + wn * 32 + nf * 16 + l15;
        const float bv = bias[col];
#pragma unroll
        for (int qr = 0; qr < 2; ++qr)
#pragma unroll
        for (int mf = 0; mf < 4; ++mf) {
            const int rowb = m0 + wm * 128 + qr * 64 + mf * 16 + r0;
#pragma unroll
            for (int r = 0; r < 4; ++r) {
                float v = acc[qr][qc][mf][nf][r] + bv;
                if (do_relu) v = fmaxf(v, 0.f);
                C[(size_t)(rowb + r) * N + col] = f2b(v);
            }
        }
    }
}

// ===========================================================================
// score8: causal score GEMM on the 8-phase 256x256 template, writing packed P.
// grid.x = nb*38: z = idx/38, t = idx%38.
//   t < 36 : triangular (bi,bj), bj <= bi -> 256x256 score tile.
//   t >= 36: tiny pad block (p = t-36): MASKVAL-fills 8 of the 16 packed-P
//            pad tiles/batch not covered by diagonal score blocks:
//            (mi, ni) = (4g+{0,1}, 4g+{2,3}), g = 0..3.
// A = B = h[z] (2048 x 1024). K = DH (NT=16, same control flow as gemm8).
// Epilogue scatters the four 128x128 quadrants into packed-P; diagonal
// blocks (bi==bj) apply the causal mask (and thereby emit the (2bi,2bi+1)
// pad tile as all-MASKVAL).
// ===========================================================================
__global__ __launch_bounds__(512, 2) void score8(
    const u16* __restrict__ h, u16* __restrict__ P)
{
    __shared__ __attribute__((aligned(16))) u16 AS_[2][16384];
    __shared__ __attribute__((aligned(16))) u16 BS_[2][16384];

    const int z = blockIdx.x / 38;
    const int t = blockIdx.x % 38;

    if (t >= 36) {                               // merged pad-fill blocks
        const int p = t - 36;
        const u16 mb = f2b(MASKVAL);
        const u32 m2 = (u32)mb | ((u32)mb << 16);
        uint4 mv; mv.x = m2; mv.y = m2; mv.z = m2; mv.w = m2;
        u16* Pz0 = P + (size_t)z * PZ_U16;
#pragma unroll
        for (int i = 0; i < 8; ++i) {
            const int idx = p * 8 + i;
            const int g  = idx >> 2;
            const int mi = 4 * g + ((idx >> 1) & 1);
            const int ni = 4 * g + 2 + (idx & 1);
            u16* Pz = Pz0 + (size_t)(4 * (g + 1) * (mi - 2 * g)) * 16384;
            const size_t rstride = (size_t)(4 * (g + 1)) * 128;
            for (int q = threadIdx.x; q < 2048; q += 512) {
                int row = q >> 4, cl = (q & 15) * 8;
                *(uint4*)&Pz[(size_t)row * rstride + ni * 128 + cl] = mv;
            }
        }
        return;
    }

    int bi = 0;
    while ((bi + 1) * (bi + 2) / 2 <= t) ++bi;
    const int bj = t - bi * (bi + 1) / 2;
    const bool diag = (bi == bj);

    const int tid  = threadIdx.x;
    const int lane = tid & 63;
    const int w    = tid >> 6;
    const int wm   = w >> 2, wn = w & 3;
    const int quad = lane >> 4, l15 = lane & 15;
    const int m0 = bi * 256, n0 = bj * 256;

    const u16* hz = h + (size_t)z * S_ * DH;
    const int rg = tid >> 3;
    const int ch = (lane & 7) ^ ((lane >> 3) & 7);
    const u16* gA = hz + (size_t)(m0 + rg) * DH + ch * 8;
    const u16* gB = hz + (size_t)(n0 + rg) * DH + ch * 8;
    const int wslot = w * 512;

#define STGA(BUF, U, T) load_lds16(gA + (size_t)(U) * 64 * DH + (T) * 64, \
                                   &AS_[BUF][(U) * 4096 + wslot])
#define STGB(BUF, U, T) load_lds16(gB + (size_t)(U) * 64 * DH + (T) * 64, \
                                   &BS_[BUF][(U) * 4096 + wslot])

    f32x4 acc[2][2][4][2];
#pragma unroll
    for (int p = 0; p < 2; ++p)
#pragma unroll
    for (int q = 0; q < 2; ++q)
#pragma unroll
    for (int m = 0; m < 4; ++m)
#pragma unroll
    for (int n = 0; n < 2; ++n) acc[p][q][m][n] = (f32x4){0.f, 0.f, 0.f, 0.f};

    bf16x8 a[4][2], b0r[2][2], b1r[2][2];

    const int NT = DH >> 6;      // 16

    STGA(0, 0, 0); STGA(0, 1, 0); STGA(0, 2, 0); STGA(0, 3, 0);
    STGB(0, 0, 0); STGB(0, 1, 0); STGB(0, 2, 0); STGB(0, 3, 0);
    STGA(1, 0, 1); STGA(1, 2, 1);
    STGB(1, 0, 1); STGB(1, 1, 1);
    G8VMC4(); G8BAR();

    const int arow = wm * 128 + l15;
    const int brow = wn * 32 + l15;
    G8_LOOP_BODY(NT)
#undef STGA
#undef STGB

    // epilogue: scatter into packed P with causal mask on diagonal blocks.
    const int mi = 2 * bi + wm;
    const int g  = mi >> 2;
    u16* Pz = P + (size_t)z * PZ_U16
                + (size_t)(4 * (g + 1) * (mi - 2 * g)) * 16384;
    const size_t rstride = (size_t)(4 * (g + 1)) * 128;

    const int r0 = quad * 4;
#pragma unroll
    for (int qc = 0; qc < 2; ++qc) {
        const int ni = 2 * bj + qc;
#pragma unroll
        for (int nf = 0; nf < 2; ++nf) {
            const int cl = wn * 32 + nf * 16 + l15;
            const int colg = n0 + qc * 128 + cl;
#pragma unroll
            for (int qr = 0; qr < 2; ++qr)
#pragma unroll
            for (int mf = 0; mf < 4; ++mf) {
                const int rl = qr * 64 + mf * 16 + r0;
                const int rowg = m0 + wm * 128 + rl;
#pragma unroll
                for (int r = 0; r < 4; ++r) {
                    float v = acc[qr][qc][mf][nf][r];
                    if (diag && colg > rowg + r) v = MASKVAL;
                    Pz[(size_t)(rl + r) * rstride + ni * 128 + cl] = f2b(v);
                }
            }
        }
    }
}

// ===========================================================================
// pv8: ctx[z] = P[z] @ V[z] on the 8-phase 256x256 template.
// Uses the packed-P pair-contiguity: rows [bi*256, bi*256+256) of batch z
// form a dense row-major matrix with lda = K = ((bi>>1)+1)*512.
// Pad tiles at the K-tail hold exact softmax zeros -> including them is
// bitwise-identical to skipping (x + 0*V = x), same ascending-K MFMA order.
// grid.x = nb*32, LPT: bi = 7 - idx/(4*nb) (big-K blocks dispatch FIRST);
// rem = idx%(4*nb): nj = rem&3 (256-col tile of DH), z = rem>>2.
// NT in {8,16,24,32}: with nb=16 (512 blocks), 32+8 and 24+16 pair to a
// balanced 40-NT makespan on 256 CUs.
// ===========================================================================
__global__ __launch_bounds__(512, 2) void pv8(
    const u16* __restrict__ P, const u16* __restrict__ hT,
    u16* __restrict__ ctx, int nb)
{
    __shared__ __attribute__((aligned(16))) u16 AS_[2][16384];
    __shared__ __attribute__((aligned(16))) u16 BS_[2][16384];

    const int per_bi = 4 * nb;
    const int bi  = 7 - (int)(blockIdx.x / per_bi);  // LPT heavy-first
    const int rem = blockIdx.x % per_bi;
    const int nj  = rem & 3;
    const int z   = rem >> 2;

    const int g  = bi >> 1;
    const int K  = (g + 1) * 512;                // = r4*128 = lda
    const int NT = K >> 6;                       // 8/16/24/32 (all even)
    const int n0 = nj * 256;

    const u16* Az = P + (size_t)z * PZ_U16
                      + (size_t)(4 * (g + 1) * (2 * bi - 2 * g)) * 16384;
    const u16* Bz = hT + (size_t)z * DH * S_;
    u16*       C  = ctx + (size_t)z * S_ * DH;

    const int tid  = threadIdx.x;
    const int lane = tid & 63;
    const int w    = tid >> 6;
    const int wm   = w >> 2, wn = w & 3;
    const int quad = lane >> 4, l15 = lane & 15;

    const int rg = tid >> 3;
    const int ch = (lane & 7) ^ ((lane >> 3) & 7);
    const u16* gA = Az + (size_t)rg * K + ch * 8;
    const u16* gB = Bz + (size_t)(n0 + rg) * S_ + ch * 8;
    const int wslot = w * 512;

#define STGA(BUF, U, T) load_lds16(gA + (size_t)(U) * 64 * K + (T) * 64, \
                                   &AS_[BUF][(U) * 4096 + wslot])
#define STGB(BUF, U, T) load_lds16(gB + (size_t)(U) * 64 * S_ + (T) * 64, \
                                   &BS_[BUF][(U) * 4096 + wslot])

    f32x4 acc[2][2][4][2];
#pragma unroll
    for (int p = 0; p < 2; ++p)
#pragma unroll
    for (int q = 0; q < 2; ++q)
#pragma unroll
    for (int m = 0; m < 4; ++m)
#pragma unroll
    for (int n = 0; n < 2; ++n) acc[p][q][m][n] = (f32x4){0.f, 0.f, 0.f, 0.f};

    bf16x8 a[4][2], b0r[2][2], b1r[2][2];

    STGA(0, 0, 0); STGA(0, 1, 0); STGA(0, 2, 0); STGA(0, 3, 0);
    STGB(0, 0, 0); STGB(0, 1, 0); STGB(0, 2, 0); STGB(0, 3, 0);
    STGA(1, 0, 1); STGA(1, 2, 1);
    STGB(1, 0, 1); STGB(1, 1, 1);
    G8VMC4(); G8BAR();

    const int arow = wm * 128 + l15;
    const int brow = wn * 32 + l15;
    G8_LOOP_BODY(NT)
#undef STGA
#undef STGB

    // epilogue: plain bf16 store into ctx
    const int r0 = quad * 4;
#pragma unroll
    for (int qc = 0; qc < 2; ++qc)
#pragma unroll
    for (int nf = 0; nf < 2; ++nf) {
        const int col = n0 + qc * 128 + wn * 32 + nf * 16 + l15;
#pragma unroll
        for (int qr = 0; qr < 2; ++qr)
#pragma unroll
        for (int mf = 0; mf < 4; ++mf) {
            const int rowb = bi * 256 + wm * 128 + qr * 64 + mf * 16 + r0;
#pragma unroll
            for (int r = 0; r < 4; ++r)
                C[(size_t)(rowb + r) * DH + col] = f2b(acc[qr][qc][mf][nf][r]);
        }
    }
}

// ---------------------------------------------------------------------------
// ASYNC score GEMM into PACKED P (tier-C fallback): row-block mi = causal
// tiles ni<=mi, padded to r4 tiles; pad tiles get MASKVAL. grid (16, 16, nb).
// ---------------------------------------------------------------------------
__global__ __launch_bounds__(256) void score_a(
    const u16* __restrict__ h, u16* __restrict__ P)
{
    __shared__ __attribute__((aligned(16))) u16 As[128 * 32];
    __shared__ __attribute__((aligned(16))) u16 Bs[128 * 32];

    const int mi = 15 - blockIdx.x;              // LPT: heavy rows first
    const int ni = blockIdx.y;
    const int g  = mi >> 2;
    const int r4 = (g + 1) * 4;
    if (ni >= r4) return;

    const int tid = threadIdx.x;
    u16* Pz = P + (size_t)blockIdx.z * PZ_U16
                + (size_t)(4 * (g + 1) * (mi - 2 * g)) * 16384;
    const size_t rstride = (size_t)r4 * 128;

    if (ni > mi) {                               // pad tile: MASKVAL fill
        const u16 mb = f2b(MASKVAL);
        const u32 m2 = (u32)mb | ((u32)mb << 16);
        uint4 mv; mv.x = m2; mv.y = m2; mv.z = m2; mv.w = m2;
#pragma unroll
        for (int i = 0; i < 8; ++i) {
            int q = tid + i * 256;
            int row = q >> 4, cl = (q & 15) * 8;
            *(uint4*)&Pz[(size_t)row * rstride + ni * 128 + cl] = mv;
        }
        return;
    }

    const int m0 = mi * 128, n0 = ni * 128;
    const u16* A = h + (size_t)blockIdx.z * S_ * DH;

    const int lane = tid & 63;
    const int w    = tid >> 6;
    const int wm   = w >> 1, wn = w & 1;
    const int quad = lane >> 4, l15 = lane & 15;

    const int c0 = tid, c1 = tid + 256;
    const u16* gA0 = A + ((size_t)(m0 + (c0 >> 2)) * DH + (c0 & 3) * 8);
    const u16* gA1 = A + ((size_t)(m0 + (c1 >> 2)) * DH + (c1 & 3) * 8);
    const u16* gB0 = A + ((size_t)(n0 + (c0 >> 2)) * DH + (c0 & 3) * 8);
    const u16* gB1 = A + ((size_t)(n0 + (c1 >> 2)) * DH + (c1 & 3) * 8);
    u16* lA0 = &As[(w * 64) * 8];
    u16* lA1 = &As[(256 + w * 64) * 8];
    u16* lB0 = &Bs[(w * 64) * 8];
    u16* lB1 = &Bs[(256 + w * 64) * 8];

    f32x4 acc[4][4];
#pragma unroll
    for (int i = 0; i < 4; ++i)
#pragma unroll
        for (int j = 0; j < 4; ++j) acc[i][j] = (f32x4){0.f, 0.f, 0.f, 0.f};

    const int nk = DH >> 5;
    for (int kk = 0; kk < nk; ++kk) {
        load_lds16(gA0, lA0); load_lds16(gA1, lA1);
        load_lds16(gB0, lB0); load_lds16(gB1, lB1);
        gA0 += 32; gA1 += 32; gB0 += 32; gB1 += 32;
        __syncthreads();
        bf16x8 af[4], bfr[4];
#pragma unroll
        for (int i = 0; i < 4; ++i)
            af[i] = *(const bf16x8*)&As[(wm * 64 + i * 16 + l15) * 32 + quad * 8];
#pragma unroll
        for (int j = 0; j < 4; ++j)
            bfr[j] = *(const bf16x8*)&Bs[(wn * 64 + j * 16 + l15) * 32 + quad * 8];
#pragma unroll
        for (int i = 0; i < 4; ++i)
#pragma unroll
            for (int j = 0; j < 4; ++j)
                acc[i][j] = mfma16(af[i], bfr[j], acc[i][j]);
        __syncthreads();
    }

    const int r0 = quad * 4;
#pragma unroll
    for (int j = 0; j < 4; ++j) {
        int cl = wn * 64 + j * 16 + l15;
#pragma unroll
        for (int i = 0; i < 4; ++i) {
            int rl = wm * 64 + i * 16 + r0;
#pragma unroll
            for (int r = 0; r < 4; ++r) {
                int row = rl + r;
                float v = (n0 + cl <= m0 + row) ? acc[i][j][r] : MASKVAL;
                Pz[(size_t)row * rstride + ni * 128 + cl] = f2b(v);
            }
        }
    }
}

// ---------------------------------------------------------------------------
// softmax_rows: in-place row softmax of packed P. One wave per row.
// Row length = kb*512 cols (kb = (mi>>2)+1), includes MASKVAL padding.
// ---------------------------------------------------------------------------
__global__ __launch_bounds__(256) void softmax_rows(u16* __restrict__ P)
{
    const int tid = threadIdx.x;
    const int lane = tid & 63, w = tid >> 6;
    const size_t row = (size_t)blockIdx.x * 4 + w;
    const int z    = (int)(row >> 11);
    const int rloc = (int)(row & (S_ - 1));
    const int mi = rloc >> 7, g = mi >> 2;
    const int kb = g + 1;
    u16* p = P + (size_t)z * PZ_U16
               + (size_t)(4 * (g + 1) * (mi - 2 * g)) * 16384
               + (size_t)(rloc & 127) * ((g + 1) * 4 * 128);
    float v[32];
    float m = -1e30f;
    for (int k = 0; k < kb; ++k) {
        uint4 u = *(const uint4*)&p[k * 512 + lane * 8];
        const u32* uu = (const u32*)&u;
#pragma unroll
        for (int i = 0; i < 4; ++i) {
            float a = b2f((u16)(uu[i] & 0xFFFFu));
            float b = b2f((u16)(uu[i] >> 16));
            v[k * 8 + 2 * i] = a; v[k * 8 + 2 * i + 1] = b;
            m = fmaxf(m, fmaxf(a, b));
        }
    }
#pragma unroll
    for (int off = 32; off >= 1; off >>= 1) m = fmaxf(m, __shfl_xor(m, off, 64));
    float s = 0.f;
    for (int k = 0; k < kb; ++k)
#pragma unroll
        for (int i = 0; i < 8; ++i) {
            float e = __expf(v[k * 8 + i] - m);
            v[k * 8 + i] = e; s += e;
        }
#pragma unroll
    for (int off = 32; off >= 1; off >>= 1) s += __shfl_xor(s, off, 64);
    float inv = 1.0f / s;
    for (int k = 0; k < kb; ++k) {
        uint4 u; u32* uu = (u32*)&u;
#pragma unroll
        for (int i = 0; i < 4; ++i)
            uu[i] = pack2(v[k * 8 + 2 * i] * inv, v[k * 8 + 2 * i + 1] * inv);
        *(uint4*)&p[k * 512 + lane * 8] = u;
    }
}

// ---------------------------------------------------------------------------
// ASYNC pv GEMM (128x128 tile, A2/B/C fallback), LPT 1D grid.
// grid.x = 16*8*nb; idx -> mi = 15 - idx/(8*nb); sub = idx%(8*nb):
// n = sub&7, z = sub>>3. nk = (mi+1)*4.
// ---------------------------------------------------------------------------
__global__ __launch_bounds__(256) void pv_a(
    const u16* __restrict__ P, const u16* __restrict__ hT, u16* __restrict__ ctx,
    int nb)
{
    __shared__ __attribute__((aligned(16))) u16 As[128 * 32];
    __shared__ __attribute__((aligned(16))) u16 Bs[128 * 32];

    const int idx = blockIdx.x;
    const int per_mi = 8 * nb;
    const int mi = 15 - (idx / per_mi);          // LPT: heavy row-blocks first
    const int sub = idx % per_mi;
    const int nblk = sub & 7;
    const int z    = sub >> 3;
    const int g = mi >> 2;
    const int m0 = mi * 128;
    const int n0 = nblk * 128;
    const size_t rstride = (size_t)((g + 1) * 4) * 128;
    const u16* A  = P  + (size_t)z * PZ_U16
                       + (size_t)(4 * (g + 1) * (mi - 2 * g)) * 16384;
    const u16* Bt = hT + (size_t)z * DH * S_;
    u16*      C   = ctx + (size_t)z * S_ * DH;

    const int tid  = threadIdx.x;
    const int lane = tid & 63;
    const int w    = tid >> 6;
    const int wm   = w >> 1, wn = w & 1;
    const int quad = lane >> 4, l15 = lane & 15;

    const int c0 = tid, c1 = tid + 256;
    const u16* gA0 = A  + ((size_t)(c0 >> 2) * rstride + (c0 & 3) * 8);
    const u16* gA1 = A  + ((size_t)(c1 >> 2) * rstride + (c1 & 3) * 8);
    const u16* gB0 = Bt + ((size_t)(n0 + (c0 >> 2)) * S_ + (c0 & 3) * 8);
    const u16* gB1 = Bt + ((size_t)(n0 + (c1 >> 2)) * S_ + (c1 & 3) * 8);
    u16* lA0 = &As[(w * 64) * 8];
    u16* lA1 = &As[(256 + w * 64) * 8];
    u16* lB0 = &Bs[(w * 64) * 8];
    u16* lB1 = &Bs[(256 + w * 64) * 8];

    f32x4 acc[4][4];
#pragma unroll
    for (int i = 0; i < 4; ++i)
#pragma unroll
        for (int j = 0; j < 4; ++j) acc[i][j] = (f32x4){0.f, 0.f, 0.f, 0.f};

    const int nk = (mi + 1) * 4;
    for (int kk = 0; kk < nk; ++kk) {
        load_lds16(gA0, lA0); load_lds16(gA1, lA1);
        load_lds16(gB0, lB0); load_lds16(gB1, lB1);
        gA0 += 32; gA1 += 32; gB0 += 32; gB1 += 32;
        __syncthreads();
        bf16x8 af[4], bfr[4];
#pragma unroll
        for (int i = 0; i < 4; ++i)
            af[i] = *(const bf16x8*)&As[(wm * 64 + i * 16 + l15) * 32 + quad * 8];
#pragma unroll
        for (int j = 0; j < 4; ++j)
            bfr[j] = *(const bf16x8*)&Bs[(wn * 64 + j * 16 + l15) * 32 + quad * 8];
#pragma unroll
        for (int i = 0; i < 4; ++i)
#pragma unroll
            for (int j = 0; j < 4; ++j)
                acc[i][j] = mfma16(af[i], bfr[j], acc[i][j]);
        __syncthreads();
    }

    const int r0 = quad * 4;
#pragma unroll
    for (int j = 0; j < 4; ++j) {
        int col = n0 + wn * 64 + j * 16 + l15;
#pragma unroll
        for (int i = 0; i < 4; ++i) {
            int rowb = m0 + wm * 64 + i * 16 + r0;
#pragma unroll
            for (int r = 0; r < 4; ++r)
                C[(size_t)(rowb + r) * DH + col] = f2b(acc[i][j][r]);
        }
    }
}

// ---------------------------------------------------------------------------
// SYNC-staged GEMM (tier-C fallback only; A may be f32)
// ---------------------------------------------------------------------------
template<bool AF32>
__global__ __launch_bounds__(256) void gemm_bt_bias_relu(
    const void* __restrict__ A, const u16* __restrict__ Bt,
    const float* __restrict__ bias, u16* __restrict__ C,
    int M, int N, int K, int do_relu)
{
    __shared__ __attribute__((aligned(16))) u16 As[128 * 32];
    __shared__ __attribute__((aligned(16))) u16 Bs[128 * 32];

    const int tid  = threadIdx.x;
    const int lane = tid & 63;
    const int w    = tid >> 6;
    const int wm   = w >> 1, wn = w & 1;
    const int quad = lane >> 4, l15 = lane & 15;

    const int m0 = blockIdx.x * 128;
    const int n0 = blockIdx.y * 128;

    const int c0 = tid, c1 = tid + 256;
    size_t eA0 = (size_t)(m0 + (c0 >> 2)) * K + (c0 & 3) * 8;
    size_t eA1 = (size_t)(m0 + (c1 >> 2)) * K + (c1 & 3) * 8;
    size_t eB0 = (size_t)(n0 + (c0 >> 2)) * K + (c0 & 3) * 8;
    size_t eB1 = (size_t)(n0 + (c1 >> 2)) * K + (c1 & 3) * 8;

    f32x4 acc[4][4];
#pragma unroll
    for (int i = 0; i < 4; ++i)
#pragma unroll
        for (int j = 0; j < 4; ++j) acc[i][j] = (f32x4){0.f, 0.f, 0.f, 0.f};

    uint4 va0 = ld8<AF32>(A, eA0), va1 = ld8<AF32>(A, eA1);
    uint4 vb0 = ld8<false>(Bt, eB0), vb1 = ld8<false>(Bt, eB1);

    const int nk = K >> 5;
    for (int kk = 0; kk < nk; ++kk) {
        __syncthreads();
        *(uint4*)&As[c0 * 8] = va0;
        *(uint4*)&As[c1 * 8] = va1;
        *(uint4*)&Bs[c0 * 8] = vb0;
        *(uint4*)&Bs[c1 * 8] = vb1;
        if (kk + 1 < nk) {
            eA0 += 32; eA1 += 32; eB0 += 32; eB1 += 32;
            va0 = ld8<AF32>(A, eA0); va1 = ld8<AF32>(A, eA1);
            vb0 = ld8<false>(Bt, eB0); vb1 = ld8<false>(Bt, eB1);
        }
        __syncthreads();
        bf16x8 af[4], bfr[4];
#pragma unroll
        for (int i = 0; i < 4; ++i)
            af[i] = *(const bf16x8*)&As[(wm * 64 + i * 16 + l15) * 32 + quad * 8];
#pragma unroll
        for (int j = 0; j < 4; ++j)
            bfr[j] = *(const bf16x8*)&Bs[(wn * 64 + j * 16 + l15) * 32 + quad * 8];
#pragma unroll
        for (int i = 0; i < 4; ++i)
#pragma unroll
            for (int j = 0; j < 4; ++j)
                acc[i][j] = mfma16(af[i], bfr[j], acc[i][j]);
    }

    const int r0 = quad * 4;
#pragma unroll
    for (int j = 0; j < 4; ++j) {
        int col = n0 + wn * 64 + j * 16 + l15;
        float bv = bias[col];
#pragma unroll
        for (int i = 0; i < 4; ++i) {
            int rowb = m0 + wm * 64 + i * 16 + r0;
#pragma unroll
            for (int r = 0; r < 4; ++r) {
                float v = acc[i][j][r] + bv;
                if (do_relu) v = fmaxf(v, 0.f);
                C[(size_t)(rowb + r) * N + col] = f2b(v);
            }
        }
    }
}

// ---------------------------------------------------------------------------
// transpose + f32->bf16 convert: in f32 [R][C] -> out bf16 [C][R]. block (32,8)
// ---------------------------------------------------------------------------
__global__ __launch_bounds__(256) void transpose_cvt(
    const float* __restrict__ in, u16* __restrict__ out, int R, int C)
{
    __shared__ u16 t[32][33];
    int c0 = blockIdx.x * 32, r0 = blockIdx.y * 32;
    int tx = threadIdx.x, ty = threadIdx.y;
#pragma unroll
    for (int i = 0; i < 4; ++i)
        t[ty + i * 8][tx] = f2b(in[(size_t)(r0 + ty + i * 8) * C + c0 + tx]);
    __syncthreads();
#pragma unroll
    for (int i = 0; i < 4; ++i)
        out[(size_t)(c0 + ty + i * 8) * R + r0 + tx] = t[tx][ty + i * 8];
}

// batched bf16 transpose: in [z][R][C] -> out [z][C][R]. block (32,8)
__global__ __launch_bounds__(256) void transpose_b(
    const u16* __restrict__ in, u16* __restrict__ out, int R, int C)
{
    __shared__ u16 t[32][33];
    const u16* ip = in  + (size_t)blockIdx.z * R * C;
    u16*       op = out + (size_t)blockIdx.z * R * C;
    int c0 = blockIdx.x * 32, r0 = blockIdx.y * 32;
    int tx = threadIdx.x, ty = threadIdx.y;
#pragma unroll
    for (int i = 0; i < 4; ++i)
        t[ty + i * 8][tx] = ip[(size_t)(r0 + ty + i * 8) * C + c0 + tx];
    __syncthreads();
#pragma unroll
    for (int i = 0; i < 4; ++i)
        op[(size_t)(c0 + ty + i * 8) * R + r0 + tx] = t[tx][ty + i * 8];
}

// ---------------------------------------------------------------------------
// head: out[row,:] = log_softmax(o[row,:] @ W4 + b4). One wave per row.
// ---------------------------------------------------------------------------
__global__ __launch_bounds__(256) void head_logsoftmax(
    const u16* __restrict__ o, const float* __restrict__ W4,
    const float* __restrict__ b4, float* __restrict__ out)
{
    __shared__ float W4s[DIN * DOUT];
    __shared__ float b4s[DOUT];
    const int tid = threadIdx.x;
    for (int i = tid; i < DIN * DOUT; i += 256) W4s[i] = W4[i];
    if (tid < DOUT) b4s[tid] = b4[tid];
    __syncthreads();
    const int lane = tid & 63, w = tid >> 6;
    const size_t row = (size_t)blockIdx.x * 4 + w;
    const uint4 ov = *(const uint4*)&o[row * DIN + lane * 8];
    const u32* ou = (const u32*)&ov;
    float oc[8];
#pragma unroll
    for (int i = 0; i < 4; ++i) {
        oc[2*i]   = b2f((u16)(ou[i] & 0xFFFFu));
        oc[2*i+1] = b2f((u16)(ou[i] >> 16));
    }
    float acc[DOUT];
#pragma unroll
    for (int c = 0; c < DOUT; ++c) acc[c] = 0.f;
#pragma unroll
    for (int i = 0; i < 8; ++i) {
        int k = lane * 8 + i;
        float x = oc[i];
#pragma unroll
        for (int c = 0; c < DOUT; ++c) acc[c] += x * W4s[k * DOUT + c];
    }
#pragma unroll
    for (int off = 32; off >= 1; off >>= 1)
#pragma unroll
        for (int c = 0; c < DOUT; ++c) acc[c] += __shfl_xor(acc[c], off, 64);
    float mx = -1e30f;
#pragma unroll
    for (int c = 0; c < DOUT; ++c) { acc[c] += b4s[c]; mx = fmaxf(mx, acc[c]); }
    float sum = 0.f;
#pragma unroll
    for (int c = 0; c < DOUT; ++c) sum += __expf(acc[c] - mx);
    float lse = mx + logf(sum);
    if (lane == 0) {
#pragma unroll
        for (int c = 0; c < DOUT; ++c) out[row * DOUT + c] = acc[c] - lse;
    }
}

// ---------------------------------------------------------------------------
extern "C" void kernel_launch(void* const* d_in, const int* in_sizes, int n_in,
                              void* d_out, int out_size, void* d_ws, size_t ws_size,
                              hipStream_t stream) {
    const float* x  = (const float*)d_in[0];
    const float* gv = (const float*)d_in[1];
    const float* uv = (const float*)d_in[2];
    const float* W1 = (const float*)d_in[3];
    const float* b1 = (const float*)d_in[4];
    const float* W2 = (const float*)d_in[5];
    const float* b2 = (const float*)d_in[6];
    const float* W3 = (const float*)d_in[7];
    const float* b3 = (const float*)d_in[8];
    const float* W4 = (const float*)d_in[9];
    const float* b4 = (const float*)d_in[10];
    float* out = (float*)d_out;

    char* ws = (char*)d_ws;
    const size_t MB64 = (size_t)67108864;
    const size_t MiB  = (size_t)1048576;
    const size_t TIER_A3 = 2 * MB64 + 80 * MiB + 4 * MiB;   // 212 MiB single-pass
    const size_t TIER_A2 = 2 * MB64 + 72 * MiB + 8 * MiB;   // 208 MiB gate
    const size_t TIER_B  = 3 * MB64 + 5 * MiB;              // 197 MiB

    if (ws_size >= TIER_A3) {
        // Single-pass, alias-packed layout:
        //  [0,64)    h1 (gemm1 out) -> hT (after gemm2)
        //  [64,128)  h  (gemm2 out) -> ctx (pv8 out, h dead after score8)
        //  [128,208) xb (dead after gemm1) -> P (80 MiB) -> o (gemm3 out)
        //  [208,212) W1t/W2t/W3t
        u16* h1  = (u16*)(ws);
        u16* hT  = h1;
        u16* h   = (u16*)(ws + MB64);
        u16* ctx = h;
        u16* xb  = (u16*)(ws + 2 * MB64);
        u16* P   = xb;
        u16* o   = xb;
        u16* W1t = (u16*)(ws + 2 * MB64 + 80 * MiB);
        u16* W2t = W1t + 512 * 1024;
        u16* W3t = W2t + 1024 * 1024;

        cvt_f32_bf16<<<8192, 256, 0, stream>>>(x, xb, 2097152);
        transpose_cvt<<<dim3(32, 16), dim3(32, 8), 0, stream>>>(W1, W1t, 512, 1024);
        transpose_cvt<<<dim3(32, 32), dim3(32, 8), 0, stream>>>(W2, W2t, 1024, 1024);
        transpose_cvt<<<dim3(16, 32), dim3(32, 8), 0, stream>>>(W3, W3t, 1024, 512);

        gemm8<<<dim3(128, 4), 512, 0, stream>>>(xb, W1t, b1, h1, 1024, 512, 1);
        gemm8<<<dim3(128, 4), 512, 0, stream>>>(h1, W2t, b2, h,  1024, 1024, 1);

        transpose_b<<<dim3(32, 64, 16), dim3(32, 8), 0, stream>>>(h, hT, 2048, 1024);
        score8<<<38 * 16, 512, 0, stream>>>(h, P);       // 608 blocks
        softmax_rows<<<8192, 256, 0, stream>>>(P);
        pv8<<<32 * 16, 512, 0, stream>>>(P, hT, ctx, 16); // 512 blocks, LPT

        gemm8<<<dim3(128, 2), 512, 0, stream>>>(ctx, W3t, b3, o, 512, 1024, 1);
        head_logsoftmax<<<8192, 256, 0, stream>>>(o, W4, b4, out);
    } else if (ws_size >= TIER_A2) {
        u16* h1   = (u16*)(ws);
        u16* ctx  = h1;
        u16* h    = (u16*)(ws + MB64);
        u16* o    = h;
        u16* xb   = (u16*)(ws + 2 * MB64);
        u16* hT_c = xb;
        u16* P_c  = (u16*)(ws + 2 * MB64 + 32 * MiB);
        u16* W1t  = (u16*)(ws + 2 * MB64 + 72 * MiB);
        u16* W2t  = W1t + 512 * 1024;
        u16* W3t  = W2t + 1024 * 1024;

        cvt_f32_bf16<<<8192, 256, 0, stream>>>(x, xb, 2097152);
        transpose_cvt<<<dim3(32, 16), dim3(32, 8), 0, stream>>>(W1, W1t, 512, 1024);
        transpose_cvt<<<dim3(32, 32), dim3(32, 8), 0, stream>>>(W2, W2t, 1024, 1024);
        transpose_cvt<<<dim3(16, 32), dim3(32, 8), 0, stream>>>(W3, W3t, 1024, 512);

        gemm8<<<dim3(128, 4), 512, 0, stream>>>(xb, W1t, b1, h1, 1024, 512, 1);
        gemm8<<<dim3(128, 4), 512, 0, stream>>>(h1, W2t, b2, h,  1024, 1024, 1);

        for (int c = 0; c < 2; ++c) {
            const u16* hc  = h   + (size_t)c * 8 * S_ * DH;
            u16*       cxc = ctx + (size_t)c * 8 * S_ * DH;
            transpose_b<<<dim3(32, 64, 8), dim3(32, 8), 0, stream>>>(hc, hT_c, 2048, 1024);
            score8<<<38 * 8, 512, 0, stream>>>(hc, P_c);
            softmax_rows<<<4096, 256, 0, stream>>>(P_c);
            pv_a<<<16 * 8 * 8, 256, 0, stream>>>(P_c, hT_c, cxc, 8);
        }

        gemm8<<<dim3(128, 2), 512, 0, stream>>>(ctx, W3t, b3, o, 512, 1024, 1);
        head_logsoftmax<<<8192, 256, 0, stream>>>(o, W4, b4, out);
    } else if (ws_size >= TIER_B) {
        u16* h1   = (u16*)(ws);
        u16* ctx  = h1;
        u16* h    = (u16*)(ws + MB64);
        u16* xb   = (u16*)(ws + 2 * MB64);
        u16* hT_c = xb;
        u16* P_c  = (u16*)(ws + 2 * MB64 + 16 * MiB);
        u16* o    = (u16*)(ws + 2 * MB64);
        u16* W1t  = (u16*)(ws + 3 * MB64);
        u16* W2t  = W1t + 512 * 1024;
        u16* W3t  = W2t + 1024 * 1024;

        cvt_f32_bf16<<<8192, 256, 0, stream>>>(x, xb, 2097152);
        transpose_cvt<<<dim3(32, 16), dim3(32, 8), 0, stream>>>(W1, W1t, 512, 1024);
        transpose_cvt<<<dim3(32, 32), dim3(32, 8), 0, stream>>>(W2, W2t, 1024, 1024);
        transpose_cvt<<<dim3(16, 32), dim3(32, 8), 0, stream>>>(W3, W3t, 1024, 512);

        gemm8<<<dim3(128, 4), 512, 0, stream>>>(xb, W1t, b1, h1, 1024, 512, 1);
        gemm8<<<dim3(128, 4), 512, 0, stream>>>(h1, W2t, b2, h,  1024, 1024, 1);

        for (int c = 0; c < 4; ++c) {
            const u16* hc  = h   + (size_t)c * 4 * S_ * DH;
            u16*       cxc = ctx + (size_t)c * 4 * S_ * DH;
            transpose_b<<<dim3(32, 64, 4), dim3(32, 8), 0, stream>>>(hc, hT_c, 2048, 1024);
            score8<<<38 * 4, 512, 0, stream>>>(hc, P_c);
            softmax_rows<<<2048, 256, 0, stream>>>(P_c);
            pv_a<<<16 * 8 * 4, 256, 0, stream>>>(P_c, hT_c, cxc, 4);
        }

        gemm8<<<dim3(128, 2), 512, 0, stream>>>(ctx, W3t, b3, o, 512, 1024, 1);
        head_logsoftmax<<<8192, 256, 0, stream>>>(o, W4, b4, out);
    } else {
        u16* h    = (u16*)(ws);
        u16* hT_b = (u16*)(ws + MB64);
        u16* P_b  = (u16*)(ws + MB64 + 4 * MiB);
        u16* ctx_b= (u16*)(ws + MB64 + 12 * MiB);
        u16* o_b  = (u16*)(ws + MB64 + 16 * MiB);
        u16* W1t  = (u16*)(ws + MB64 + 18 * MiB);
        u16* W2t  = W1t + 512 * 1024;
        u16* W3t  = W2t + 1024 * 1024;
        u16* h1_b = P_b;

        transpose_cvt<<<dim3(32, 16), dim3(32, 8), 0, stream>>>(W1, W1t, 512, 1024);
        transpose_cvt<<<dim3(32, 32), dim3(32, 8), 0, stream>>>(W2, W2t, 1024, 1024);
        transpose_cvt<<<dim3(16, 32), dim3(32, 8), 0, stream>>>(W3, W3t, 1024, 512);

        for (int c = 0; c < 8; ++c) {
            const float* xc = x + (size_t)c * 4096 * DIN;
            u16*         hc = h + (size_t)c * 4096 * DH;
            gemm_bt_bias_relu<true ><<<dim3(32, 8), 256, 0, stream>>>(xc, W1t, b1, h1_b,
                                                                      4096, 1024, 512, 1);
            gemm_bt_bias_relu<false><<<dim3(32, 8), 256, 0, stream>>>(h1_b, W2t, b2, hc,
                                                                      4096, 1024, 1024, 1);
        }
        for (int b = 0; b < B_; ++b) {
            const u16* hb = h + (size_t)b * S_ * DH;
            transpose_b<<<dim3(32, 64, 1), dim3(32, 8), 0, stream>>>(hb, hT_b, 2048, 1024);
            score_a<<<dim3(16, 16, 1), 256, 0, stream>>>(hb, P_b);
            softmax_rows<<<512, 256, 0, stream>>>(P_b);
            pv_a<<<16 * 8, 256, 0, stream>>>(P_b, hT_b, ctx_b, 1);
            gemm_bt_bias_relu<false><<<dim3(16, 4), 256, 0, stream>>>(ctx_b, W3t, b3, o_b,
                                                                      2048, 512, 1024, 1);
            head_logsoftmax<<<512, 256, 0, stream>>>(o_b, W4, b4,
                                                     out + (size_t)b * S_ * DOUT);
        }
    }

    // pass-throughs (f32)
    size_t n_gv = (size_t)in_sizes[1], n_uv = (size_t)in_sizes[2];
    size_t o0 = (size_t)out_size - n_gv - n_uv;
    hipMemcpyAsync(out + o0,        gv, n_gv * 4, hipMemcpyDeviceToDevice, stream);
    hipMemcpyAsync(out + o0 + n_gv, uv, n_uv * 4, hipMemcpyDeviceToDevice, stream);
}

// Round 5
// 548.631 us; speedup vs baseline: 1.2441x; 1.0726x over previous
//
#include <hip/hip_runtime.h>
#include <stdint.h>

// Problem constants (fixed by reference)
#define B_   16
#define S_   2048
#define DIN  512
#define DH   1024
#define DOUT 10

typedef unsigned short u16;
typedef unsigned int   u32;

typedef __bf16 bf16_t;
typedef bf16_t bf16x8 __attribute__((ext_vector_type(8)));
typedef float  f32x4  __attribute__((ext_vector_type(4)));

#define MASKVAL (-3.0e4f)
// Packed-P geometry: row-block mi holds r4 = ((mi>>2)+1)*4 tiles of 128 cols.
// Tile-offset of row-block mi: S4(mi) = 4*(g+1)*(mi-2g), g = mi>>2.
// Pair property: S4(2bi+1)-S4(2bi) = 4(g+1) tiles = 128 rows x rstride, and
// both halves share g => rows [bi*256, bi*256+256) are CONTIGUOUS with
// lda = r4*128. Per-batch packed size = 160 tiles * 16384 u16 = 5 MiB.
#define PZ_U16 ((size_t)160 * 16384)

__device__ __forceinline__ float b2f(u16 u) {
    union { u32 i; float f; } v; v.i = ((u32)u) << 16; return v.f;
}
__device__ __forceinline__ u16 f2b(float f) {
    union { float f; u32 i; } v; v.f = f;
    u32 u = v.i;
    u32 r = (u + 0x7FFFu + ((u >> 16) & 1u)) >> 16;  // RNE
    return (u16)r;
}
__device__ __forceinline__ u32 pack2(float a, float b) {
    return (u32)f2b(a) | ((u32)f2b(b) << 16);
}

__device__ __forceinline__ f32x4 mfma16(bf16x8 a, bf16x8 b, f32x4 c) {
    return __builtin_amdgcn_mfma_f32_16x16x32_bf16(a, b, c, 0, 0, 0);
}

// async global->LDS, 16B per lane; LDS dest = wave-uniform base + lane*16
__device__ __forceinline__ void load_lds16(const u16* g, u16* l) {
    __builtin_amdgcn_global_load_lds(
        (__attribute__((address_space(1))) u32*)(g),
        (__attribute__((address_space(3))) u32*)(l), 16, 0, 0);
}

// load 8 contiguous elements at element-index eidx as packed bf16x8 (uint4)
template<bool F32>
__device__ __forceinline__ uint4 ld8(const void* base, size_t eidx) {
    if constexpr (F32) {
        const float* p = (const float*)base + eidx;
        float4 f0 = *(const float4*)p;
        float4 f1 = *(const float4*)(p + 4);
        uint4 r;
        r.x = pack2(f0.x, f0.y); r.y = pack2(f0.z, f0.w);
        r.z = pack2(f1.x, f1.y); r.w = pack2(f1.z, f1.w);
        return r;
    } else {
        return *(const uint4*)((const u16*)base + eidx);
    }
}

// ---------------------------------------------------------------------------
// f32 -> bf16 elementwise convert (8 elems/thread)
// ---------------------------------------------------------------------------
__global__ __launch_bounds__(256) void cvt_f32_bf16(
    const float* __restrict__ in, u16* __restrict__ out, int n8)
{
    int i = blockIdx.x * 256 + threadIdx.x;
    if (i >= n8) return;
    size_t e = (size_t)i * 8;
    float4 f0 = *(const float4*)(in + e);
    float4 f1 = *(const float4*)(in + e + 4);
    uint4 r;
    r.x = pack2(f0.x, f0.y); r.y = pack2(f0.z, f0.w);
    r.z = pack2(f1.x, f1.y); r.w = pack2(f1.z, f1.w);
    *(uint4*)(out + e) = r;
}

// ===========================================================================
// 8-phase 256x256 machinery (T2 swizzle + T3/T4 counted vmcnt + T5 setprio).
// LDS: AS/BS[2 dbuf][256 rows][64 cols] bf16. Load-unit = 64 rows x 64 cols.
// Swizzle: linear slot (row, c) holds data chunk c ^ (row&7) (16B chunks);
// write side pre-swizzles the global source chunk, read side XORs the chunk.
// ===========================================================================
template<int QR>
__device__ __forceinline__ void rda(bf16x8 (&a)[4][2], const u16* T,
                                    int arow, int quad) {
#pragma unroll
    for (int mf = 0; mf < 4; ++mf) {
        const int row = arow + QR * 64 + mf * 16;
        const int sw = row & 7;
#pragma unroll
        for (int ks = 0; ks < 2; ++ks)
            a[mf][ks] = *(const bf16x8*)(T + row * 64 + (((ks * 4 + quad) ^ sw) << 3));
    }
}

template<int QC>
__device__ __forceinline__ void rdb(bf16x8 (&b)[2][2], const u16* T,
                                    int brow, int quad) {
#pragma unroll
    for (int nf = 0; nf < 2; ++nf) {
        const int row = brow + QC * 128 + nf * 16;
        const int sw = row & 7;
#pragma unroll
        for (int ks = 0; ks < 2; ++ks)
            b[nf][ks] = *(const bf16x8*)(T + row * 64 + (((ks * 4 + quad) ^ sw) << 3));
    }
}

template<int QR, int QC>
__device__ __forceinline__ void mmq(f32x4 (&acc)[2][2][4][2],
                                    const bf16x8 (&a)[4][2],
                                    const bf16x8 (&b)[2][2]) {
#pragma unroll
    for (int ks = 0; ks < 2; ++ks)
#pragma unroll
        for (int mf = 0; mf < 4; ++mf)
#pragma unroll
            for (int nf = 0; nf < 2; ++nf)
                acc[QR][QC][mf][nf] = mfma16(a[mf][ks], b[nf][ks], acc[QR][QC][mf][nf]);
}

#define G8BAR()  __builtin_amdgcn_s_barrier()
#define G8LGKM() do { asm volatile("s_waitcnt lgkmcnt(0)" ::: "memory"); \
                      __builtin_amdgcn_sched_barrier(0); } while (0)
#define G8VMC4() asm volatile("s_waitcnt vmcnt(4)" ::: "memory")

// The 8-phase K-loop body, parameterized on staging macros STGA/STGB.
// Phases P1-P4 consume buf0 (quadrants (0,0),(0,1),(1,0),(1,1)), P5-P8 buf1.
// Stage stream (2 units/phase), each unit staged >=1 end-barrier after its
// last reader retired; vmcnt(4) ONLY at P4/P8 end.
#define G8_LOOP_BODY(NT_)                                                     \
    const int NI = (NT_) >> 1;                                                \
    for (int i = 0; i < NI; ++i) {                                            \
        const int t1 = 2 * i + 1, t2 = 2 * i + 2, t3 = 2 * i + 3;             \
        rda<0>(a, AS_[0], arow, quad); rdb<0>(b0r, BS_[0], brow, quad);       \
        STGB(1, 2, t1); STGB(1, 3, t1);                                       \
        G8BAR(); G8LGKM();                                                    \
        __builtin_amdgcn_s_setprio(1); mmq<0, 0>(acc, a, b0r);                \
        __builtin_amdgcn_s_setprio(0); G8BAR();                               \
        rdb<1>(b1r, BS_[0], brow, quad);                                      \
        STGA(1, 1, t1); STGA(1, 3, t1);                                       \
        G8BAR(); G8LGKM();                                                    \
        __builtin_amdgcn_s_setprio(1); mmq<0, 1>(acc, a, b1r);                \
        __builtin_amdgcn_s_setprio(0); G8BAR();                               \
        rda<1>(a, AS_[0], arow, quad);                                        \
        if (t2 < (NT_)) { STGA(0, 0, t2); STGA(0, 2, t2); }                   \
        G8BAR(); G8LGKM();                                                    \
        __builtin_amdgcn_s_setprio(1); mmq<1, 0>(acc, a, b0r);                \
        __builtin_amdgcn_s_setprio(0); G8BAR();                               \
        if (t2 < (NT_)) { STGB(0, 0, t2); STGB(0, 1, t2); }                   \
        G8BAR();                                                              \
        __builtin_amdgcn_s_setprio(1); mmq<1, 1>(acc, a, b1r);                \
        __builtin_amdgcn_s_setprio(0);                                        \
        G8VMC4(); G8BAR();                                                    \
        rda<0>(a, AS_[1], arow, quad); rdb<0>(b0r, BS_[1], brow, quad);       \
        if (t2 < (NT_)) { STGB(0, 2, t2); STGB(0, 3, t2); }                   \
        G8BAR(); G8LGKM();                                                    \
        __builtin_amdgcn_s_setprio(1); mmq<0, 0>(acc, a, b0r);                \
        __builtin_amdgcn_s_setprio(0); G8BAR();                               \
        rdb<1>(b1r, BS_[1], brow, quad);                                      \
        if (t2 < (NT_)) { STGA(0, 1, t2); STGA(0, 3, t2); }                   \
        G8BAR(); G8LGKM();                                                    \
        __builtin_amdgcn_s_setprio(1); mmq<0, 1>(acc, a, b1r);                \
        __builtin_amdgcn_s_setprio(0); G8BAR();                               \
        rda<1>(a, AS_[1], arow, quad);                                        \
        if (t3 < (NT_)) { STGA(1, 0, t3); STGA(1, 2, t3); }                   \
        G8BAR(); G8LGKM();                                                    \
        __builtin_amdgcn_s_setprio(1); mmq<1, 0>(acc, a, b0r);                \
        __builtin_amdgcn_s_setprio(0); G8BAR();                               \
        if (t3 < (NT_)) { STGB(1, 0, t3); STGB(1, 1, t3); }                   \
        G8BAR();                                                              \
        __builtin_amdgcn_s_setprio(1); mmq<1, 1>(acc, a, b1r);                \
        __builtin_amdgcn_s_setprio(0);                                        \
        G8VMC4(); G8BAR();                                                    \
    }

// ===========================================================================
// gemm8: C[M,N] = relu(A[M,K] @ Bt[N,K]^T + bias[N]), bf16.
// grid = (M/256, N/256), block = 512. Requires K % 128 == 0.
// ===========================================================================
__global__ __launch_bounds__(512, 2) void gemm8(
    const u16* __restrict__ A, const u16* __restrict__ Bt,
    const float* __restrict__ bias, u16* __restrict__ C,
    int N, int K, int do_relu)
{
    __shared__ __attribute__((aligned(16))) u16 AS_[2][16384];
    __shared__ __attribute__((aligned(16))) u16 BS_[2][16384];

    const int tid  = threadIdx.x;
    const int lane = tid & 63;
    const int w    = tid >> 6;
    const int wm   = w >> 2, wn = w & 3;
    const int quad = lane >> 4, l15 = lane & 15;
    const int m0 = blockIdx.x * 256, n0 = blockIdx.y * 256;

    // staging bases: row-in-unit = tid>>3, pre-swizzled 16B chunk
    const int rg = tid >> 3;
    const int ch = (lane & 7) ^ ((lane >> 3) & 7);
    const u16* gA = A  + (size_t)(m0 + rg) * K + ch * 8;
    const u16* gB = Bt + (size_t)(n0 + rg) * K + ch * 8;
    const int wslot = w * 512;  // u16 offset of wave's 8-row slice in a unit

#define STGA(BUF, U, T) load_lds16(gA + (size_t)(U) * 64 * K + (T) * 64, \
                                   &AS_[BUF][(U) * 4096 + wslot])
#define STGB(BUF, U, T) load_lds16(gB + (size_t)(U) * 64 * K + (T) * 64, \
                                   &BS_[BUF][(U) * 4096 + wslot])

    f32x4 acc[2][2][4][2];
#pragma unroll
    for (int p = 0; p < 2; ++p)
#pragma unroll
    for (int q = 0; q < 2; ++q)
#pragma unroll
    for (int m = 0; m < 4; ++m)
#pragma unroll
    for (int n = 0; n < 2; ++n) acc[p][q][m][n] = (f32x4){0.f, 0.f, 0.f, 0.f};

    bf16x8 a[4][2], b0r[2][2], b1r[2][2];

    const int NT = K >> 6;       // 64-wide K tiles (even: K % 128 == 0)

    // prologue: full tile0 -> buf0; tile1 A0,A2,B0,B1 -> buf1 (as-if P7,P8)
    STGA(0, 0, 0); STGA(0, 1, 0); STGA(0, 2, 0); STGA(0, 3, 0);
    STGB(0, 0, 0); STGB(0, 1, 0); STGB(0, 2, 0); STGB(0, 3, 0);
    STGA(1, 0, 1); STGA(1, 2, 1);
    STGB(1, 0, 1); STGB(1, 1, 1);
    G8VMC4(); G8BAR();

    const int arow = wm * 128 + l15;
    const int brow = wn * 32 + l15;
    G8_LOOP_BODY(NT)
#undef STGA
#undef STGB

    // epilogue: bias + relu + bf16 store
    const int r0 = quad * 4;
#pragma unroll
    for (int qc = 0; qc < 2; ++qc)
#pragma unroll
    for (int nf = 0; nf < 2; ++nf) {
        const int col = n0 + qc * 128 + wn * 32 + nf * 16 + l15;
        const float bv = bias[col];
#pragma unroll
        for (int qr = 0; qr < 2; ++qr)
#pragma unroll
        for (int mf = 0; mf < 4; ++mf) {
            const int rowb = m0 + wm * 128 + qr * 64 + mf * 16 + r0;
#pragma unroll
            for (int r = 0; r < 4; ++r) {
                float v = acc[qr][qc][mf][nf][r] + bv;
                if (do_relu) v = fmaxf(v, 0.f);
                C[(size_t)(rowb + r) * N + col] = f2b(v);
            }
        }
    }
}

// ===========================================================================
// score8: causal score GEMM on the 8-phase 256x256 template, writing packed P.
// Logical index l = z*38 + t:
//   t < 36 : triangular (bi,bj), bj <= bi -> 256x256 score tile.
//   t >= 36: tiny pad block (p = t-36): MASKVAL-fills 8 of the 16 packed-P
//            pad tiles/batch not covered by diagonal score blocks:
//            (mi, ni) = (4g+{0,1}, 4g+{2,3}), g = 0..3.
// XCD swizzle (T1, when nb%8==0): blockIdx p -> xcd=p&7, slot=p>>3,
//   z=(slot/38)*8+xcd, t=slot%38. All 38 blocks of a z land on ONE XCD so
//   the z's 4 MB h-panel fits that XCD's 4 MiB private L2 (cuts re-fetch).
// A = B = h[z] (2048 x 1024). K = DH (NT=16, same control flow as gemm8).
// Epilogue scatters the four 128x128 quadrants into packed-P; diagonal
// blocks (bi==bj) apply the causal mask (and thereby emit the (2bi,2bi+1)
// pad tile as all-MASKVAL).
// ===========================================================================
__global__ __launch_bounds__(512, 2) void score8(
    const u16* __restrict__ h, u16* __restrict__ P, int nbb)
{
    __shared__ __attribute__((aligned(16))) u16 AS_[2][16384];
    __shared__ __attribute__((aligned(16))) u16 BS_[2][16384];

    int z, t;
    if ((nbb & 7) == 0) {
        const int xcd = blockIdx.x & 7, slot = blockIdx.x >> 3;
        z = (slot / 38) * 8 + xcd;
        t = slot % 38;
    } else {
        z = blockIdx.x / 38;
        t = blockIdx.x % 38;
    }

    if (t >= 36) {                               // merged pad-fill blocks
        const int p = t - 36;
        const u16 mb = f2b(MASKVAL);
        const u32 m2 = (u32)mb | ((u32)mb << 16);
        uint4 mv; mv.x = m2; mv.y = m2; mv.z = m2; mv.w = m2;
        u16* Pz0 = P + (size_t)z * PZ_U16;
#pragma unroll
        for (int i = 0; i < 8; ++i) {
            const int idx = p * 8 + i;
            const int g  = idx >> 2;
            const int mi = 4 * g + ((idx >> 1) & 1);
            const int ni = 4 * g + 2 + (idx & 1);
            u16* Pz = Pz0 + (size_t)(4 * (g + 1) * (mi - 2 * g)) * 16384;
            const size_t rstride = (size_t)(4 * (g + 1)) * 128;
            for (int q = threadIdx.x; q < 2048; q += 512) {
                int row = q >> 4, cl = (q & 15) * 8;
                *(uint4*)&Pz[(size_t)row * rstride + ni * 128 + cl] = mv;
            }
        }
        return;
    }

    int bi = 0;
    while ((bi + 1) * (bi + 2) / 2 <= t) ++bi;
    const int bj = t - bi * (bi + 1) / 2;
    const bool diag = (bi == bj);

    const int tid  = threadIdx.x;
    const int lane = tid & 63;
    const int w    = tid >> 6;
    const int wm   = w >> 2, wn = w & 3;
    const int quad = lane >> 4, l15 = lane & 15;
    const int m0 = bi * 256, n0 = bj * 256;

    const u16* hz = h + (size_t)z * S_ * DH;
    const int rg = tid >> 3;
    const int ch = (lane & 7) ^ ((lane >> 3) & 7);
    const u16* gA = hz + (size_t)(m0 + rg) * DH + ch * 8;
    const u16* gB = hz + (size_t)(n0 + rg) * DH + ch * 8;
    const int wslot = w * 512;

#define STGA(BUF, U, T) load_lds16(gA + (size_t)(U) * 64 * DH + (T) * 64, \
                                   &AS_[BUF][(U) * 4096 + wslot])
#define STGB(BUF, U, T) load_lds16(gB + (size_t)(U) * 64 * DH + (T) * 64, \
                                   &BS_[BUF][(U) * 4096 + wslot])

    f32x4 acc[2][2][4][2];
#pragma unroll
    for (int p = 0; p < 2; ++p)
#pragma unroll
    for (int q = 0; q < 2; ++q)
#pragma unroll
    for (int m = 0; m < 4; ++m)
#pragma unroll
    for (int n = 0; n < 2; ++n) acc[p][q][m][n] = (f32x4){0.f, 0.f, 0.f, 0.f};

    bf16x8 a[4][2], b0r[2][2], b1r[2][2];

    const int NT = DH >> 6;      // 16

    STGA(0, 0, 0); STGA(0, 1, 0); STGA(0, 2, 0); STGA(0, 3, 0);
    STGB(0, 0, 0); STGB(0, 1, 0); STGB(0, 2, 0); STGB(0, 3, 0);
    STGA(1, 0, 1); STGA(1, 2, 1);
    STGB(1, 0, 1); STGB(1, 1, 1);
    G8VMC4(); G8BAR();

    const int arow = wm * 128 + l15;
    const int brow = wn * 32 + l15;
    G8_LOOP_BODY(NT)
#undef STGA
#undef STGB

    // epilogue: scatter into packed P with causal mask on diagonal blocks.
    const int mi = 2 * bi + wm;
    const int g  = mi >> 2;
    u16* Pz = P + (size_t)z * PZ_U16
                + (size_t)(4 * (g + 1) * (mi - 2 * g)) * 16384;
    const size_t rstride = (size_t)(4 * (g + 1)) * 128;

    const int r0 = quad * 4;
#pragma unroll
    for (int qc = 0; qc < 2; ++qc) {
        const int ni = 2 * bj + qc;
#pragma unroll
        for (int nf = 0; nf < 2; ++nf) {
            const int cl = wn * 32 + nf * 16 + l15;
            const int colg = n0 + qc * 128 + cl;
#pragma unroll
            for (int qr = 0; qr < 2; ++qr)
#pragma unroll
            for (int mf = 0; mf < 4; ++mf) {
                const int rl = qr * 64 + mf * 16 + r0;
                const int rowg = m0 + wm * 128 + rl;
#pragma unroll
                for (int r = 0; r < 4; ++r) {
                    float v = acc[qr][qc][mf][nf][r];
                    if (diag && colg > rowg + r) v = MASKVAL;
                    Pz[(size_t)(rl + r) * rstride + ni * 128 + cl] = f2b(v);
                }
            }
        }
    }
}

// ===========================================================================
// pv8: ctx[z] = P[z] @ V[z] on the 8-phase 256x256 template.
// Uses the packed-P pair-contiguity: rows [bi*256, bi*256+256) of batch z
// form a dense row-major matrix with lda = K = ((bi>>1)+1)*512.
// Pad tiles at the K-tail hold exact softmax zeros -> including them is
// bitwise-identical to skipping (x + 0*V = x), same ascending-K MFMA order.
// grid.x = nb*32, LPT: bi = 7 - idx/(4*nb) (big-K blocks dispatch FIRST);
// rem = idx%(4*nb): nj = rem&3 (256-col tile of DH), z = rem>>2.
// NT in {8,16,24,32}: with nb=16 (512 blocks), 32+8 and 24+16 pair to a
// balanced 40-NT makespan on 256 CUs.
// ===========================================================================
__global__ __launch_bounds__(512, 2) void pv8(
    const u16* __restrict__ P, const u16* __restrict__ hT,
    u16* __restrict__ ctx, int nb)
{
    __shared__ __attribute__((aligned(16))) u16 AS_[2][16384];
    __shared__ __attribute__((aligned(16))) u16 BS_[2][16384];

    const int per_bi = 4 * nb;
    const int bi  = 7 - (int)(blockIdx.x / per_bi);  // LPT heavy-first
    const int rem = blockIdx.x % per_bi;
    const int nj  = rem & 3;
    const int z   = rem >> 2;

    const int g  = bi >> 1;
    const int K  = (g + 1) * 512;                // = r4*128 = lda
    const int NT = K >> 6;                       // 8/16/24/32 (all even)
    const int n0 = nj * 256;

    const u16* Az = P + (size_t)z * PZ_U16
                      + (size_t)(4 * (g + 1) * (2 * bi - 2 * g)) * 16384;
    const u16* Bz = hT + (size_t)z * DH * S_;
    u16*       C  = ctx + (size_t)z * S_ * DH;

    const int tid  = threadIdx.x;
    const int lane = tid & 63;
    const int w    = tid >> 6;
    const int wm   = w >> 2, wn = w & 3;
    const int quad = lane >> 4, l15 = lane & 15;

    const int rg = tid >> 3;
    const int ch = (lane & 7) ^ ((lane >> 3) & 7);
    const u16* gA = Az + (size_t)rg * K + ch * 8;
    const u16* gB = Bz + (size_t)(n0 + rg) * S_ + ch * 8;
    const int wslot = w * 512;

#define STGA(BUF, U, T) load_lds16(gA + (size_t)(U) * 64 * K + (T) * 64, \
                                   &AS_[BUF][(U) * 4096 + wslot])
#define STGB(BUF, U, T) load_lds16(gB + (size_t)(U) * 64 * S_ + (T) * 64, \
                                   &BS_[BUF][(U) * 4096 + wslot])

    f32x4 acc[2][2][4][2];
#pragma unroll
    for (int p = 0; p < 2; ++p)
#pragma unroll
    for (int q = 0; q < 2; ++q)
#pragma unroll
    for (int m = 0; m < 4; ++m)
#pragma unroll
    for (int n = 0; n < 2; ++n) acc[p][q][m][n] = (f32x4){0.f, 0.f, 0.f, 0.f};

    bf16x8 a[4][2], b0r[2][2], b1r[2][2];

    STGA(0, 0, 0); STGA(0, 1, 0); STGA(0, 2, 0); STGA(0, 3, 0);
    STGB(0, 0, 0); STGB(0, 1, 0); STGB(0, 2, 0); STGB(0, 3, 0);
    STGA(1, 0, 1); STGA(1, 2, 1);
    STGB(1, 0, 1); STGB(1, 1, 1);
    G8VMC4(); G8BAR();

    const int arow = wm * 128 + l15;
    const int brow = wn * 32 + l15;
    G8_LOOP_BODY(NT)
#undef STGA
#undef STGB

    // epilogue: plain bf16 store into ctx
    const int r0 = quad * 4;
#pragma unroll
    for (int qc = 0; qc < 2; ++qc)
#pragma unroll
    for (int nf = 0; nf < 2; ++nf) {
        const int col = n0 + qc * 128 + wn * 32 + nf * 16 + l15;
#pragma unroll
        for (int qr = 0; qr < 2; ++qr)
#pragma unroll
        for (int mf = 0; mf < 4; ++mf) {
            const int rowb = bi * 256 + wm * 128 + qr * 64 + mf * 16 + r0;
#pragma unroll
            for (int r = 0; r < 4; ++r)
                C[(size_t)(rowb + r) * DH + col] = f2b(acc[qr][qc][mf][nf][r]);
        }
    }
}

// ---------------------------------------------------------------------------
// ASYNC score GEMM into PACKED P (tier-C fallback): row-block mi = causal
// tiles ni<=mi, padded to r4 tiles; pad tiles get MASKVAL. grid (16, 16, nb).
// ---------------------------------------------------------------------------
__global__ __launch_bounds__(256) void score_a(
    const u16* __restrict__ h, u16* __restrict__ P)
{
    __shared__ __attribute__((aligned(16))) u16 As[128 * 32];
    __shared__ __attribute__((aligned(16))) u16 Bs[128 * 32];

    const int mi = 15 - blockIdx.x;              // LPT: heavy rows first
    const int ni = blockIdx.y;
    const int g  = mi >> 2;
    const int r4 = (g + 1) * 4;
    if (ni >= r4) return;

    const int tid = threadIdx.x;
    u16* Pz = P + (size_t)blockIdx.z * PZ_U16
                + (size_t)(4 * (g + 1) * (mi - 2 * g)) * 16384;
    const size_t rstride = (size_t)r4 * 128;

    if (ni > mi) {                               // pad tile: MASKVAL fill
        const u16 mb = f2b(MASKVAL);
        const u32 m2 = (u32)mb | ((u32)mb << 16);
        uint4 mv; mv.x = m2; mv.y = m2; mv.z = m2; mv.w = m2;
#pragma unroll
        for (int i = 0; i < 8; ++i) {
            int q = tid + i * 256;
            int row = q >> 4, cl = (q & 15) * 8;
            *(uint4*)&Pz[(size_t)row * rstride + ni * 128 + cl] = mv;
        }
        return;
    }

    const int m0 = mi * 128, n0 = ni * 128;
    const u16* A = h + (size_t)blockIdx.z * S_ * DH;

    const int lane = tid & 63;
    const int w    = tid >> 6;
    const int wm   = w >> 1, wn = w & 1;
    const int quad = lane >> 4, l15 = lane & 15;

    const int c0 = tid, c1 = tid + 256;
    const u16* gA0 = A + ((size_t)(m0 + (c0 >> 2)) * DH + (c0 & 3) * 8);
    const u16* gA1 = A + ((size_t)(m0 + (c1 >> 2)) * DH + (c1 & 3) * 8);
    const u16* gB0 = A + ((size_t)(n0 + (c0 >> 2)) * DH + (c0 & 3) * 8);
    const u16* gB1 = A + ((size_t)(n0 + (c1 >> 2)) * DH + (c1 & 3) * 8);
    u16* lA0 = &As[(w * 64) * 8];
    u16* lA1 = &As[(256 + w * 64) * 8];
    u16* lB0 = &Bs[(w * 64) * 8];
    u16* lB1 = &Bs[(256 + w * 64) * 8];

    f32x4 acc[4][4];
#pragma unroll
    for (int i = 0; i < 4; ++i)
#pragma unroll
        for (int j = 0; j < 4; ++j) acc[i][j] = (f32x4){0.f, 0.f, 0.f, 0.f};

    const int nk = DH >> 5;
    for (int kk = 0; kk < nk; ++kk) {
        load_lds16(gA0, lA0); load_lds16(gA1, lA1);
        load_lds16(gB0, lB0); load_lds16(gB1, lB1);
        gA0 += 32; gA1 += 32; gB0 += 32; gB1 += 32;
        __syncthreads();
        bf16x8 af[4], bfr[4];
#pragma unroll
        for (int i = 0; i < 4; ++i)
            af[i] = *(const bf16x8*)&As[(wm * 64 + i * 16 + l15) * 32 + quad * 8];
#pragma unroll
        for (int j = 0; j < 4; ++j)
            bfr[j] = *(const bf16x8*)&Bs[(wn * 64 + j * 16 + l15) * 32 + quad * 8];
#pragma unroll
        for (int i = 0; i < 4; ++i)
#pragma unroll
            for (int j = 0; j < 4; ++j)
                acc[i][j] = mfma16(af[i], bfr[j], acc[i][j]);
        __syncthreads();
    }

    const int r0 = quad * 4;
#pragma unroll
    for (int j = 0; j < 4; ++j) {
        int cl = wn * 64 + j * 16 + l15;
#pragma unroll
        for (int i = 0; i < 4; ++i) {
            int rl = wm * 64 + i * 16 + r0;
#pragma unroll
            for (int r = 0; r < 4; ++r) {
                int row = rl + r;
                float v = (n0 + cl <= m0 + row) ? acc[i][j][r] : MASKVAL;
                Pz[(size_t)row * rstride + ni * 128 + cl] = f2b(v);
            }
        }
    }
}

// ---------------------------------------------------------------------------
// softmax_rows: in-place row softmax of packed P. One wave per row.
// Row length = kb*512 cols (kb = (mi>>2)+1), includes MASKVAL padding.
// ---------------------------------------------------------------------------
__global__ __launch_bounds__(256) void softmax_rows(u16* __restrict__ P)
{
    const int tid = threadIdx.x;
    const int lane = tid & 63, w = tid >> 6;
    const size_t row = (size_t)blockIdx.x * 4 + w;
    const int z    = (int)(row >> 11);
    const int rloc = (int)(row & (S_ - 1));
    const int mi = rloc >> 7, g = mi >> 2;
    const int kb = g + 1;
    u16* p = P + (size_t)z * PZ_U16
               + (size_t)(4 * (g + 1) * (mi - 2 * g)) * 16384
               + (size_t)(rloc & 127) * ((g + 1) * 4 * 128);
    float v[32];
    float m = -1e30f;
    for (int k = 0; k < kb; ++k) {
        uint4 u = *(const uint4*)&p[k * 512 + lane * 8];
        const u32* uu = (const u32*)&u;
#pragma unroll
        for (int i = 0; i < 4; ++i) {
            float a = b2f((u16)(uu[i] & 0xFFFFu));
            float b = b2f((u16)(uu[i] >> 16));
            v[k * 8 + 2 * i] = a; v[k * 8 + 2 * i + 1] = b;
            m = fmaxf(m, fmaxf(a, b));
        }
    }
#pragma unroll
    for (int off = 32; off >= 1; off >>= 1) m = fmaxf(m, __shfl_xor(m, off, 64));
    float s = 0.f;
    for (int k = 0; k < kb; ++k)
#pragma unroll
        for (int i = 0; i < 8; ++i) {
            float e = __expf(v[k * 8 + i] - m);
            v[k * 8 + i] = e; s += e;
        }
#pragma unroll
    for (int off = 32; off >= 1; off >>= 1) s += __shfl_xor(s, off, 64);
    float inv = 1.0f / s;
    for (int k = 0; k < kb; ++k) {
        uint4 u; u32* uu = (u32*)&u;
#pragma unroll
        for (int i = 0; i < 4; ++i)
            uu[i] = pack2(v[k * 8 + 2 * i] * inv, v[k * 8 + 2 * i + 1] * inv);
        *(uint4*)&p[k * 512 + lane * 8] = u;
    }
}

// ---------------------------------------------------------------------------
// ASYNC pv GEMM (128x128 tile, A2/B/C fallback), LPT 1D grid.
// grid.x = 16*8*nb; idx -> mi = 15 - idx/(8*nb); sub = idx%(8*nb):
// n = sub&7, z = sub>>3. nk = (mi+1)*4.
// ---------------------------------------------------------------------------
__global__ __launch_bounds__(256) void pv_a(
    const u16* __restrict__ P, const u16* __restrict__ hT, u16* __restrict__ ctx,
    int nb)
{
    __shared__ __attribute__((aligned(16))) u16 As[128 * 32];
    __shared__ __attribute__((aligned(16))) u16 Bs[128 * 32];

    const int idx = blockIdx.x;
    const int per_mi = 8 * nb;
    const int mi = 15 - (idx / per_mi);          // LPT: heavy row-blocks first
    const int sub = idx % per_mi;
    const int nblk = sub & 7;
    const int z    = sub >> 3;
    const int g = mi >> 2;
    const int m0 = mi * 128;
    const int n0 = nblk * 128;
    const size_t rstride = (size_t)((g + 1) * 4) * 128;
    const u16* A  = P  + (size_t)z * PZ_U16
                       + (size_t)(4 * (g + 1) * (mi - 2 * g)) * 16384;
    const u16* Bt = hT + (size_t)z * DH * S_;
    u16*      C   = ctx + (size_t)z * S_ * DH;

    const int tid  = threadIdx.x;
    const int lane = tid & 63;
    const int w    = tid >> 6;
    const int wm   = w >> 1, wn = w & 1;
    const int quad = lane >> 4, l15 = lane & 15;

    const int c0 = tid, c1 = tid + 256;
    const u16* gA0 = A  + ((size_t)(c0 >> 2) * rstride + (c0 & 3) * 8);
    const u16* gA1 = A  + ((size_t)(c1 >> 2) * rstride + (c1 & 3) * 8);
    const u16* gB0 = Bt + ((size_t)(n0 + (c0 >> 2)) * S_ + (c0 & 3) * 8);
    const u16* gB1 = Bt + ((size_t)(n0 + (c1 >> 2)) * S_ + (c1 & 3) * 8);
    u16* lA0 = &As[(w * 64) * 8];
    u16* lA1 = &As[(256 + w * 64) * 8];
    u16* lB0 = &Bs[(w * 64) * 8];
    u16* lB1 = &Bs[(256 + w * 64) * 8];

    f32x4 acc[4][4];
#pragma unroll
    for (int i = 0; i < 4; ++i)
#pragma unroll
        for (int j = 0; j < 4; ++j) acc[i][j] = (f32x4){0.f, 0.f, 0.f, 0.f};

    const int nk = (mi + 1) * 4;
    for (int kk = 0; kk < nk; ++kk) {
        load_lds16(gA0, lA0); load_lds16(gA1, lA1);
        load_lds16(gB0, lB0); load_lds16(gB1, lB1);
        gA0 += 32; gA1 += 32; gB0 += 32; gB1 += 32;
        __syncthreads();
        bf16x8 af[4], bfr[4];
#pragma unroll
        for (int i = 0; i < 4; ++i)
            af[i] = *(const bf16x8*)&As[(wm * 64 + i * 16 + l15) * 32 + quad * 8];
#pragma unroll
        for (int j = 0; j < 4; ++j)
            bfr[j] = *(const bf16x8*)&Bs[(wn * 64 + j * 16 + l15) * 32 + quad * 8];
#pragma unroll
        for (int i = 0; i < 4; ++i)
#pragma unroll
            for (int j = 0; j < 4; ++j)
                acc[i][j] = mfma16(af[i], bfr[j], acc[i][j]);
        __syncthreads();
    }

    const int r0 = quad * 4;
#pragma unroll
    for (int j = 0; j < 4; ++j) {
        int col = n0 + wn * 64 + j * 16 + l15;
#pragma unroll
        for (int i = 0; i < 4; ++i) {
            int rowb = m0 + wm * 64 + i * 16 + r0;
#pragma unroll
            for (int r = 0; r < 4; ++r)
                C[(size_t)(rowb + r) * DH + col] = f2b(acc[i][j][r]);
        }
    }
}

// ---------------------------------------------------------------------------
// SYNC-staged GEMM (tier-C fallback only; A may be f32)
// ---------------------------------------------------------------------------
template<bool AF32>
__global__ __launch_bounds__(256) void gemm_bt_bias_relu(
    const void* __restrict__ A, const u16* __restrict__ Bt,
    const float* __restrict__ bias, u16* __restrict__ C,
    int M, int N, int K, int do_relu)
{
    __shared__ __attribute__((aligned(16))) u16 As[128 * 32];
    __shared__ __attribute__((aligned(16))) u16 Bs[128 * 32];

    const int tid  = threadIdx.x;
    const int lane = tid & 63;
    const int w    = tid >> 6;
    const int wm   = w >> 1, wn = w & 1;
    const int quad = lane >> 4, l15 = lane & 15;

    const int m0 = blockIdx.x * 128;
    const int n0 = blockIdx.y * 128;

    const int c0 = tid, c1 = tid + 256;
    size_t eA0 = (size_t)(m0 + (c0 >> 2)) * K + (c0 & 3) * 8;
    size_t eA1 = (size_t)(m0 + (c1 >> 2)) * K + (c1 & 3) * 8;
    size_t eB0 = (size_t)(n0 + (c0 >> 2)) * K + (c0 & 3) * 8;
    size_t eB1 = (size_t)(n0 + (c1 >> 2)) * K + (c1 & 3) * 8;

    f32x4 acc[4][4];
#pragma unroll
    for (int i = 0; i < 4; ++i)
#pragma unroll
        for (int j = 0; j < 4; ++j) acc[i][j] = (f32x4){0.f, 0.f, 0.f, 0.f};

    uint4 va0 = ld8<AF32>(A, eA0), va1 = ld8<AF32>(A, eA1);
    uint4 vb0 = ld8<false>(Bt, eB0), vb1 = ld8<false>(Bt, eB1);

    const int nk = K >> 5;
    for (int kk = 0; kk < nk; ++kk) {
        __syncthreads();
        *(uint4*)&As[c0 * 8] = va0;
        *(uint4*)&As[c1 * 8] = va1;
        *(uint4*)&Bs[c0 * 8] = vb0;
        *(uint4*)&Bs[c1 * 8] = vb1;
        if (kk + 1 < nk) {
            eA0 += 32; eA1 += 32; eB0 += 32; eB1 += 32;
            va0 = ld8<AF32>(A, eA0); va1 = ld8<AF32>(A, eA1);
            vb0 = ld8<false>(Bt, eB0); vb1 = ld8<false>(Bt, eB1);
        }
        __syncthreads();
        bf16x8 af[4], bfr[4];
#pragma unroll
        for (int i = 0; i < 4; ++i)
            af[i] = *(const bf16x8*)&As[(wm * 64 + i * 16 + l15) * 32 + quad * 8];
#pragma unroll
        for (int j = 0; j < 4; ++j)
            bfr[j] = *(const bf16x8*)&Bs[(wn * 64 + j * 16 + l15) * 32 + quad * 8];
#pragma unroll
        for (int i = 0; i < 4; ++i)
#pragma unroll
            for (int j = 0; j < 4; ++j)
                acc[i][j] = mfma16(af[i], bfr[j], acc[i][j]);
    }

    const int r0 = quad * 4;
#pragma unroll
    for (int j = 0; j < 4; ++j) {
        int col = n0 + wn * 64 + j * 16 + l15;
        float bv = bias[col];
#pragma unroll
        for (int i = 0; i < 4; ++i) {
            int rowb = m0 + wm * 64 + i * 16 + r0;
#pragma unroll
            for (int r = 0; r < 4; ++r) {
                float v = acc[i][j][r] + bv;
                if (do_relu) v = fmaxf(v, 0.f);
                C[(size_t)(rowb + r) * N + col] = f2b(v);
            }
        }
    }
}

// ---------------------------------------------------------------------------
// wprep: fused weight prep — transpose + f32->bf16 for W1/W2/W3 in ONE launch.
// Logical tiles: W1 512x1024 (512), W2 1024x1024 (1024), W3 1024x512 (512).
// grid 2048 x block (32,8).
// ---------------------------------------------------------------------------
__global__ __launch_bounds__(256) void wprep(
    const float* __restrict__ W1, const float* __restrict__ W2,
    const float* __restrict__ W3,
    u16* __restrict__ W1t, u16* __restrict__ W2t, u16* __restrict__ W3t)
{
    __shared__ u16 t[32][33];
    int i = blockIdx.x;
    const float* in; u16* out; int R, C, xt;
    if (i < 512)       { in = W1; out = W1t; R = 512;  C = 1024; xt = 32; }
    else if (i < 1536) { in = W2; out = W2t; R = 1024; C = 1024; xt = 32; i -= 512; }
    else               { in = W3; out = W3t; R = 1024; C = 512;  xt = 16; i -= 1536; }
    const int c0 = (i % xt) * 32, r0 = (i / xt) * 32;
    const int tx = threadIdx.x, ty = threadIdx.y;
#pragma unroll
    for (int k = 0; k < 4; ++k)
        t[ty + k * 8][tx] = f2b(in[(size_t)(r0 + ty + k * 8) * C + c0 + tx]);
    __syncthreads();
#pragma unroll
    for (int k = 0; k < 4; ++k)
        out[(size_t)(c0 + ty + k * 8) * R + r0 + tx] = t[tx][ty + k * 8];
}

// ---------------------------------------------------------------------------
// transpose_v: vectorized batched bf16 transpose, in [z][R][C] -> out [z][C][R].
// Tile 32 rows x 64 cols, 256 threads. Global loads/stores are uint4 (16B).
// LDS [64][33] u16 (pad breaks power-of-2 strides). Bitwise copy.
// grid (C/64, R/32, nb).
// ---------------------------------------------------------------------------
__global__ __launch_bounds__(256) void transpose_v(
    const u16* __restrict__ in, u16* __restrict__ out, int R, int C)
{
    __shared__ u16 st[64][33];
    const u16* ip = in  + (size_t)blockIdx.z * R * C;
    u16*       op = out + (size_t)blockIdx.z * R * C;
    const int c0 = blockIdx.x * 64, r0 = blockIdx.y * 32;
    const int t = threadIdx.x;
    {
        const int row = t >> 3, ch = t & 7;       // 32 rows x 8 chunks
        uint4 v = *(const uint4*)&ip[(size_t)(r0 + row) * C + c0 + ch * 8];
        const u16* pv = (const u16*)&v;
#pragma unroll
        for (int k = 0; k < 8; ++k) st[ch * 8 + k][row] = pv[k];
    }
    __syncthreads();
    {
        const int oc = t >> 2, r4 = t & 3;        // 64 out-rows x 4 chunks
        uint4 v; u16* pv = (u16*)&v;
#pragma unroll
        for (int k = 0; k < 8; ++k) pv[k] = st[oc][r4 * 8 + k];
        *(uint4*)&op[(size_t)(c0 + oc) * R + r0 + r4 * 8] = v;
    }
}

// ---------------------------------------------------------------------------
// head: out[row,:] = log_softmax(o[row,:] @ W4 + b4). One wave per row,
// 4 rows per wave (16 rows/block) to amortize the W4 LDS staging.
// ---------------------------------------------------------------------------
__global__ __launch_bounds__(256) void head_logsoftmax(
    const u16* __restrict__ o, const float* __restrict__ W4,
    const float* __restrict__ b4, float* __restrict__ out)
{
    __shared__ float W4s[DIN * DOUT];
    __shared__ float b4s[DOUT];
    const int tid = threadIdx.x;
    for (int i = tid; i < DIN * DOUT; i += 256) W4s[i] = W4[i];
    if (tid < DOUT) b4s[tid] = b4[tid];
    __syncthreads();
    const int lane = tid & 63, w = tid >> 6;
    for (int rr = 0; rr < 4; ++rr) {
        const size_t row = (size_t)blockIdx.x * 16 + w * 4 + rr;
        const uint4 ov = *(const uint4*)&o[row * DIN + lane * 8];
        const u32* ou = (const u32*)&ov;
        float oc[8];
#pragma unroll
        for (int i = 0; i < 4; ++i) {
            oc[2*i]   = b2f((u16)(ou[i] & 0xFFFFu));
            oc[2*i+1] = b2f((u16)(ou[i] >> 16));
        }
        float acc[DOUT];
#pragma unroll
        for (int c = 0; c < DOUT; ++c) acc[c] = 0.f;
#pragma unroll
        for (int i = 0; i < 8; ++i) {
            int k = lane * 8 + i;
            float x = oc[i];
#pragma unroll
            for (int c = 0; c < DOUT; ++c) acc[c] += x * W4s[k * DOUT + c];
        }
#pragma unroll
        for (int off = 32; off >= 1; off >>= 1)
#pragma unroll
            for (int c = 0; c < DOUT; ++c) acc[c] += __shfl_xor(acc[c], off, 64);
        float mx = -1e30f;
#pragma unroll
        for (int c = 0; c < DOUT; ++c) { acc[c] += b4s[c]; mx = fmaxf(mx, acc[c]); }
        float sum = 0.f;
#pragma unroll
        for (int c = 0; c < DOUT; ++c) sum += __expf(acc[c] - mx);
        float lse = mx + logf(sum);
        if (lane == 0) {
#pragma unroll
            for (int c = 0; c < DOUT; ++c) out[row * DOUT + c] = acc[c] - lse;
        }
    }
}

// ---------------------------------------------------------------------------
extern "C" void kernel_launch(void* const* d_in, const int* in_sizes, int n_in,
                              void* d_out, int out_size, void* d_ws, size_t ws_size,
                              hipStream_t stream) {
    const float* x  = (const float*)d_in[0];
    const float* gv = (const float*)d_in[1];
    const float* uv = (const float*)d_in[2];
    const float* W1 = (const float*)d_in[3];
    const float* b1 = (const float*)d_in[4];
    const float* W2 = (const float*)d_in[5];
    const float* b2 = (const float*)d_in[6];
    const float* W3 = (const float*)d_in[7];
    const float* b3 = (const float*)d_in[8];
    const float* W4 = (const float*)d_in[9];
    const float* b4 = (const float*)d_in[10];
    float* out = (float*)d_out;

    char* ws = (char*)d_ws;
    const size_t MB64 = (size_t)67108864;
    const size_t MiB  = (size_t)1048576;
    const size_t TIER_A3 = 2 * MB64 + 80 * MiB + 4 * MiB;   // 212 MiB single-pass
    const size_t TIER_A2 = 2 * MB64 + 72 * MiB + 8 * MiB;   // 208 MiB gate
    const size_t TIER_B  = 3 * MB64 + 5 * MiB;              // 197 MiB

    if (ws_size >= TIER_A3) {
        // Single-pass, alias-packed layout:
        //  [0,64)    h1 (gemm1 out) -> hT (after gemm2)
        //  [64,128)  h  (gemm2 out) -> ctx (pv8 out, h dead after score8)
        //  [128,208) xb (dead after gemm1) -> P (80 MiB) -> o (gemm3 out)
        //  [208,212) W1t/W2t/W3t
        u16* h1  = (u16*)(ws);
        u16* hT  = h1;
        u16* h   = (u16*)(ws + MB64);
        u16* ctx = h;
        u16* xb  = (u16*)(ws + 2 * MB64);
        u16* P   = xb;
        u16* o   = xb;
        u16* W1t = (u16*)(ws + 2 * MB64 + 80 * MiB);
        u16* W2t = W1t + 512 * 1024;
        u16* W3t = W2t + 1024 * 1024;

        cvt_f32_bf16<<<8192, 256, 0, stream>>>(x, xb, 2097152);
        wprep<<<2048, dim3(32, 8), 0, stream>>>(W1, W2, W3, W1t, W2t, W3t);

        gemm8<<<dim3(128, 4), 512, 0, stream>>>(xb, W1t, b1, h1, 1024, 512, 1);
        gemm8<<<dim3(128, 4), 512, 0, stream>>>(h1, W2t, b2, h,  1024, 1024, 1);

        transpose_v<<<dim3(16, 64, 16), 256, 0, stream>>>(h, hT, 2048, 1024);
        score8<<<38 * 16, 512, 0, stream>>>(h, P, 16);    // 608 blocks, XCD swz
        softmax_rows<<<8192, 256, 0, stream>>>(P);
        pv8<<<32 * 16, 512, 0, stream>>>(P, hT, ctx, 16); // 512 blocks, LPT

        gemm8<<<dim3(128, 2), 512, 0, stream>>>(ctx, W3t, b3, o, 512, 1024, 1);
        head_logsoftmax<<<2048, 256, 0, stream>>>(o, W4, b4, out);
    } else if (ws_size >= TIER_A2) {
        u16* h1   = (u16*)(ws);
        u16* ctx  = h1;
        u16* h    = (u16*)(ws + MB64);
        u16* o    = h;
        u16* xb   = (u16*)(ws + 2 * MB64);
        u16* hT_c = xb;
        u16* P_c  = (u16*)(ws + 2 * MB64 + 32 * MiB);
        u16* W1t  = (u16*)(ws + 2 * MB64 + 72 * MiB);
        u16* W2t  = W1t + 512 * 1024;
        u16* W3t  = W2t + 1024 * 1024;

        cvt_f32_bf16<<<8192, 256, 0, stream>>>(x, xb, 2097152);
        wprep<<<2048, dim3(32, 8), 0, stream>>>(W1, W2, W3, W1t, W2t, W3t);

        gemm8<<<dim3(128, 4), 512, 0, stream>>>(xb, W1t, b1, h1, 1024, 512, 1);
        gemm8<<<dim3(128, 4), 512, 0, stream>>>(h1, W2t, b2, h,  1024, 1024, 1);

        for (int c = 0; c < 2; ++c) {
            const u16* hc  = h   + (size_t)c * 8 * S_ * DH;
            u16*       cxc = ctx + (size_t)c * 8 * S_ * DH;
            transpose_v<<<dim3(16, 64, 8), 256, 0, stream>>>(hc, hT_c, 2048, 1024);
            score8<<<38 * 8, 512, 0, stream>>>(hc, P_c, 8);
            softmax_rows<<<4096, 256, 0, stream>>>(P_c);
            pv_a<<<16 * 8 * 8, 256, 0, stream>>>(P_c, hT_c, cxc, 8);
        }

        gemm8<<<dim3(128, 2), 512, 0, stream>>>(ctx, W3t, b3, o, 512, 1024, 1);
        head_logsoftmax<<<2048, 256, 0, stream>>>(o, W4, b4, out);
    } else if (ws_size >= TIER_B) {
        u16* h1   = (u16*)(ws);
        u16* ctx  = h1;
        u16* h    = (u16*)(ws + MB64);
        u16* xb   = (u16*)(ws + 2 * MB64);
        u16* hT_c = xb;
        u16* P_c  = (u16*)(ws + 2 * MB64 + 16 * MiB);
        u16* o    = (u16*)(ws + 2 * MB64);
        u16* W1t  = (u16*)(ws + 3 * MB64);
        u16* W2t  = W1t + 512 * 1024;
        u16* W3t  = W2t + 1024 * 1024;

        cvt_f32_bf16<<<8192, 256, 0, stream>>>(x, xb, 2097152);
        wprep<<<2048, dim3(32, 8), 0, stream>>>(W1, W2, W3, W1t, W2t, W3t);

        gemm8<<<dim3(128, 4), 512, 0, stream>>>(xb, W1t, b1, h1, 1024, 512, 1);
        gemm8<<<dim3(128, 4), 512, 0, stream>>>(h1, W2t, b2, h,  1024, 1024, 1);

        for (int c = 0; c < 4; ++c) {
            const u16* hc  = h   + (size_t)c * 4 * S_ * DH;
            u16*       cxc = ctx + (size_t)c * 4 * S_ * DH;
            transpose_v<<<dim3(16, 64, 4), 256, 0, stream>>>(hc, hT_c, 2048, 1024);
            score8<<<38 * 4, 512, 0, stream>>>(hc, P_c, 4);
            softmax_rows<<<2048, 256, 0, stream>>>(P_c);
            pv_a<<<16 * 8 * 4, 256, 0, stream>>>(P_c, hT_c, cxc, 4);
        }

        gemm8<<<dim3(128, 2), 512, 0, stream>>>(ctx, W3t, b3, o, 512, 1024, 1);
        head_logsoftmax<<<2048, 256, 0, stream>>>(o, W4, b4, out);
    } else {
        u16* h    = (u16*)(ws);
        u16* hT_b = (u16*)(ws + MB64);
        u16* P_b  = (u16*)(ws + MB64 + 4 * MiB);
        u16* ctx_b= (u16*)(ws + MB64 + 12 * MiB);
        u16* o_b  = (u16*)(ws + MB64 + 16 * MiB);
        u16* W1t  = (u16*)(ws + MB64 + 18 * MiB);
        u16* W2t  = W1t + 512 * 1024;
        u16* W3t  = W2t + 1024 * 1024;
        u16* h1_b = P_b;

        wprep<<<2048, dim3(32, 8), 0, stream>>>(W1, W2, W3, W1t, W2t, W3t);

        for (int c = 0; c < 8; ++c) {
            const float* xc = x + (size_t)c * 4096 * DIN;
            u16*         hc = h + (size_t)c * 4096 * DH;
            gemm_bt_bias_relu<true ><<<dim3(32, 8), 256, 0, stream>>>(xc, W1t, b1, h1_b,
                                                                      4096, 1024, 512, 1);
            gemm_bt_bias_relu<false><<<dim3(32, 8), 256, 0, stream>>>(h1_b, W2t, b2, hc,
                                                                      4096, 1024, 1024, 1);
        }
        for (int b = 0; b < B_; ++b) {
            const u16* hb = h + (size_t)b * S_ * DH;
            transpose_v<<<dim3(16, 64, 1), 256, 0, stream>>>(hb, hT_b, 2048, 1024);
            score_a<<<dim3(16, 16, 1), 256, 0, stream>>>(hb, P_b);
            softmax_rows<<<512, 256, 0, stream>>>(P_b);
            pv_a<<<16 * 8, 256, 0, stream>>>(P_b, hT_b, ctx_b, 1);
            gemm_bt_bias_relu<false><<<dim3(16, 4), 256, 0, stream>>>(ctx_b, W3t, b3, o_b,
                                                                      2048, 512, 1024, 1);
            head_logsoftmax<<<128, 256, 0, stream>>>(o_b, W4, b4,
                                                     out + (size_t)b * S_ * DOUT);
        }
    }

    // pass-throughs (f32)
    size_t n_gv = (size_t)in_sizes[1], n_uv = (size_t)in_sizes[2];
    size_t o0 = (size_t)out_size - n_gv - n_uv;
    hipMemcpyAsync(out + o0,        gv, n_gv * 4, hipMemcpyDeviceToDevice, stream);
    hipMemcpyAsync(out + o0 + n_gv, uv, n_uv * 4, hipMemcpyDeviceToDevice, stream);
}

// Round 6
// 543.771 us; speedup vs baseline: 1.2552x; 1.0089x over previous
//
#include <hip/hip_runtime.h>
#include <stdint.h>

// Problem constants (fixed by reference)
#define B_   16
#define S_   2048
#define DIN  512
#define DH   1024
#define DOUT 10

typedef unsigned short u16;
typedef unsigned int   u32;

typedef __bf16 bf16_t;
typedef bf16_t bf16x8 __attribute__((ext_vector_type(8)));
typedef float  f32x4  __attribute__((ext_vector_type(4)));

#define MASKVAL (-3.0e4f)
// Packed-P geometry: row-block mi holds r4 = ((mi>>2)+1)*4 tiles of 128 cols.
// Tile-offset of row-block mi: S4(mi) = 4*(g+1)*(mi-2g), g = mi>>2.
// Pair property: rows [bi*256, bi*256+256) are CONTIGUOUS with lda = r4*128.
// Per-batch packed size = 160 tiles * 16384 u16 = 5 MiB.
// Pad tiles (ni > mi) are NEVER written by score8; softmax_rows synthesizes
// them (skip read, exp -> 0) and writes zeros there for pv to consume.
#define PZ_U16 ((size_t)160 * 16384)

__device__ __forceinline__ float b2f(u16 u) {
    union { u32 i; float f; } v; v.i = ((u32)u) << 16; return v.f;
}
__device__ __forceinline__ u16 f2b(float f) {
    union { float f; u32 i; } v; v.f = f;
    u32 u = v.i;
    u32 r = (u + 0x7FFFu + ((u >> 16) & 1u)) >> 16;  // RNE
    return (u16)r;
}
__device__ __forceinline__ u32 pack2(float a, float b) {
    return (u32)f2b(a) | ((u32)f2b(b) << 16);
}

__device__ __forceinline__ f32x4 mfma16(bf16x8 a, bf16x8 b, f32x4 c) {
    return __builtin_amdgcn_mfma_f32_16x16x32_bf16(a, b, c, 0, 0, 0);
}

// async global->LDS, 16B per lane; LDS dest = wave-uniform base + lane*16
__device__ __forceinline__ void load_lds16(const u16* g, u16* l) {
    __builtin_amdgcn_global_load_lds(
        (__attribute__((address_space(1))) u32*)(g),
        (__attribute__((address_space(3))) u32*)(l), 16, 0, 0);
}

// load 8 contiguous elements at element-index eidx as packed bf16x8 (uint4)
template<bool F32>
__device__ __forceinline__ uint4 ld8(const void* base, size_t eidx) {
    if constexpr (F32) {
        const float* p = (const float*)base + eidx;
        float4 f0 = *(const float4*)p;
        float4 f1 = *(const float4*)(p + 4);
        uint4 r;
        r.x = pack2(f0.x, f0.y); r.y = pack2(f0.z, f0.w);
        r.z = pack2(f1.x, f1.y); r.w = pack2(f1.z, f1.w);
        return r;
    } else {
        return *(const uint4*)((const u16*)base + eidx);
    }
}

// ---------------------------------------------------------------------------
// prep_all: fused input cvt (x f32->bf16, 8192 blocks) + weight prep
// (transpose+cvt W1/W2/W3, 2048 blocks). grid 10240 x 256.
// ---------------------------------------------------------------------------
__global__ __launch_bounds__(256) void prep_all(
    const float* __restrict__ x, u16* __restrict__ xb,
    const float* __restrict__ W1, const float* __restrict__ W2,
    const float* __restrict__ W3,
    u16* __restrict__ W1t, u16* __restrict__ W2t, u16* __restrict__ W3t)
{
    const int tid = threadIdx.x;
    if (blockIdx.x < 8192) {
        size_t e = ((size_t)blockIdx.x * 256 + tid) * 8;
        float4 f0 = *(const float4*)(x + e);
        float4 f1 = *(const float4*)(x + e + 4);
        uint4 r;
        r.x = pack2(f0.x, f0.y); r.y = pack2(f0.z, f0.w);
        r.z = pack2(f1.x, f1.y); r.w = pack2(f1.z, f1.w);
        *(uint4*)(xb + e) = r;
        return;
    }
    __shared__ u16 t[32][33];
    int i = blockIdx.x - 8192;
    const float* in; u16* out; int R, C, xt;
    if (i < 512)       { in = W1; out = W1t; R = 512;  C = 1024; xt = 32; }
    else if (i < 1536) { in = W2; out = W2t; R = 1024; C = 1024; xt = 32; i -= 512; }
    else               { in = W3; out = W3t; R = 1024; C = 512;  xt = 16; i -= 1536; }
    const int c0 = (i % xt) * 32, r0 = (i / xt) * 32;
    const int tx = tid & 31, ty = tid >> 5;
#pragma unroll
    for (int k = 0; k < 4; ++k)
        t[ty + k * 8][tx] = f2b(in[(size_t)(r0 + ty + k * 8) * C + c0 + tx]);
    __syncthreads();
#pragma unroll
    for (int k = 0; k < 4; ++k)
        out[(size_t)(c0 + ty + k * 8) * R + r0 + tx] = t[tx][ty + k * 8];
}

// wprep: standalone weight prep (tier-C). grid 2048 x (32,8).
__global__ __launch_bounds__(256) void wprep(
    const float* __restrict__ W1, const float* __restrict__ W2,
    const float* __restrict__ W3,
    u16* __restrict__ W1t, u16* __restrict__ W2t, u16* __restrict__ W3t)
{
    __shared__ u16 t[32][33];
    int i = blockIdx.x;
    const float* in; u16* out; int R, C, xt;
    if (i < 512)       { in = W1; out = W1t; R = 512;  C = 1024; xt = 32; }
    else if (i < 1536) { in = W2; out = W2t; R = 1024; C = 1024; xt = 32; i -= 512; }
    else               { in = W3; out = W3t; R = 1024; C = 512;  xt = 16; i -= 1536; }
    const int c0 = (i % xt) * 32, r0 = (i / xt) * 32;
    const int tx = threadIdx.x, ty = threadIdx.y;
#pragma unroll
    for (int k = 0; k < 4; ++k)
        t[ty + k * 8][tx] = f2b(in[(size_t)(r0 + ty + k * 8) * C + c0 + tx]);
    __syncthreads();
#pragma unroll
    for (int k = 0; k < 4; ++k)
        out[(size_t)(c0 + ty + k * 8) * R + r0 + tx] = t[tx][ty + k * 8];
}

// ===========================================================================
// 8-phase 256x256 machinery (T2 swizzle + T3/T4 counted vmcnt + T5 setprio).
// LDS: AS/BS[2 dbuf][256 rows][64 cols] bf16. Load-unit = 64 rows x 64 cols.
// Swizzle: linear slot (row, c) holds data chunk c ^ (row&7) (16B chunks);
// write side pre-swizzles the global source chunk, read side XORs the chunk.
// ===========================================================================
template<int QR>
__device__ __forceinline__ void rda(bf16x8 (&a)[4][2], const u16* T,
                                    int arow, int quad) {
#pragma unroll
    for (int mf = 0; mf < 4; ++mf) {
        const int row = arow + QR * 64 + mf * 16;
        const int sw = row & 7;
#pragma unroll
        for (int ks = 0; ks < 2; ++ks)
            a[mf][ks] = *(const bf16x8*)(T + row * 64 + (((ks * 4 + quad) ^ sw) << 3));
    }
}

template<int QC>
__device__ __forceinline__ void rdb(bf16x8 (&b)[2][2], const u16* T,
                                    int brow, int quad) {
#pragma unroll
    for (int nf = 0; nf < 2; ++nf) {
        const int row = brow + QC * 128 + nf * 16;
        const int sw = row & 7;
#pragma unroll
        for (int ks = 0; ks < 2; ++ks)
            b[nf][ks] = *(const bf16x8*)(T + row * 64 + (((ks * 4 + quad) ^ sw) << 3));
    }
}

template<int QR, int QC>
__device__ __forceinline__ void mmq(f32x4 (&acc)[2][2][4][2],
                                    const bf16x8 (&a)[4][2],
                                    const bf16x8 (&b)[2][2]) {
#pragma unroll
    for (int ks = 0; ks < 2; ++ks)
#pragma unroll
        for (int mf = 0; mf < 4; ++mf)
#pragma unroll
            for (int nf = 0; nf < 2; ++nf)
                acc[QR][QC][mf][nf] = mfma16(a[mf][ks], b[nf][ks], acc[QR][QC][mf][nf]);
}

#define G8BAR()  __builtin_amdgcn_s_barrier()
#define G8LGKM() do { asm volatile("s_waitcnt lgkmcnt(0)" ::: "memory"); \
                      __builtin_amdgcn_sched_barrier(0); } while (0)
#define G8VMC4() asm volatile("s_waitcnt vmcnt(4)" ::: "memory")

// The 8-phase K-loop body, parameterized on staging macros STGA/STGB.
// Phases P1-P4 consume buf0 (quadrants (0,0),(0,1),(1,0),(1,1)), P5-P8 buf1.
// Stage stream (2 units/phase), each unit staged >=1 end-barrier after its
// last reader retired; vmcnt(4) ONLY at P4/P8 end.
#define G8_LOOP_BODY(NT_)                                                     \
    const int NI = (NT_) >> 1;                                                \
    for (int i = 0; i < NI; ++i) {                                            \
        const int t1 = 2 * i + 1, t2 = 2 * i + 2, t3 = 2 * i + 3;             \
        rda<0>(a, AS_[0], arow, quad); rdb<0>(b0r, BS_[0], brow, quad);       \
        STGB(1, 2, t1); STGB(1, 3, t1);                                       \
        G8BAR(); G8LGKM();                                                    \
        __builtin_amdgcn_s_setprio(1); mmq<0, 0>(acc, a, b0r);                \
        __builtin_amdgcn_s_setprio(0); G8BAR();                               \
        rdb<1>(b1r, BS_[0], brow, quad);                                      \
        STGA(1, 1, t1); STGA(1, 3, t1);                                       \
        G8BAR(); G8LGKM();                                                    \
        __builtin_amdgcn_s_setprio(1); mmq<0, 1>(acc, a, b1r);                \
        __builtin_amdgcn_s_setprio(0); G8BAR();                               \
        rda<1>(a, AS_[0], arow, quad);                                        \
        if (t2 < (NT_)) { STGA(0, 0, t2); STGA(0, 2, t2); }                   \
        G8BAR(); G8LGKM();                                                    \
        __builtin_amdgcn_s_setprio(1); mmq<1, 0>(acc, a, b0r);                \
        __builtin_amdgcn_s_setprio(0); G8BAR();                               \
        if (t2 < (NT_)) { STGB(0, 0, t2); STGB(0, 1, t2); }                   \
        G8BAR();                                                              \
        __builtin_amdgcn_s_setprio(1); mmq<1, 1>(acc, a, b1r);                \
        __builtin_amdgcn_s_setprio(0);                                        \
        G8VMC4(); G8BAR();                                                    \
        rda<0>(a, AS_[1], arow, quad); rdb<0>(b0r, BS_[1], brow, quad);       \
        if (t2 < (NT_)) { STGB(0, 2, t2); STGB(0, 3, t2); }                   \
        G8BAR(); G8LGKM();                                                    \
        __builtin_amdgcn_s_setprio(1); mmq<0, 0>(acc, a, b0r);                \
        __builtin_amdgcn_s_setprio(0); G8BAR();                               \
        rdb<1>(b1r, BS_[1], brow, quad);                                      \
        if (t2 < (NT_)) { STGA(0, 1, t2); STGA(0, 3, t2); }                   \
        G8BAR(); G8LGKM();                                                    \
        __builtin_amdgcn_s_setprio(1); mmq<0, 1>(acc, a, b1r);                \
        __builtin_amdgcn_s_setprio(0); G8BAR();                               \
        rda<1>(a, AS_[1], arow, quad);                                        \
        if (t3 < (NT_)) { STGA(1, 0, t3); STGA(1, 2, t3); }                   \
        G8BAR(); G8LGKM();                                                    \
        __builtin_amdgcn_s_setprio(1); mmq<1, 0>(acc, a, b0r);                \
        __builtin_amdgcn_s_setprio(0); G8BAR();                               \
        if (t3 < (NT_)) { STGB(1, 0, t3); STGB(1, 1, t3); }                   \
        G8BAR();                                                              \
        __builtin_amdgcn_s_setprio(1); mmq<1, 1>(acc, a, b1r);                \
        __builtin_amdgcn_s_setprio(0);                                        \
        G8VMC4(); G8BAR();                                                    \
    }

// common per-thread decomposition + acc init for the 8-phase kernels
#define G8_SETUP()                                                            \
    const int tid  = threadIdx.x;                                             \
    const int lane = tid & 63;                                                \
    const int w    = tid >> 6;                                                \
    const int wm   = w >> 2, wn = w & 3;                                      \
    const int quad = lane >> 4, l15 = lane & 15;                              \
    const int rg = tid >> 3;                                                  \
    const int ch = (lane & 7) ^ ((lane >> 3) & 7);                            \
    const int wslot = w * 512;                                                \
    f32x4 acc[2][2][4][2];                                                    \
    _Pragma("unroll") for (int p_ = 0; p_ < 2; ++p_)                          \
    _Pragma("unroll") for (int q_ = 0; q_ < 2; ++q_)                          \
    _Pragma("unroll") for (int m_ = 0; m_ < 4; ++m_)                          \
    _Pragma("unroll") for (int n_ = 0; n_ < 2; ++n_)                          \
        acc[p_][q_][m_][n_] = (f32x4){0.f, 0.f, 0.f, 0.f};                    \
    bf16x8 a[4][2], b0r[2][2], b1r[2][2];                                     \
    const int arow = wm * 128 + l15;                                          \
    const int brow = wn * 32 + l15;

#define G8_PROLOGUE()                                                         \
    STGA(0, 0, 0); STGA(0, 1, 0); STGA(0, 2, 0); STGA(0, 3, 0);               \
    STGB(0, 0, 0); STGB(0, 1, 0); STGB(0, 2, 0); STGB(0, 3, 0);               \
    STGA(1, 0, 1); STGA(1, 2, 1);                                             \
    STGB(1, 0, 1); STGB(1, 1, 1);                                             \
    G8VMC4(); G8BAR();

// ===========================================================================
// gemm8: C[M,N] = relu(A[M,K] @ Bt[N,K]^T + bias[N]), bf16.
// grid = (M/256, N/256), block = 512. Requires K % 128 == 0.
// ===========================================================================
__global__ __launch_bounds__(512, 2) void gemm8(
    const u16* __restrict__ A, const u16* __restrict__ Bt,
    const float* __restrict__ bias, u16* __restrict__ C,
    int N, int K, int do_relu)
{
    __shared__ __attribute__((aligned(16))) u16 AS_[2][16384];
    __shared__ __attribute__((aligned(16))) u16 BS_[2][16384];

    G8_SETUP()
    const int m0 = blockIdx.x * 256, n0 = blockIdx.y * 256;
    const u16* gA = A  + (size_t)(m0 + rg) * K + ch * 8;
    const u16* gB = Bt + (size_t)(n0 + rg) * K + ch * 8;

#define STGA(BUF, U, T) load_lds16(gA + (size_t)(U) * 64 * K + (T) * 64, \
                                   &AS_[BUF][(U) * 4096 + wslot])
#define STGB(BUF, U, T) load_lds16(gB + (size_t)(U) * 64 * K + (T) * 64, \
                                   &BS_[BUF][(U) * 4096 + wslot])

    const int NT = K >> 6;
    G8_PROLOGUE()
    G8_LOOP_BODY(NT)
#undef STGA
#undef STGB

    // epilogue: bias + relu + bf16 store
    const int r0 = quad * 4;
#pragma unroll
    for (int qc = 0; qc < 2; ++qc)
#pragma unroll
    for (int nf = 0; nf < 2; ++nf) {
        const int col = n0 + qc * 128 + wn * 32 + nf * 16 + l15;
        const float bv = bias[col];
#pragma unroll
        for (int qr = 0; qr < 2; ++qr)
#pragma unroll
        for (int mf = 0; mf < 4; ++mf) {
            const int rowb = m0 + wm * 128 + qr * 64 + mf * 16 + r0;
#pragma unroll
            for (int r = 0; r < 4; ++r) {
                float v = acc[qr][qc][mf][nf][r] + bv;
                if (do_relu) v = fmaxf(v, 0.f);
                C[(size_t)(rowb + r) * N + col] = f2b(v);
            }
        }
    }
}

// ===========================================================================
// gemm8t: gemm8 (relu fixed on) + fused transposed epilogue.
// Writes C[M,N] row-major AND CT = [z][N][2048] (z = row/2048) so the
// separate transpose kernel is eliminated. CT bits == f2b values == C bits.
// After the K-loop: vmcnt(0)+barrier drains tail global_load_lds before the
// LDS is reused as the 256x256 transpose staging buffer (exactly 128 KiB).
// ===========================================================================
__global__ __launch_bounds__(512, 2) void gemm8t(
    const u16* __restrict__ A, const u16* __restrict__ Bt,
    const float* __restrict__ bias, u16* __restrict__ C,
    u16* __restrict__ CT, int N, int K)
{
    __shared__ __attribute__((aligned(16))) u16 SM[65536];
    u16* const AS_[2] = {SM, SM + 16384};
    u16* const BS_[2] = {SM + 32768, SM + 49152};

    G8_SETUP()
    const int m0 = blockIdx.x * 256, n0 = blockIdx.y * 256;
    const u16* gA = A  + (size_t)(m0 + rg) * K + ch * 8;
    const u16* gB = Bt + (size_t)(n0 + rg) * K + ch * 8;

#define STGA(BUF, U, T) load_lds16(gA + (size_t)(U) * 64 * K + (T) * 64, \
                                   &AS_[BUF][(U) * 4096 + wslot])
#define STGB(BUF, U, T) load_lds16(gB + (size_t)(U) * 64 * K + (T) * 64, \
                                   &BS_[BUF][(U) * 4096 + wslot])

    const int NT = K >> 6;
    G8_PROLOGUE()
    G8_LOOP_BODY(NT)
#undef STGA
#undef STGB

    // drain in-flight global_load_lds (tail tiles) before LDS reuse
    asm volatile("s_waitcnt vmcnt(0)" ::: "memory");
    G8BAR();

    // C store + LDS transpose staging. Logical (row,col) lives at
    // SM[col*256 + (((row>>3) ^ (col&31))<<3) + (row&7)]  (8-u16 chunk XOR
    // swizzle breaks the 512B column stride).
    const int r0 = quad * 4;
#pragma unroll
    for (int qc = 0; qc < 2; ++qc)
#pragma unroll
    for (int nf = 0; nf < 2; ++nf) {
        const int cl  = qc * 128 + wn * 32 + nf * 16 + l15;
        const int col = n0 + cl;
        const float bv = bias[col];
#pragma unroll
        for (int qr = 0; qr < 2; ++qr)
#pragma unroll
        for (int mf = 0; mf < 4; ++mf) {
            const int rl   = wm * 128 + qr * 64 + mf * 16 + r0;
            const int rowb = m0 + rl;
            u16 b0 = f2b(fmaxf(acc[qr][qc][mf][nf][0] + bv, 0.f));
            u16 b1 = f2b(fmaxf(acc[qr][qc][mf][nf][1] + bv, 0.f));
            u16 b2 = f2b(fmaxf(acc[qr][qc][mf][nf][2] + bv, 0.f));
            u16 b3 = f2b(fmaxf(acc[qr][qc][mf][nf][3] + bv, 0.f));
            C[(size_t)(rowb + 0) * N + col] = b0;
            C[(size_t)(rowb + 1) * N + col] = b1;
            C[(size_t)(rowb + 2) * N + col] = b2;
            C[(size_t)(rowb + 3) * N + col] = b3;
            const int rc  = rl >> 3;           // rl%8 in {0,4}: 4 elems stay in chunk
            const int off = cl * 256 + ((rc ^ (cl & 31)) << 3) + (rl & 7);
            uint2 wv; wv.x = (u32)b0 | ((u32)b1 << 16);
            wv.y = (u32)b2 | ((u32)b3 << 16);
            *(uint2*)&SM[off] = wv;
        }
    }
    __syncthreads();

    // CT stores: thread t -> out-row oc = t>>1, half = t&1; 16x dwordx4.
    const int z  = m0 >> 11;
    const int rz = m0 & 2047;
    u16* CTz = CT + (size_t)z * DH * S_;
    const int oc   = tid >> 1;
    const int half = tid & 1;
#pragma unroll
    for (int it = 0; it < 16; ++it) {
        const int r   = half * 128 + it * 8;
        const int rc  = r >> 3;
        const int off = oc * 256 + ((rc ^ (oc & 31)) << 3);
        uint4 v = *(const uint4*)&SM[off];
        *(uint4*)&CTz[(size_t)(n0 + oc) * S_ + rz + r] = v;
    }
}

// ===========================================================================
// score8: causal score GEMM on the 8-phase 256x256 template, writing packed P.
// grid = 36*nb. Logical l = z*36 + t -> triangular (bi,bj), bj <= bi.
// XCD swizzle (T1, when nb%8==0): p -> xcd=p&7, slot=p>>3, z=(slot/36)*8+xcd,
// t=slot%36: all 36 blocks of a z land on ONE XCD (4MB h-panel fits its L2).
// Pad tiles are NOT written (softmax synthesizes them).
// ===========================================================================
__global__ __launch_bounds__(512, 2) void score8(
    const u16* __restrict__ h, u16* __restrict__ P, int nbb)
{
    __shared__ __attribute__((aligned(16))) u16 AS_[2][16384];
    __shared__ __attribute__((aligned(16))) u16 BS_[2][16384];

    int z, t;
    if ((nbb & 7) == 0) {
        const int xcd = blockIdx.x & 7, slot = blockIdx.x >> 3;
        z = (slot / 36) * 8 + xcd;
        t = slot % 36;
    } else {
        z = blockIdx.x / 36;
        t = blockIdx.x % 36;
    }

    int bi = 0;
    while ((bi + 1) * (bi + 2) / 2 <= t) ++bi;
    const int bj = t - bi * (bi + 1) / 2;
    const bool diag = (bi == bj);

    G8_SETUP()
    const int m0 = bi * 256, n0 = bj * 256;
    const u16* hz = h + (size_t)z * S_ * DH;
    const u16* gA = hz + (size_t)(m0 + rg) * DH + ch * 8;
    const u16* gB = hz + (size_t)(n0 + rg) * DH + ch * 8;

#define STGA(BUF, U, T) load_lds16(gA + (size_t)(U) * 64 * DH + (T) * 64, \
                                   &AS_[BUF][(U) * 4096 + wslot])
#define STGB(BUF, U, T) load_lds16(gB + (size_t)(U) * 64 * DH + (T) * 64, \
                                   &BS_[BUF][(U) * 4096 + wslot])

    const int NT = DH >> 6;      // 16
    G8_PROLOGUE()
    G8_LOOP_BODY(NT)
#undef STGA
#undef STGB

    // epilogue: scatter into packed P with causal mask on diagonal blocks.
    const int mi = 2 * bi + wm;
    const int g  = mi >> 2;
    u16* Pz = P + (size_t)z * PZ_U16
                + (size_t)(4 * (g + 1) * (mi - 2 * g)) * 16384;
    const size_t rstride = (size_t)(4 * (g + 1)) * 128;

    const int r0 = quad * 4;
#pragma unroll
    for (int qc = 0; qc < 2; ++qc) {
        const int ni = 2 * bj + qc;
#pragma unroll
        for (int nf = 0; nf < 2; ++nf) {
            const int cl = wn * 32 + nf * 16 + l15;
            const int colg = n0 + qc * 128 + cl;
#pragma unroll
            for (int qr = 0; qr < 2; ++qr)
#pragma unroll
            for (int mf = 0; mf < 4; ++mf) {
                const int rl = qr * 64 + mf * 16 + r0;
                const int rowg = m0 + wm * 128 + rl;
#pragma unroll
                for (int r = 0; r < 4; ++r) {
                    float v = acc[qr][qc][mf][nf][r];
                    if (diag && colg > rowg + r) v = MASKVAL;
                    Pz[(size_t)(rl + r) * rstride + ni * 128 + cl] = f2b(v);
                }
            }
        }
    }
}

// ===========================================================================
// pv8: ctx[z] = P[z] @ V[z] on the 8-phase 256x256 template.
// Packed-P pair-contiguity: rows [bi*256, bi*256+256) form a dense row-major
// matrix with lda = K = ((bi>>1)+1)*512. Pad tiles hold exact zeros (written
// by softmax) -> including them is bitwise-identical to skipping.
// grid.x = nb*32, LPT: bi = 7 - idx/(4*nb); rem: nj = rem&3, z = rem>>2.
// ===========================================================================
__global__ __launch_bounds__(512, 2) void pv8(
    const u16* __restrict__ P, const u16* __restrict__ hT,
    u16* __restrict__ ctx, int nb)
{
    __shared__ __attribute__((aligned(16))) u16 AS_[2][16384];
    __shared__ __attribute__((aligned(16))) u16 BS_[2][16384];

    const int per_bi = 4 * nb;
    const int bi  = 7 - (int)(blockIdx.x / per_bi);  // LPT heavy-first
    const int rem = blockIdx.x % per_bi;
    const int nj  = rem & 3;
    const int z   = rem >> 2;

    const int g  = bi >> 1;
    const int K  = (g + 1) * 512;                // = r4*128 = lda
    const int NT = K >> 6;                       // 8/16/24/32 (all even)
    const int n0 = nj * 256;

    const u16* Az = P + (size_t)z * PZ_U16
                      + (size_t)(4 * (g + 1) * (2 * bi - 2 * g)) * 16384;
    const u16* Bz = hT + (size_t)z * DH * S_;
    u16*       C  = ctx + (size_t)z * S_ * DH;

    G8_SETUP()
    const u16* gA = Az + (size_t)rg * K + ch * 8;
    const u16* gB = Bz + (size_t)(n0 + rg) * S_ + ch * 8;

#define STGA(BUF, U, T) load_lds16(gA + (size_t)(U) * 64 * K + (T) * 64, \
                                   &AS_[BUF][(U) * 4096 + wslot])
#define STGB(BUF, U, T) load_lds16(gB + (size_t)(U) * 64 * S_ + (T) * 64, \
                                   &BS_[BUF][(U) * 4096 + wslot])

    G8_PROLOGUE()
    G8_LOOP_BODY(NT)
#undef STGA
#undef STGB

    // epilogue: plain bf16 store into ctx
    const int r0 = quad * 4;
#pragma unroll
    for (int qc = 0; qc < 2; ++qc)
#pragma unroll
    for (int nf = 0; nf < 2; ++nf) {
        const int col = n0 + qc * 128 + wn * 32 + nf * 16 + l15;
#pragma unroll
        for (int qr = 0; qr < 2; ++qr)
#pragma unroll
        for (int mf = 0; mf < 4; ++mf) {
            const int rowb = bi * 256 + wm * 128 + qr * 64 + mf * 16 + r0;
#pragma unroll
            for (int r = 0; r < 4; ++r)
                C[(size_t)(rowb + r) * DH + col] = f2b(acc[qr][qc][mf][nf][r]);
        }
    }
}

// ---------------------------------------------------------------------------
// ASYNC score GEMM into PACKED P (tier-C fallback): row-block mi = causal
// tiles ni<=mi, padded to r4 tiles; pad tiles get MASKVAL. grid (16, 16, nb).
// ---------------------------------------------------------------------------
__global__ __launch_bounds__(256) void score_a(
    const u16* __restrict__ h, u16* __restrict__ P)
{
    __shared__ __attribute__((aligned(16))) u16 As[128 * 32];
    __shared__ __attribute__((aligned(16))) u16 Bs[128 * 32];

    const int mi = 15 - blockIdx.x;              // LPT: heavy rows first
    const int ni = blockIdx.y;
    const int g  = mi >> 2;
    const int r4 = (g + 1) * 4;
    if (ni >= r4) return;

    const int tid = threadIdx.x;
    u16* Pz = P + (size_t)blockIdx.z * PZ_U16
                + (size_t)(4 * (g + 1) * (mi - 2 * g)) * 16384;
    const size_t rstride = (size_t)r4 * 128;

    if (ni > mi) {                               // pad tile: MASKVAL fill
        const u16 mb = f2b(MASKVAL);
        const u32 m2 = (u32)mb | ((u32)mb << 16);
        uint4 mv; mv.x = m2; mv.y = m2; mv.z = m2; mv.w = m2;
#pragma unroll
        for (int i = 0; i < 8; ++i) {
            int q = tid + i * 256;
            int row = q >> 4, cl = (q & 15) * 8;
            *(uint4*)&Pz[(size_t)row * rstride + ni * 128 + cl] = mv;
        }
        return;
    }

    const int m0 = mi * 128, n0 = ni * 128;
    const u16* A = h + (size_t)blockIdx.z * S_ * DH;

    const int lane = tid & 63;
    const int w    = tid >> 6;
    const int wm   = w >> 1, wn = w & 1;
    const int quad = lane >> 4, l15 = lane & 15;

    const int c0 = tid, c1 = tid + 256;
    const u16* gA0 = A + ((size_t)(m0 + (c0 >> 2)) * DH + (c0 & 3) * 8);
    const u16* gA1 = A + ((size_t)(m0 + (c1 >> 2)) * DH + (c1 & 3) * 8);
    const u16* gB0 = A + ((size_t)(n0 + (c0 >> 2)) * DH + (c0 & 3) * 8);
    const u16* gB1 = A + ((size_t)(n0 + (c1 >> 2)) * DH + (c1 & 3) * 8);
    u16* lA0 = &As[(w * 64) * 8];
    u16* lA1 = &As[(256 + w * 64) * 8];
    u16* lB0 = &Bs[(w * 64) * 8];
    u16* lB1 = &Bs[(256 + w * 64) * 8];

    f32x4 acc[4][4];
#pragma unroll
    for (int i = 0; i < 4; ++i)
#pragma unroll
        for (int j = 0; j < 4; ++j) acc[i][j] = (f32x4){0.f, 0.f, 0.f, 0.f};

    const int nk = DH >> 5;
    for (int kk = 0; kk < nk; ++kk) {
        load_lds16(gA0, lA0); load_lds16(gA1, lA1);
        load_lds16(gB0, lB0); load_lds16(gB1, lB1);
        gA0 += 32; gA1 += 32; gB0 += 32; gB1 += 32;
        __syncthreads();
        bf16x8 af[4], bfr[4];
#pragma unroll
        for (int i = 0; i < 4; ++i)
            af[i] = *(const bf16x8*)&As[(wm * 64 + i * 16 + l15) * 32 + quad * 8];
#pragma unroll
        for (int j = 0; j < 4; ++j)
            bfr[j] = *(const bf16x8*)&Bs[(wn * 64 + j * 16 + l15) * 32 + quad * 8];
#pragma unroll
        for (int i = 0; i < 4; ++i)
#pragma unroll
            for (int j = 0; j < 4; ++j)
                acc[i][j] = mfma16(af[i], bfr[j], acc[i][j]);
        __syncthreads();
    }

    const int r0 = quad * 4;
#pragma unroll
    for (int j = 0; j < 4; ++j) {
        int cl = wn * 64 + j * 16 + l15;
#pragma unroll
        for (int i = 0; i < 4; ++i) {
            int rl = wm * 64 + i * 16 + r0;
#pragma unroll
            for (int r = 0; r < 4; ++r) {
                int row = rl + r;
                float v = (n0 + cl <= m0 + row) ? acc[i][j][r] : MASKVAL;
                Pz[(size_t)row * rstride + ni * 128 + cl] = f2b(v);
            }
        }
    }
}

// ---------------------------------------------------------------------------
// softmax_rows: in-place row softmax of packed P. One wave per row.
// Pad tiles (ni > mi) are SYNTHESIZED: no read (v = MASKVAL -> exp = 0.0f,
// identical bits to reading a stored MASKVAL), but zeros ARE written so
// pv8/pv_a can read them. Row max >= diagonal >= 0 > MASKVAL always.
// ---------------------------------------------------------------------------
__global__ __launch_bounds__(256) void softmax_rows(u16* __restrict__ P)
{
    const int tid = threadIdx.x;
    const int lane = tid & 63, w = tid >> 6;
    const int quad = lane >> 4;
    const size_t row = (size_t)blockIdx.x * 4 + w;
    const int z    = (int)(row >> 11);
    const int rloc = (int)(row & (S_ - 1));
    const int mi = rloc >> 7, g = mi >> 2;
    const int kb = g + 1;
    u16* p = P + (size_t)z * PZ_U16
               + (size_t)(4 * (g + 1) * (mi - 2 * g)) * 16384
               + (size_t)(rloc & 127) * ((g + 1) * 4 * 128);
    float v[32];
    float m = -1e30f;
    for (int k = 0; k < kb; ++k) {
        if (k * 4 + quad <= mi) {                // real tile for this lane
            uint4 u = *(const uint4*)&p[k * 512 + lane * 8];
            const u32* uu = (const u32*)&u;
#pragma unroll
            for (int i = 0; i < 4; ++i) {
                float a = b2f((u16)(uu[i] & 0xFFFFu));
                float b = b2f((u16)(uu[i] >> 16));
                v[k * 8 + 2 * i] = a; v[k * 8 + 2 * i + 1] = b;
                m = fmaxf(m, fmaxf(a, b));
            }
        } else {                                 // pad tile: synthesize
#pragma unroll
            for (int i = 0; i < 8; ++i) v[k * 8 + i] = MASKVAL;
        }
    }
#pragma unroll
    for (int off = 32; off >= 1; off >>= 1) m = fmaxf(m, __shfl_xor(m, off, 64));
    float s = 0.f;
    for (int k = 0; k < kb; ++k)
#pragma unroll
        for (int i = 0; i < 8; ++i) {
            float e = __expf(v[k * 8 + i] - m);
            v[k * 8 + i] = e; s += e;
        }
#pragma unroll
    for (int off = 32; off >= 1; off >>= 1) s += __shfl_xor(s, off, 64);
    float inv = 1.0f / s;
    for (int k = 0; k < kb; ++k) {
        uint4 u; u32* uu = (u32*)&u;
#pragma unroll
        for (int i = 0; i < 4; ++i)
            uu[i] = pack2(v[k * 8 + 2 * i] * inv, v[k * 8 + 2 * i + 1] * inv);
        *(uint4*)&p[k * 512 + lane * 8] = u;
    }
}

// ---------------------------------------------------------------------------
// ASYNC pv GEMM (128x128 tile, A2/B/C fallback), LPT 1D grid.
// grid.x = 16*8*nb; idx -> mi = 15 - idx/(8*nb); sub = idx%(8*nb):
// n = sub&7, z = sub>>3. nk = (mi+1)*4.
// ---------------------------------------------------------------------------
__global__ __launch_bounds__(256) void pv_a(
    const u16* __restrict__ P, const u16* __restrict__ hT, u16* __restrict__ ctx,
    int nb)
{
    __shared__ __attribute__((aligned(16))) u16 As[128 * 32];
    __shared__ __attribute__((aligned(16))) u16 Bs[128 * 32];

    const int idx = blockIdx.x;
    const int per_mi = 8 * nb;
    const int mi = 15 - (idx / per_mi);          // LPT: heavy row-blocks first
    const int sub = idx % per_mi;
    const int nblk = sub & 7;
    const int z    = sub >> 3;
    const int g = mi >> 2;
    const int m0 = mi * 128;
    const int n0 = nblk * 128;
    const size_t rstride = (size_t)((g + 1) * 4) * 128;
    const u16* A  = P  + (size_t)z * PZ_U16
                       + (size_t)(4 * (g + 1) * (mi - 2 * g)) * 16384;
    const u16* Bt = hT + (size_t)z * DH * S_;
    u16*      C   = ctx + (size_t)z * S_ * DH;

    const int tid  = threadIdx.x;
    const int lane = tid & 63;
    const int w    = tid >> 6;
    const int wm   = w >> 1, wn = w & 1;
    const int quad = lane >> 4, l15 = lane & 15;

    const int c0 = tid, c1 = tid + 256;
    const u16* gA0 = A  + ((size_t)(c0 >> 2) * rstride + (c0 & 3) * 8);
    const u16* gA1 = A  + ((size_t)(c1 >> 2) * rstride + (c1 & 3) * 8);
    const u16* gB0 = Bt + ((size_t)(n0 + (c0 >> 2)) * S_ + (c0 & 3) * 8);
    const u16* gB1 = Bt + ((size_t)(n0 + (c1 >> 2)) * S_ + (c1 & 3) * 8);
    u16* lA0 = &As[(w * 64) * 8];
    u16* lA1 = &As[(256 + w * 64) * 8];
    u16* lB0 = &Bs[(w * 64) * 8];
    u16* lB1 = &Bs[(256 + w * 64) * 8];

    f32x4 acc[4][4];
#pragma unroll
    for (int i = 0; i < 4; ++i)
#pragma unroll
        for (int j = 0; j < 4; ++j) acc[i][j] = (f32x4){0.f, 0.f, 0.f, 0.f};

    const int nk = (mi + 1) * 4;
    for (int kk = 0; kk < nk; ++kk) {
        load_lds16(gA0, lA0); load_lds16(gA1, lA1);
        load_lds16(gB0, lB0); load_lds16(gB1, lB1);
        gA0 += 32; gA1 += 32; gB0 += 32; gB1 += 32;
        __syncthreads();
        bf16x8 af[4], bfr[4];
#pragma unroll
        for (int i = 0; i < 4; ++i)
            af[i] = *(const bf16x8*)&As[(wm * 64 + i * 16 + l15) * 32 + quad * 8];
#pragma unroll
        for (int j = 0; j < 4; ++j)
            bfr[j] = *(const bf16x8*)&Bs[(wn * 64 + j * 16 + l15) * 32 + quad * 8];
#pragma unroll
        for (int i = 0; i < 4; ++i)
#pragma unroll
            for (int j = 0; j < 4; ++j)
                acc[i][j] = mfma16(af[i], bfr[j], acc[i][j]);
        __syncthreads();
    }

    const int r0 = quad * 4;
#pragma unroll
    for (int j = 0; j < 4; ++j) {
        int col = n0 + wn * 64 + j * 16 + l15;
#pragma unroll
        for (int i = 0; i < 4; ++i) {
            int rowb = m0 + wm * 64 + i * 16 + r0;
#pragma unroll
            for (int r = 0; r < 4; ++r)
                C[(size_t)(rowb + r) * DH + col] = f2b(acc[i][j][r]);
        }
    }
}

// ---------------------------------------------------------------------------
// SYNC-staged GEMM (tier-C fallback only; A may be f32)
// ---------------------------------------------------------------------------
template<bool AF32>
__global__ __launch_bounds__(256) void gemm_bt_bias_relu(
    const void* __restrict__ A, const u16* __restrict__ Bt,
    const float* __restrict__ bias, u16* __restrict__ C,
    int M, int N, int K, int do_relu)
{
    __shared__ __attribute__((aligned(16))) u16 As[128 * 32];
    __shared__ __attribute__((aligned(16))) u16 Bs[128 * 32];

    const int tid  = threadIdx.x;
    const int lane = tid & 63;
    const int w    = tid >> 6;
    const int wm   = w >> 1, wn = w & 1;
    const int quad = lane >> 4, l15 = lane & 15;

    const int m0 = blockIdx.x * 128;
    const int n0 = blockIdx.y * 128;

    const int c0 = tid, c1 = tid + 256;
    size_t eA0 = (size_t)(m0 + (c0 >> 2)) * K + (c0 & 3) * 8;
    size_t eA1 = (size_t)(m0 + (c1 >> 2)) * K + (c1 & 3) * 8;
    size_t eB0 = (size_t)(n0 + (c0 >> 2)) * K + (c0 & 3) * 8;
    size_t eB1 = (size_t)(n0 + (c1 >> 2)) * K + (c1 & 3) * 8;

    f32x4 acc[4][4];
#pragma unroll
    for (int i = 0; i < 4; ++i)
#pragma unroll
        for (int j = 0; j < 4; ++j) acc[i][j] = (f32x4){0.f, 0.f, 0.f, 0.f};

    uint4 va0 = ld8<AF32>(A, eA0), va1 = ld8<AF32>(A, eA1);
    uint4 vb0 = ld8<false>(Bt, eB0), vb1 = ld8<false>(Bt, eB1);

    const int nk = K >> 5;
    for (int kk = 0; kk < nk; ++kk) {
        __syncthreads();
        *(uint4*)&As[c0 * 8] = va0;
        *(uint4*)&As[c1 * 8] = va1;
        *(uint4*)&Bs[c0 * 8] = vb0;
        *(uint4*)&Bs[c1 * 8] = vb1;
        if (kk + 1 < nk) {
            eA0 += 32; eA1 += 32; eB0 += 32; eB1 += 32;
            va0 = ld8<AF32>(A, eA0); va1 = ld8<AF32>(A, eA1);
            vb0 = ld8<false>(Bt, eB0); vb1 = ld8<false>(Bt, eB1);
        }
        __syncthreads();
        bf16x8 af[4], bfr[4];
#pragma unroll
        for (int i = 0; i < 4; ++i)
            af[i] = *(const bf16x8*)&As[(wm * 64 + i * 16 + l15) * 32 + quad * 8];
#pragma unroll
        for (int j = 0; j < 4; ++j)
            bfr[j] = *(const bf16x8*)&Bs[(wn * 64 + j * 16 + l15) * 32 + quad * 8];
#pragma unroll
        for (int i = 0; i < 4; ++i)
#pragma unroll
            for (int j = 0; j < 4; ++j)
                acc[i][j] = mfma16(af[i], bfr[j], acc[i][j]);
    }

    const int r0 = quad * 4;
#pragma unroll
    for (int j = 0; j < 4; ++j) {
        int col = n0 + wn * 64 + j * 16 + l15;
        float bv = bias[col];
#pragma unroll
        for (int i = 0; i < 4; ++i) {
            int rowb = m0 + wm * 64 + i * 16 + r0;
#pragma unroll
            for (int r = 0; r < 4; ++r) {
                float v = acc[i][j][r] + bv;
                if (do_relu) v = fmaxf(v, 0.f);
                C[(size_t)(rowb + r) * N + col] = f2b(v);
            }
        }
    }
}

// ---------------------------------------------------------------------------
// transpose_v: vectorized batched bf16 transpose, in [z][R][C] -> out [z][C][R].
// Tile 32 rows x 64 cols, 256 threads, uint4 global loads/stores.
// grid (C/64, R/32, nb).
// ---------------------------------------------------------------------------
__global__ __launch_bounds__(256) void transpose_v(
    const u16* __restrict__ in, u16* __restrict__ out, int R, int C)
{
    __shared__ u16 st[64][33];
    const u16* ip = in  + (size_t)blockIdx.z * R * C;
    u16*       op = out + (size_t)blockIdx.z * R * C;
    const int c0 = blockIdx.x * 64, r0 = blockIdx.y * 32;
    const int t = threadIdx.x;
    {
        const int row = t >> 3, ch = t & 7;       // 32 rows x 8 chunks
        uint4 v = *(const uint4*)&ip[(size_t)(r0 + row) * C + c0 + ch * 8];
        const u16* pv = (const u16*)&v;
#pragma unroll
        for (int k = 0; k < 8; ++k) st[ch * 8 + k][row] = pv[k];
    }
    __syncthreads();
    {
        const int oc = t >> 2, r4 = t & 3;        // 64 out-rows x 4 chunks
        uint4 v; u16* pv = (u16*)&v;
#pragma unroll
        for (int k = 0; k < 8; ++k) pv[k] = st[oc][r4 * 8 + k];
        *(uint4*)&op[(size_t)(c0 + oc) * R + r0 + r4 * 8] = v;
    }
}

// ---------------------------------------------------------------------------
// head: out[row,:] = log_softmax(o[row,:] @ W4 + b4). One wave per row,
// 4 rows per wave (16 rows/block) to amortize the W4 LDS staging.
// ---------------------------------------------------------------------------
__global__ __launch_bounds__(256) void head_logsoftmax(
    const u16* __restrict__ o, const float* __restrict__ W4,
    const float* __restrict__ b4, float* __restrict__ out)
{
    __shared__ float W4s[DIN * DOUT];
    __shared__ float b4s[DOUT];
    const int tid = threadIdx.x;
    for (int i = tid; i < DIN * DOUT; i += 256) W4s[i] = W4[i];
    if (tid < DOUT) b4s[tid] = b4[tid];
    __syncthreads();
    const int lane = tid & 63, w = tid >> 6;
    for (int rr = 0; rr < 4; ++rr) {
        const size_t row = (size_t)blockIdx.x * 16 + w * 4 + rr;
        const uint4 ov = *(const uint4*)&o[row * DIN + lane * 8];
        const u32* ou = (const u32*)&ov;
        float oc[8];
#pragma unroll
        for (int i = 0; i < 4; ++i) {
            oc[2*i]   = b2f((u16)(ou[i] & 0xFFFFu));
            oc[2*i+1] = b2f((u16)(ou[i] >> 16));
        }
        float acc[DOUT];
#pragma unroll
        for (int c = 0; c < DOUT; ++c) acc[c] = 0.f;
#pragma unroll
        for (int i = 0; i < 8; ++i) {
            int k = lane * 8 + i;
            float x = oc[i];
#pragma unroll
            for (int c = 0; c < DOUT; ++c) acc[c] += x * W4s[k * DOUT + c];
        }
#pragma unroll
        for (int off = 32; off >= 1; off >>= 1)
#pragma unroll
            for (int c = 0; c < DOUT; ++c) acc[c] += __shfl_xor(acc[c], off, 64);
        float mx = -1e30f;
#pragma unroll
        for (int c = 0; c < DOUT; ++c) { acc[c] += b4s[c]; mx = fmaxf(mx, acc[c]); }
        float sum = 0.f;
#pragma unroll
        for (int c = 0; c < DOUT; ++c) sum += __expf(acc[c] - mx);
        float lse = mx + logf(sum);
        if (lane == 0) {
#pragma unroll
            for (int c = 0; c < DOUT; ++c) out[row * DOUT + c] = acc[c] - lse;
        }
    }
}

// ---------------------------------------------------------------------------
extern "C" void kernel_launch(void* const* d_in, const int* in_sizes, int n_in,
                              void* d_out, int out_size, void* d_ws, size_t ws_size,
                              hipStream_t stream) {
    const float* x  = (const float*)d_in[0];
    const float* gv = (const float*)d_in[1];
    const float* uv = (const float*)d_in[2];
    const float* W1 = (const float*)d_in[3];
    const float* b1 = (const float*)d_in[4];
    const float* W2 = (const float*)d_in[5];
    const float* b2 = (const float*)d_in[6];
    const float* W3 = (const float*)d_in[7];
    const float* b3 = (const float*)d_in[8];
    const float* W4 = (const float*)d_in[9];
    const float* b4 = (const float*)d_in[10];
    float* out = (float*)d_out;

    char* ws = (char*)d_ws;
    const size_t MB64 = (size_t)67108864;
    const size_t MiB  = (size_t)1048576;
    const size_t TIER_A4 = 276 * MiB;                       // fused-transpose
    const size_t TIER_A3 = 2 * MB64 + 80 * MiB + 4 * MiB;   // 212 MiB single-pass
    const size_t TIER_A2 = 2 * MB64 + 72 * MiB + 8 * MiB;   // 208 MiB gate
    const size_t TIER_B  = 3 * MB64 + 5 * MiB;              // 197 MiB

    if (ws_size >= TIER_A4) {
        // [0,32) o (h1 dead by gemm3) | [0,64) h1/xb'? layout:
        //  h1 [0,64)   gemm1 out (dead after gemm8t)
        //  h  [64,128) gemm8t row-major out -> ctx (pv8 out; h dead post-score8)
        //  hT [128,192) gemm8t transposed out (read by pv8)
        //  P  [192,272) packed scores
        //  o  [0,32)   gemm3 out (h1 region, dead)
        //  W  [272,276)
        u16* h1  = (u16*)(ws);
        u16* o   = (u16*)(ws);
        u16* h   = (u16*)(ws + MB64);
        u16* ctx = h;
        u16* hT  = (u16*)(ws + 128 * MiB);
        u16* P   = (u16*)(ws + 192 * MiB);
        u16* xb  = hT;   // xb dead after gemm1; reuse hT region for it
        u16* W1t = (u16*)(ws + 272 * MiB);
        u16* W2t = W1t + 512 * 1024;
        u16* W3t = W2t + 1024 * 1024;

        prep_all<<<10240, 256, 0, stream>>>(x, xb, W1, W2, W3, W1t, W2t, W3t);
        gemm8<<<dim3(128, 4), 512, 0, stream>>>(xb, W1t, b1, h1, 1024, 512, 1);
        gemm8t<<<dim3(128, 4), 512, 0, stream>>>(h1, W2t, b2, h, hT, 1024, 1024);

        score8<<<36 * 16, 512, 0, stream>>>(h, P, 16);    // 576 blocks, XCD swz
        softmax_rows<<<8192, 256, 0, stream>>>(P);
        pv8<<<32 * 16, 512, 0, stream>>>(P, hT, ctx, 16); // 512 blocks, LPT

        gemm8<<<dim3(128, 2), 512, 0, stream>>>(ctx, W3t, b3, o, 512, 1024, 1);
        head_logsoftmax<<<2048, 256, 0, stream>>>(o, W4, b4, out);
    } else if (ws_size >= TIER_A3) {
        // Single-pass, alias-packed layout (R5 path):
        //  [0,64) h1 -> hT ; [64,128) h -> ctx ; [128,208) xb -> P -> o
        u16* h1  = (u16*)(ws);
        u16* hT  = h1;
        u16* h   = (u16*)(ws + MB64);
        u16* ctx = h;
        u16* xb  = (u16*)(ws + 2 * MB64);
        u16* P   = xb;
        u16* o   = xb;
        u16* W1t = (u16*)(ws + 2 * MB64 + 80 * MiB);
        u16* W2t = W1t + 512 * 1024;
        u16* W3t = W2t + 1024 * 1024;

        prep_all<<<10240, 256, 0, stream>>>(x, xb, W1, W2, W3, W1t, W2t, W3t);
        gemm8<<<dim3(128, 4), 512, 0, stream>>>(xb, W1t, b1, h1, 1024, 512, 1);
        gemm8<<<dim3(128, 4), 512, 0, stream>>>(h1, W2t, b2, h,  1024, 1024, 1);

        transpose_v<<<dim3(16, 64, 16), 256, 0, stream>>>(h, hT, 2048, 1024);
        score8<<<36 * 16, 512, 0, stream>>>(h, P, 16);
        softmax_rows<<<8192, 256, 0, stream>>>(P);
        pv8<<<32 * 16, 512, 0, stream>>>(P, hT, ctx, 16);

        gemm8<<<dim3(128, 2), 512, 0, stream>>>(ctx, W3t, b3, o, 512, 1024, 1);
        head_logsoftmax<<<2048, 256, 0, stream>>>(o, W4, b4, out);
    } else if (ws_size >= TIER_A2) {
        u16* h1   = (u16*)(ws);
        u16* ctx  = h1;
        u16* h    = (u16*)(ws + MB64);
        u16* o    = h;
        u16* xb   = (u16*)(ws + 2 * MB64);
        u16* hT_c = xb;
        u16* P_c  = (u16*)(ws + 2 * MB64 + 32 * MiB);
        u16* W1t  = (u16*)(ws + 2 * MB64 + 72 * MiB);
        u16* W2t  = W1t + 512 * 1024;
        u16* W3t  = W2t + 1024 * 1024;

        prep_all<<<10240, 256, 0, stream>>>(x, xb, W1, W2, W3, W1t, W2t, W3t);
        gemm8<<<dim3(128, 4), 512, 0, stream>>>(xb, W1t, b1, h1, 1024, 512, 1);
        gemm8<<<dim3(128, 4), 512, 0, stream>>>(h1, W2t, b2, h,  1024, 1024, 1);

        for (int c = 0; c < 2; ++c) {
            const u16* hc  = h   + (size_t)c * 8 * S_ * DH;
            u16*       cxc = ctx + (size_t)c * 8 * S_ * DH;
            transpose_v<<<dim3(16, 64, 8), 256, 0, stream>>>(hc, hT_c, 2048, 1024);
            score8<<<36 * 8, 512, 0, stream>>>(hc, P_c, 8);
            softmax_rows<<<4096, 256, 0, stream>>>(P_c);
            pv_a<<<16 * 8 * 8, 256, 0, stream>>>(P_c, hT_c, cxc, 8);
        }

        gemm8<<<dim3(128, 2), 512, 0, stream>>>(ctx, W3t, b3, o, 512, 1024, 1);
        head_logsoftmax<<<2048, 256, 0, stream>>>(o, W4, b4, out);
    } else if (ws_size >= TIER_B) {
        u16* h1   = (u16*)(ws);
        u16* ctx  = h1;
        u16* h    = (u16*)(ws + MB64);
        u16* xb   = (u16*)(ws + 2 * MB64);
        u16* hT_c = xb;
        u16* P_c  = (u16*)(ws + 2 * MB64 + 16 * MiB);
        u16* o    = (u16*)(ws + 2 * MB64);
        u16* W1t  = (u16*)(ws + 3 * MB64);
        u16* W2t  = W1t + 512 * 1024;
        u16* W3t  = W2t + 1024 * 1024;

        prep_all<<<10240, 256, 0, stream>>>(x, xb, W1, W2, W3, W1t, W2t, W3t);
        gemm8<<<dim3(128, 4), 512, 0, stream>>>(xb, W1t, b1, h1, 1024, 512, 1);
        gemm8<<<dim3(128, 4), 512, 0, stream>>>(h1, W2t, b2, h,  1024, 1024, 1);

        for (int c = 0; c < 4; ++c) {
            const u16* hc  = h   + (size_t)c * 4 * S_ * DH;
            u16*       cxc = ctx + (size_t)c * 4 * S_ * DH;
            transpose_v<<<dim3(16, 64, 4), 256, 0, stream>>>(hc, hT_c, 2048, 1024);
            score8<<<36 * 4, 512, 0, stream>>>(hc, P_c, 4);
            softmax_rows<<<2048, 256, 0, stream>>>(P_c);
            pv_a<<<16 * 8 * 4, 256, 0, stream>>>(P_c, hT_c, cxc, 4);
        }

        gemm8<<<dim3(128, 2), 512, 0, stream>>>(ctx, W3t, b3, o, 512, 1024, 1);
        head_logsoftmax<<<2048, 256, 0, stream>>>(o, W4, b4, out);
    } else {
        u16* h    = (u16*)(ws);
        u16* hT_b = (u16*)(ws + MB64);
        u16* P_b  = (u16*)(ws + MB64 + 4 * MiB);
        u16* ctx_b= (u16*)(ws + MB64 + 12 * MiB);
        u16* o_b  = (u16*)(ws + MB64 + 16 * MiB);
        u16* W1t  = (u16*)(ws + MB64 + 18 * MiB);
        u16* W2t  = W1t + 512 * 1024;
        u16* W3t  = W2t + 1024 * 1024;
        u16* h1_b = P_b;

        wprep<<<2048, dim3(32, 8), 0, stream>>>(W1, W2, W3, W1t, W2t, W3t);

        for (int c = 0; c < 8; ++c) {
            const float* xc = x + (size_t)c * 4096 * DIN;
            u16*         hc = h + (size_t)c * 4096 * DH;
            gemm_bt_bias_relu<true ><<<dim3(32, 8), 256, 0, stream>>>(xc, W1t, b1, h1_b,
                                                                      4096, 1024, 512, 1);
            gemm_bt_bias_relu<false><<<dim3(32, 8), 256, 0, stream>>>(h1_b, W2t, b2, hc,
                                                                      4096, 1024, 1024, 1);
        }
        for (int b = 0; b < B_; ++b) {
            const u16* hb = h + (size_t)b * S_ * DH;
            transpose_v<<<dim3(16, 64, 1), 256, 0, stream>>>(hb, hT_b, 2048, 1024);
            score_a<<<dim3(16, 16, 1), 256, 0, stream>>>(hb, P_b);
            softmax_rows<<<512, 256, 0, stream>>>(P_b);
            pv_a<<<16 * 8, 256, 0, stream>>>(P_b, hT_b, ctx_b, 1);
            gemm_bt_bias_relu<false><<<dim3(16, 4), 256, 0, stream>>>(ctx_b, W3t, b3, o_b,
                                                                      2048, 512, 1024, 1);
            head_logsoftmax<<<128, 256, 0, stream>>>(o_b, W4, b4,
                                                     out + (size_t)b * S_ * DOUT);
        }
    }

    // pass-throughs (f32)
    size_t n_gv = (size_t)in_sizes[1], n_uv = (size_t)in_sizes[2];
    size_t o0 = (size_t)out_size - n_gv - n_uv;
    hipMemcpyAsync(out + o0,        gv, n_gv * 4, hipMemcpyDeviceToDevice, stream);
    hipMemcpyAsync(out + o0 + n_gv, uv, n_uv * 4, hipMemcpyDeviceToDevice, stream);
}

// Round 7
// 543.123 us; speedup vs baseline: 1.2567x; 1.0012x over previous
//
#include <hip/hip_runtime.h>
#include <stdint.h>

// Problem constants (fixed by reference)
#define B_   16
#define S_   2048
#define DIN  512
#define DH   1024
#define DOUT 10

typedef unsigned short u16;
typedef unsigned int   u32;

typedef __bf16 bf16_t;
typedef bf16_t bf16x8 __attribute__((ext_vector_type(8)));
typedef float  f32x4  __attribute__((ext_vector_type(4)));

#define MASKVAL (-3.0e4f)
// Packed-P geometry: row-block mi holds r4 = ((mi>>2)+1)*4 tiles of 128 cols.
// Tile-offset of row-block mi: S4(mi) = 4*(g+1)*(mi-2g), g = mi>>2.
// Pair property: rows [bi*256, bi*256+256) are CONTIGUOUS with lda = r4*128.
// Per-batch packed size = 160 tiles * 16384 u16 = 5 MiB.
// Pad tiles (ni > mi) are NEVER written by score8; softmax_rows synthesizes
// them (skip read, exp -> 0) and writes zeros there for pv to consume.
#define PZ_U16 ((size_t)160 * 16384)

__device__ __forceinline__ float b2f(u16 u) {
    union { u32 i; float f; } v; v.i = ((u32)u) << 16; return v.f;
}
__device__ __forceinline__ u16 f2b(float f) {
    union { float f; u32 i; } v; v.f = f;
    u32 u = v.i;
    u32 r = (u + 0x7FFFu + ((u >> 16) & 1u)) >> 16;  // RNE
    return (u16)r;
}
__device__ __forceinline__ u32 pack2(float a, float b) {
    return (u32)f2b(a) | ((u32)f2b(b) << 16);
}

__device__ __forceinline__ f32x4 mfma16(bf16x8 a, bf16x8 b, f32x4 c) {
    return __builtin_amdgcn_mfma_f32_16x16x32_bf16(a, b, c, 0, 0, 0);
}

// async global->LDS, 16B per lane; LDS dest = wave-uniform base + lane*16
__device__ __forceinline__ void load_lds16(const u16* g, u16* l) {
    __builtin_amdgcn_global_load_lds(
        (__attribute__((address_space(1))) u32*)(g),
        (__attribute__((address_space(3))) u32*)(l), 16, 0, 0);
}

// load 8 contiguous elements at element-index eidx as packed bf16x8 (uint4)
template<bool F32>
__device__ __forceinline__ uint4 ld8(const void* base, size_t eidx) {
    if constexpr (F32) {
        const float* p = (const float*)base + eidx;
        float4 f0 = *(const float4*)p;
        float4 f1 = *(const float4*)(p + 4);
        uint4 r;
        r.x = pack2(f0.x, f0.y); r.y = pack2(f0.z, f0.w);
        r.z = pack2(f1.x, f1.y); r.w = pack2(f1.z, f1.w);
        return r;
    } else {
        return *(const uint4*)((const u16*)base + eidx);
    }
}

// ---------------------------------------------------------------------------
// prep_all: fused input cvt (x f32->bf16, 8192 blocks) + weight prep
// (transpose+cvt W1/W2/W3, 2048 blocks). grid 10240 x 256.
// ---------------------------------------------------------------------------
__global__ __launch_bounds__(256) void prep_all(
    const float* __restrict__ x, u16* __restrict__ xb,
    const float* __restrict__ W1, const float* __restrict__ W2,
    const float* __restrict__ W3,
    u16* __restrict__ W1t, u16* __restrict__ W2t, u16* __restrict__ W3t)
{
    const int tid = threadIdx.x;
    if (blockIdx.x < 8192) {
        size_t e = ((size_t)blockIdx.x * 256 + tid) * 8;
        float4 f0 = *(const float4*)(x + e);
        float4 f1 = *(const float4*)(x + e + 4);
        uint4 r;
        r.x = pack2(f0.x, f0.y); r.y = pack2(f0.z, f0.w);
        r.z = pack2(f1.x, f1.y); r.w = pack2(f1.z, f1.w);
        *(uint4*)(xb + e) = r;
        return;
    }
    __shared__ u16 t[32][33];
    int i = blockIdx.x - 8192;
    const float* in; u16* out; int R, C, xt;
    if (i < 512)       { in = W1; out = W1t; R = 512;  C = 1024; xt = 32; }
    else if (i < 1536) { in = W2; out = W2t; R = 1024; C = 1024; xt = 32; i -= 512; }
    else               { in = W3; out = W3t; R = 1024; C = 512;  xt = 16; i -= 1536; }
    const int c0 = (i % xt) * 32, r0 = (i / xt) * 32;
    const int tx = tid & 31, ty = tid >> 5;
#pragma unroll
    for (int k = 0; k < 4; ++k)
        t[ty + k * 8][tx] = f2b(in[(size_t)(r0 + ty + k * 8) * C + c0 + tx]);
    __syncthreads();
#pragma unroll
    for (int k = 0; k < 4; ++k)
        out[(size_t)(c0 + ty + k * 8) * R + r0 + tx] = t[tx][ty + k * 8];
}

// wprep: standalone weight prep (tier-C). grid 2048 x (32,8).
__global__ __launch_bounds__(256) void wprep(
    const float* __restrict__ W1, const float* __restrict__ W2,
    const float* __restrict__ W3,
    u16* __restrict__ W1t, u16* __restrict__ W2t, u16* __restrict__ W3t)
{
    __shared__ u16 t[32][33];
    int i = blockIdx.x;
    const float* in; u16* out; int R, C, xt;
    if (i < 512)       { in = W1; out = W1t; R = 512;  C = 1024; xt = 32; }
    else if (i < 1536) { in = W2; out = W2t; R = 1024; C = 1024; xt = 32; i -= 512; }
    else               { in = W3; out = W3t; R = 1024; C = 512;  xt = 16; i -= 1536; }
    const int c0 = (i % xt) * 32, r0 = (i / xt) * 32;
    const int tx = threadIdx.x, ty = threadIdx.y;
#pragma unroll
    for (int k = 0; k < 4; ++k)
        t[ty + k * 8][tx] = f2b(in[(size_t)(r0 + ty + k * 8) * C + c0 + tx]);
    __syncthreads();
#pragma unroll
    for (int k = 0; k < 4; ++k)
        out[(size_t)(c0 + ty + k * 8) * R + r0 + tx] = t[tx][ty + k * 8];
}

// ===========================================================================
// 8-phase 256x256 machinery (T2 swizzle + T3/T4 counted vmcnt + T5 setprio).
// LDS: AS/BS[2 dbuf][256 rows][64 cols] bf16. Load-unit = 64 rows x 64 cols.
// Swizzle: linear slot (row, c) holds data chunk c ^ (row&7) (16B chunks);
// write side pre-swizzles the global source chunk, read side XORs the chunk.
// ===========================================================================
template<int QR>
__device__ __forceinline__ void rda(bf16x8 (&a)[4][2], const u16* T,
                                    int arow, int quad) {
#pragma unroll
    for (int mf = 0; mf < 4; ++mf) {
        const int row = arow + QR * 64 + mf * 16;
        const int sw = row & 7;
#pragma unroll
        for (int ks = 0; ks < 2; ++ks)
            a[mf][ks] = *(const bf16x8*)(T + row * 64 + (((ks * 4 + quad) ^ sw) << 3));
    }
}

template<int QC>
__device__ __forceinline__ void rdb(bf16x8 (&b)[2][2], const u16* T,
                                    int brow, int quad) {
#pragma unroll
    for (int nf = 0; nf < 2; ++nf) {
        const int row = brow + QC * 128 + nf * 16;
        const int sw = row & 7;
#pragma unroll
        for (int ks = 0; ks < 2; ++ks)
            b[nf][ks] = *(const bf16x8*)(T + row * 64 + (((ks * 4 + quad) ^ sw) << 3));
    }
}

template<int QR, int QC>
__device__ __forceinline__ void mmq(f32x4 (&acc)[2][2][4][2],
                                    const bf16x8 (&a)[4][2],
                                    const bf16x8 (&b)[2][2]) {
#pragma unroll
    for (int ks = 0; ks < 2; ++ks)
#pragma unroll
        for (int mf = 0; mf < 4; ++mf)
#pragma unroll
            for (int nf = 0; nf < 2; ++nf)
                acc[QR][QC][mf][nf] = mfma16(a[mf][ks], b[nf][ks], acc[QR][QC][mf][nf]);
}

#define G8BAR()  __builtin_amdgcn_s_barrier()
#define G8LGKM() do { asm volatile("s_waitcnt lgkmcnt(0)" ::: "memory"); \
                      __builtin_amdgcn_sched_barrier(0); } while (0)
#define G8VMC4() asm volatile("s_waitcnt vmcnt(4)" ::: "memory")

// The 8-phase K-loop body, parameterized on staging macros STGA/STGB.
// Phases P1-P4 consume buf0 (quadrants (0,0),(0,1),(1,0),(1,1)), P5-P8 buf1.
// Stage stream (2 units/phase), each unit staged >=1 end-barrier after its
// last reader retired; vmcnt(4) ONLY at P4/P8 end.
#define G8_LOOP_BODY(NT_)                                                     \
    const int NI = (NT_) >> 1;                                                \
    for (int i = 0; i < NI; ++i) {                                            \
        const int t1 = 2 * i + 1, t2 = 2 * i + 2, t3 = 2 * i + 3;             \
        rda<0>(a, AS_[0], arow, quad); rdb<0>(b0r, BS_[0], brow, quad);       \
        STGB(1, 2, t1); STGB(1, 3, t1);                                       \
        G8BAR(); G8LGKM();                                                    \
        __builtin_amdgcn_s_setprio(1); mmq<0, 0>(acc, a, b0r);                \
        __builtin_amdgcn_s_setprio(0); G8BAR();                               \
        rdb<1>(b1r, BS_[0], brow, quad);                                      \
        STGA(1, 1, t1); STGA(1, 3, t1);                                       \
        G8BAR(); G8LGKM();                                                    \
        __builtin_amdgcn_s_setprio(1); mmq<0, 1>(acc, a, b1r);                \
        __builtin_amdgcn_s_setprio(0); G8BAR();                               \
        rda<1>(a, AS_[0], arow, quad);                                        \
        if (t2 < (NT_)) { STGA(0, 0, t2); STGA(0, 2, t2); }                   \
        G8BAR(); G8LGKM();                                                    \
        __builtin_amdgcn_s_setprio(1); mmq<1, 0>(acc, a, b0r);                \
        __builtin_amdgcn_s_setprio(0); G8BAR();                               \
        if (t2 < (NT_)) { STGB(0, 0, t2); STGB(0, 1, t2); }                   \
        G8BAR();                                                              \
        __builtin_amdgcn_s_setprio(1); mmq<1, 1>(acc, a, b1r);                \
        __builtin_amdgcn_s_setprio(0);                                        \
        G8VMC4(); G8BAR();                                                    \
        rda<0>(a, AS_[1], arow, quad); rdb<0>(b0r, BS_[1], brow, quad);       \
        if (t2 < (NT_)) { STGB(0, 2, t2); STGB(0, 3, t2); }                   \
        G8BAR(); G8LGKM();                                                    \
        __builtin_amdgcn_s_setprio(1); mmq<0, 0>(acc, a, b0r);                \
        __builtin_amdgcn_s_setprio(0); G8BAR();                               \
        rdb<1>(b1r, BS_[1], brow, quad);                                      \
        if (t2 < (NT_)) { STGA(0, 1, t2); STGA(0, 3, t2); }                   \
        G8BAR(); G8LGKM();                                                    \
        __builtin_amdgcn_s_setprio(1); mmq<0, 1>(acc, a, b1r);                \
        __builtin_amdgcn_s_setprio(0); G8BAR();                               \
        rda<1>(a, AS_[1], arow, quad);                                        \
        if (t3 < (NT_)) { STGA(1, 0, t3); STGA(1, 2, t3); }                   \
        G8BAR(); G8LGKM();                                                    \
        __builtin_amdgcn_s_setprio(1); mmq<1, 0>(acc, a, b0r);                \
        __builtin_amdgcn_s_setprio(0); G8BAR();                               \
        if (t3 < (NT_)) { STGB(1, 0, t3); STGB(1, 1, t3); }                   \
        G8BAR();                                                              \
        __builtin_amdgcn_s_setprio(1); mmq<1, 1>(acc, a, b1r);                \
        __builtin_amdgcn_s_setprio(0);                                        \
        G8VMC4(); G8BAR();                                                    \
    }

// common per-thread decomposition + acc init for the 8-phase kernels
#define G8_SETUP()                                                            \
    const int tid  = threadIdx.x;                                             \
    const int lane = tid & 63;                                                \
    const int w    = tid >> 6;                                                \
    const int wm   = w >> 2, wn = w & 3;                                      \
    const int quad = lane >> 4, l15 = lane & 15;                              \
    const int rg = tid >> 3;                                                  \
    const int ch = (lane & 7) ^ ((lane >> 3) & 7);                            \
    const int wslot = w * 512;                                                \
    f32x4 acc[2][2][4][2];                                                    \
    _Pragma("unroll") for (int p_ = 0; p_ < 2; ++p_)                          \
    _Pragma("unroll") for (int q_ = 0; q_ < 2; ++q_)                          \
    _Pragma("unroll") for (int m_ = 0; m_ < 4; ++m_)                          \
    _Pragma("unroll") for (int n_ = 0; n_ < 2; ++n_)                          \
        acc[p_][q_][m_][n_] = (f32x4){0.f, 0.f, 0.f, 0.f};                    \
    bf16x8 a[4][2], b0r[2][2], b1r[2][2];                                     \
    const int arow = wm * 128 + l15;                                          \
    const int brow = wn * 32 + l15;

#define G8_PROLOGUE()                                                         \
    STGA(0, 0, 0); STGA(0, 1, 0); STGA(0, 2, 0); STGA(0, 3, 0);               \
    STGB(0, 0, 0); STGB(0, 1, 0); STGB(0, 2, 0); STGB(0, 3, 0);               \
    STGA(1, 0, 1); STGA(1, 2, 1);                                             \
    STGB(1, 0, 1); STGB(1, 1, 1);                                             \
    G8VMC4(); G8BAR();

// ===========================================================================
// gemm8: C[M,N] = relu(A[M,K] @ Bt[N,K]^T + bias[N]), bf16.
// grid = (M/256, N/256), block = 512. Requires K % 128 == 0.
// ===========================================================================
__global__ __launch_bounds__(512, 2) void gemm8(
    const u16* __restrict__ A, const u16* __restrict__ Bt,
    const float* __restrict__ bias, u16* __restrict__ C,
    int N, int K, int do_relu)
{
    __shared__ __attribute__((aligned(16))) u16 AS_[2][16384];
    __shared__ __attribute__((aligned(16))) u16 BS_[2][16384];

    G8_SETUP()
    const int m0 = blockIdx.x * 256, n0 = blockIdx.y * 256;
    const u16* gA = A  + (size_t)(m0 + rg) * K + ch * 8;
    const u16* gB = Bt + (size_t)(n0 + rg) * K + ch * 8;

#define STGA(BUF, U, T) load_lds16(gA + (size_t)(U) * 64 * K + (T) * 64, \
                                   &AS_[BUF][(U) * 4096 + wslot])
#define STGB(BUF, U, T) load_lds16(gB + (size_t)(U) * 64 * K + (T) * 64, \
                                   &BS_[BUF][(U) * 4096 + wslot])

    const int NT = K >> 6;
    G8_PROLOGUE()
    G8_LOOP_BODY(NT)
#undef STGA
#undef STGB

    // epilogue: bias + relu + bf16 store
    const int r0 = quad * 4;
#pragma unroll
    for (int qc = 0; qc < 2; ++qc)
#pragma unroll
    for (int nf = 0; nf < 2; ++nf) {
        const int col = n0 + qc * 128 + wn * 32 + nf * 16 + l15;
        const float bv = bias[col];
#pragma unroll
        for (int qr = 0; qr < 2; ++qr)
#pragma unroll
        for (int mf = 0; mf < 4; ++mf) {
            const int rowb = m0 + wm * 128 + qr * 64 + mf * 16 + r0;
#pragma unroll
            for (int r = 0; r < 4; ++r) {
                float v = acc[qr][qc][mf][nf][r] + bv;
                if (do_relu) v = fmaxf(v, 0.f);
                C[(size_t)(rowb + r) * N + col] = f2b(v);
            }
        }
    }
}

// ===========================================================================
// score8: causal score GEMM on the 8-phase 256x256 template, writing packed P.
// grid = 36*nb. Logical l = z*36 + t -> triangular (bi,bj), bj <= bi.
// XCD swizzle (T1, when nb%8==0): p -> xcd=p&7, slot=p>>3, z=(slot/36)*8+xcd,
// t=slot%36: all 36 blocks of a z land on ONE XCD (4MB h-panel fits its L2).
// Pad tiles are NOT written (softmax synthesizes them).
// ===========================================================================
__global__ __launch_bounds__(512, 2) void score8(
    const u16* __restrict__ h, u16* __restrict__ P, int nbb)
{
    __shared__ __attribute__((aligned(16))) u16 AS_[2][16384];
    __shared__ __attribute__((aligned(16))) u16 BS_[2][16384];

    int z, t;
    if ((nbb & 7) == 0) {
        const int xcd = blockIdx.x & 7, slot = blockIdx.x >> 3;
        z = (slot / 36) * 8 + xcd;
        t = slot % 36;
    } else {
        z = blockIdx.x / 36;
        t = blockIdx.x % 36;
    }

    int bi = 0;
    while ((bi + 1) * (bi + 2) / 2 <= t) ++bi;
    const int bj = t - bi * (bi + 1) / 2;
    const bool diag = (bi == bj);

    G8_SETUP()
    const int m0 = bi * 256, n0 = bj * 256;
    const u16* hz = h + (size_t)z * S_ * DH;
    const u16* gA = hz + (size_t)(m0 + rg) * DH + ch * 8;
    const u16* gB = hz + (size_t)(n0 + rg) * DH + ch * 8;

#define STGA(BUF, U, T) load_lds16(gA + (size_t)(U) * 64 * DH + (T) * 64, \
                                   &AS_[BUF][(U) * 4096 + wslot])
#define STGB(BUF, U, T) load_lds16(gB + (size_t)(U) * 64 * DH + (T) * 64, \
                                   &BS_[BUF][(U) * 4096 + wslot])

    const int NT = DH >> 6;      // 16
    G8_PROLOGUE()
    G8_LOOP_BODY(NT)
#undef STGA
#undef STGB

    // epilogue: scatter into packed P with causal mask on diagonal blocks.
    const int mi = 2 * bi + wm;
    const int g  = mi >> 2;
    u16* Pz = P + (size_t)z * PZ_U16
                + (size_t)(4 * (g + 1) * (mi - 2 * g)) * 16384;
    const size_t rstride = (size_t)(4 * (g + 1)) * 128;

    const int r0 = quad * 4;
#pragma unroll
    for (int qc = 0; qc < 2; ++qc) {
        const int ni = 2 * bj + qc;
#pragma unroll
        for (int nf = 0; nf < 2; ++nf) {
            const int cl = wn * 32 + nf * 16 + l15;
            const int colg = n0 + qc * 128 + cl;
#pragma unroll
            for (int qr = 0; qr < 2; ++qr)
#pragma unroll
            for (int mf = 0; mf < 4; ++mf) {
                const int rl = qr * 64 + mf * 16 + r0;
                const int rowg = m0 + wm * 128 + rl;
#pragma unroll
                for (int r = 0; r < 4; ++r) {
                    float v = acc[qr][qc][mf][nf][r];
                    if (diag && colg > rowg + r) v = MASKVAL;
                    Pz[(size_t)(rl + r) * rstride + ni * 128 + cl] = f2b(v);
                }
            }
        }
    }
}

// ===========================================================================
// pv8: ctx[z] = P[z] @ V[z] on the 8-phase 256x256 template.
// Packed-P pair-contiguity: rows [bi*256, bi*256+256) form a dense row-major
// matrix with lda = K = ((bi>>1)+1)*512. Pad tiles hold exact zeros (written
// by softmax) -> including them is bitwise-identical to skipping.
// grid.x = nb*32, LPT: bi = 7 - idx/(4*nb); rem: nj = rem&3, z = rem>>2.
// NT in {8,16,24,32}: with nb=16 (512 blocks), 32+8 and 24+16 pair to a
// balanced 40-NT makespan on 256 CUs.
// ===========================================================================
__global__ __launch_bounds__(512, 2) void pv8(
    const u16* __restrict__ P, const u16* __restrict__ hT,
    u16* __restrict__ ctx, int nb)
{
    __shared__ __attribute__((aligned(16))) u16 AS_[2][16384];
    __shared__ __attribute__((aligned(16))) u16 BS_[2][16384];

    const int per_bi = 4 * nb;
    const int bi  = 7 - (int)(blockIdx.x / per_bi);  // LPT heavy-first
    const int rem = blockIdx.x % per_bi;
    const int nj  = rem & 3;
    const int z   = rem >> 2;

    const int g  = bi >> 1;
    const int K  = (g + 1) * 512;                // = r4*128 = lda
    const int NT = K >> 6;                       // 8/16/24/32 (all even)
    const int n0 = nj * 256;

    const u16* Az = P + (size_t)z * PZ_U16
                      + (size_t)(4 * (g + 1) * (2 * bi - 2 * g)) * 16384;
    const u16* Bz = hT + (size_t)z * DH * S_;
    u16*       C  = ctx + (size_t)z * S_ * DH;

    G8_SETUP()
    const u16* gA = Az + (size_t)rg * K + ch * 8;
    const u16* gB = Bz + (size_t)(n0 + rg) * S_ + ch * 8;

#define STGA(BUF, U, T) load_lds16(gA + (size_t)(U) * 64 * K + (T) * 64, \
                                   &AS_[BUF][(U) * 4096 + wslot])
#define STGB(BUF, U, T) load_lds16(gB + (size_t)(U) * 64 * S_ + (T) * 64, \
                                   &BS_[BUF][(U) * 4096 + wslot])

    G8_PROLOGUE()
    G8_LOOP_BODY(NT)
#undef STGA
#undef STGB

    // epilogue: plain bf16 store into ctx
    const int r0 = quad * 4;
#pragma unroll
    for (int qc = 0; qc < 2; ++qc)
#pragma unroll
    for (int nf = 0; nf < 2; ++nf) {
        const int col = n0 + qc * 128 + wn * 32 + nf * 16 + l15;
#pragma unroll
        for (int qr = 0; qr < 2; ++qr)
#pragma unroll
        for (int mf = 0; mf < 4; ++mf) {
            const int rowb = bi * 256 + wm * 128 + qr * 64 + mf * 16 + r0;
#pragma unroll
            for (int r = 0; r < 4; ++r)
                C[(size_t)(rowb + r) * DH + col] = f2b(acc[qr][qc][mf][nf][r]);
        }
    }
}

// ---------------------------------------------------------------------------
// ASYNC score GEMM into PACKED P (tier-C fallback): row-block mi = causal
// tiles ni<=mi, padded to r4 tiles; pad tiles get MASKVAL. grid (16, 16, nb).
// ---------------------------------------------------------------------------
__global__ __launch_bounds__(256) void score_a(
    const u16* __restrict__ h, u16* __restrict__ P)
{
    __shared__ __attribute__((aligned(16))) u16 As[128 * 32];
    __shared__ __attribute__((aligned(16))) u16 Bs[128 * 32];

    const int mi = 15 - blockIdx.x;              // LPT: heavy rows first
    const int ni = blockIdx.y;
    const int g  = mi >> 2;
    const int r4 = (g + 1) * 4;
    if (ni >= r4) return;

    const int tid = threadIdx.x;
    u16* Pz = P + (size_t)blockIdx.z * PZ_U16
                + (size_t)(4 * (g + 1) * (mi - 2 * g)) * 16384;
    const size_t rstride = (size_t)r4 * 128;

    if (ni > mi) {                               // pad tile: MASKVAL fill
        const u16 mb = f2b(MASKVAL);
        const u32 m2 = (u32)mb | ((u32)mb << 16);
        uint4 mv; mv.x = m2; mv.y = m2; mv.z = m2; mv.w = m2;
#pragma unroll
        for (int i = 0; i < 8; ++i) {
            int q = tid + i * 256;
            int row = q >> 4, cl = (q & 15) * 8;
            *(uint4*)&Pz[(size_t)row * rstride + ni * 128 + cl] = mv;
        }
        return;
    }

    const int m0 = mi * 128, n0 = ni * 128;
    const u16* A = h + (size_t)blockIdx.z * S_ * DH;

    const int lane = tid & 63;
    const int w    = tid >> 6;
    const int wm   = w >> 1, wn = w & 1;
    const int quad = lane >> 4, l15 = lane & 15;

    const int c0 = tid, c1 = tid + 256;
    const u16* gA0 = A + ((size_t)(m0 + (c0 >> 2)) * DH + (c0 & 3) * 8);
    const u16* gA1 = A + ((size_t)(m0 + (c1 >> 2)) * DH + (c1 & 3) * 8);
    const u16* gB0 = A + ((size_t)(n0 + (c0 >> 2)) * DH + (c0 & 3) * 8);
    const u16* gB1 = A + ((size_t)(n0 + (c1 >> 2)) * DH + (c1 & 3) * 8);
    u16* lA0 = &As[(w * 64) * 8];
    u16* lA1 = &As[(256 + w * 64) * 8];
    u16* lB0 = &Bs[(w * 64) * 8];
    u16* lB1 = &Bs[(256 + w * 64) * 8];

    f32x4 acc[4][4];
#pragma unroll
    for (int i = 0; i < 4; ++i)
#pragma unroll
        for (int j = 0; j < 4; ++j) acc[i][j] = (f32x4){0.f, 0.f, 0.f, 0.f};

    const int nk = DH >> 5;
    for (int kk = 0; kk < nk; ++kk) {
        load_lds16(gA0, lA0); load_lds16(gA1, lA1);
        load_lds16(gB0, lB0); load_lds16(gB1, lB1);
        gA0 += 32; gA1 += 32; gB0 += 32; gB1 += 32;
        __syncthreads();
        bf16x8 af[4], bfr[4];
#pragma unroll
        for (int i = 0; i < 4; ++i)
            af[i] = *(const bf16x8*)&As[(wm * 64 + i * 16 + l15) * 32 + quad * 8];
#pragma unroll
        for (int j = 0; j < 4; ++j)
            bfr[j] = *(const bf16x8*)&Bs[(wn * 64 + j * 16 + l15) * 32 + quad * 8];
#pragma unroll
        for (int i = 0; i < 4; ++i)
#pragma unroll
            for (int j = 0; j < 4; ++j)
                acc[i][j] = mfma16(af[i], bfr[j], acc[i][j]);
        __syncthreads();
    }

    const int r0 = quad * 4;
#pragma unroll
    for (int j = 0; j < 4; ++j) {
        int cl = wn * 64 + j * 16 + l15;
#pragma unroll
        for (int i = 0; i < 4; ++i) {
            int rl = wm * 64 + i * 16 + r0;
#pragma unroll
            for (int r = 0; r < 4; ++r) {
                int row = rl + r;
                float v = (n0 + cl <= m0 + row) ? acc[i][j][r] : MASKVAL;
                Pz[(size_t)row * rstride + ni * 128 + cl] = f2b(v);
            }
        }
    }
}

// ---------------------------------------------------------------------------
// softmax_rows: in-place row softmax of packed P. One wave per row.
// Pad tiles (ni > mi) are SYNTHESIZED: no read (v = MASKVAL -> exp = 0.0f,
// identical bits to reading a stored MASKVAL), but zeros ARE written so
// pv8/pv_a can read them. Row max >= diagonal >= 0 > MASKVAL always.
// ---------------------------------------------------------------------------
__global__ __launch_bounds__(256) void softmax_rows(u16* __restrict__ P)
{
    const int tid = threadIdx.x;
    const int lane = tid & 63, w = tid >> 6;
    const int quad = lane >> 4;
    const size_t row = (size_t)blockIdx.x * 4 + w;
    const int z    = (int)(row >> 11);
    const int rloc = (int)(row & (S_ - 1));
    const int mi = rloc >> 7, g = mi >> 2;
    const int kb = g + 1;
    u16* p = P + (size_t)z * PZ_U16
               + (size_t)(4 * (g + 1) * (mi - 2 * g)) * 16384
               + (size_t)(rloc & 127) * ((g + 1) * 4 * 128);
    float v[32];
    float m = -1e30f;
    for (int k = 0; k < kb; ++k) {
        if (k * 4 + quad <= mi) {                // real tile for this lane
            uint4 u = *(const uint4*)&p[k * 512 + lane * 8];
            const u32* uu = (const u32*)&u;
#pragma unroll
            for (int i = 0; i < 4; ++i) {
                float a = b2f((u16)(uu[i] & 0xFFFFu));
                float b = b2f((u16)(uu[i] >> 16));
                v[k * 8 + 2 * i] = a; v[k * 8 + 2 * i + 1] = b;
                m = fmaxf(m, fmaxf(a, b));
            }
        } else {                                 // pad tile: synthesize
#pragma unroll
            for (int i = 0; i < 8; ++i) v[k * 8 + i] = MASKVAL;
        }
    }
#pragma unroll
    for (int off = 32; off >= 1; off >>= 1) m = fmaxf(m, __shfl_xor(m, off, 64));
    float s = 0.f;
    for (int k = 0; k < kb; ++k)
#pragma unroll
        for (int i = 0; i < 8; ++i) {
            float e = __expf(v[k * 8 + i] - m);
            v[k * 8 + i] = e; s += e;
        }
#pragma unroll
    for (int off = 32; off >= 1; off >>= 1) s += __shfl_xor(s, off, 64);
    float inv = 1.0f / s;
    for (int k = 0; k < kb; ++k) {
        uint4 u; u32* uu = (u32*)&u;
#pragma unroll
        for (int i = 0; i < 4; ++i)
            uu[i] = pack2(v[k * 8 + 2 * i] * inv, v[k * 8 + 2 * i + 1] * inv);
        *(uint4*)&p[k * 512 + lane * 8] = u;
    }
}

// ---------------------------------------------------------------------------
// ASYNC pv GEMM (128x128 tile, A2/B/C fallback), LPT 1D grid.
// grid.x = 16*8*nb; idx -> mi = 15 - idx/(8*nb); sub = idx%(8*nb):
// n = sub&7, z = sub>>3. nk = (mi+1)*4.
// ---------------------------------------------------------------------------
__global__ __launch_bounds__(256) void pv_a(
    const u16* __restrict__ P, const u16* __restrict__ hT, u16* __restrict__ ctx,
    int nb)
{
    __shared__ __attribute__((aligned(16))) u16 As[128 * 32];
    __shared__ __attribute__((aligned(16))) u16 Bs[128 * 32];

    const int idx = blockIdx.x;
    const int per_mi = 8 * nb;
    const int mi = 15 - (idx / per_mi);          // LPT: heavy row-blocks first
    const int sub = idx % per_mi;
    const int nblk = sub & 7;
    const int z    = sub >> 3;
    const int g = mi >> 2;
    const int m0 = mi * 128;
    const int n0 = nblk * 128;
    const size_t rstride = (size_t)((g + 1) * 4) * 128;
    const u16* A  = P  + (size_t)z * PZ_U16
                       + (size_t)(4 * (g + 1) * (mi - 2 * g)) * 16384;
    const u16* Bt = hT + (size_t)z * DH * S_;
    u16*      C   = ctx + (size_t)z * S_ * DH;

    const int tid  = threadIdx.x;
    const int lane = tid & 63;
    const int w    = tid >> 6;
    const int wm   = w >> 1, wn = w & 1;
    const int quad = lane >> 4, l15 = lane & 15;

    const int c0 = tid, c1 = tid + 256;
    const u16* gA0 = A  + ((size_t)(c0 >> 2) * rstride + (c0 & 3) * 8);
    const u16* gA1 = A  + ((size_t)(c1 >> 2) * rstride + (c1 & 3) * 8);
    const u16* gB0 = Bt + ((size_t)(n0 + (c0 >> 2)) * S_ + (c0 & 3) * 8);
    const u16* gB1 = Bt + ((size_t)(n0 + (c1 >> 2)) * S_ + (c1 & 3) * 8);
    u16* lA0 = &As[(w * 64) * 8];
    u16* lA1 = &As[(256 + w * 64) * 8];
    u16* lB0 = &Bs[(w * 64) * 8];
    u16* lB1 = &Bs[(256 + w * 64) * 8];

    f32x4 acc[4][4];
#pragma unroll
    for (int i = 0; i < 4; ++i)
#pragma unroll
        for (int j = 0; j < 4; ++j) acc[i][j] = (f32x4){0.f, 0.f, 0.f, 0.f};

    const int nk = (mi + 1) * 4;
    for (int kk = 0; kk < nk; ++kk) {
        load_lds16(gA0, lA0); load_lds16(gA1, lA1);
        load_lds16(gB0, lB0); load_lds16(gB1, lB1);
        gA0 += 32; gA1 += 32; gB0 += 32; gB1 += 32;
        __syncthreads();
        bf16x8 af[4], bfr[4];
#pragma unroll
        for (int i = 0; i < 4; ++i)
            af[i] = *(const bf16x8*)&As[(wm * 64 + i * 16 + l15) * 32 + quad * 8];
#pragma unroll
        for (int j = 0; j < 4; ++j)
            bfr[j] = *(const bf16x8*)&Bs[(wn * 64 + j * 16 + l15) * 32 + quad * 8];
#pragma unroll
        for (int i = 0; i < 4; ++i)
#pragma unroll
            for (int j = 0; j < 4; ++j)
                acc[i][j] = mfma16(af[i], bfr[j], acc[i][j]);
        __syncthreads();
    }

    const int r0 = quad * 4;
#pragma unroll
    for (int j = 0; j < 4; ++j) {
        int col = n0 + wn * 64 + j * 16 + l15;
#pragma unroll
        for (int i = 0; i < 4; ++i) {
            int rowb = m0 + wm * 64 + i * 16 + r0;
#pragma unroll
            for (int r = 0; r < 4; ++r)
                C[(size_t)(rowb + r) * DH + col] = f2b(acc[i][j][r]);
        }
    }
}

// ---------------------------------------------------------------------------
// SYNC-staged GEMM (tier-C fallback only; A may be f32)
// ---------------------------------------------------------------------------
template<bool AF32>
__global__ __launch_bounds__(256) void gemm_bt_bias_relu(
    const void* __restrict__ A, const u16* __restrict__ Bt,
    const float* __restrict__ bias, u16* __restrict__ C,
    int M, int N, int K, int do_relu)
{
    __shared__ __attribute__((aligned(16))) u16 As[128 * 32];
    __shared__ __attribute__((aligned(16))) u16 Bs[128 * 32];

    const int tid  = threadIdx.x;
    const int lane = tid & 63;
    const int w    = tid >> 6;
    const int wm   = w >> 1, wn = w & 1;
    const int quad = lane >> 4, l15 = lane & 15;

    const int m0 = blockIdx.x * 128;
    const int n0 = blockIdx.y * 128;

    const int c0 = tid, c1 = tid + 256;
    size_t eA0 = (size_t)(m0 + (c0 >> 2)) * K + (c0 & 3) * 8;
    size_t eA1 = (size_t)(m0 + (c1 >> 2)) * K + (c1 & 3) * 8;
    size_t eB0 = (size_t)(n0 + (c0 >> 2)) * K + (c0 & 3) * 8;
    size_t eB1 = (size_t)(n0 + (c1 >> 2)) * K + (c1 & 3) * 8;

    f32x4 acc[4][4];
#pragma unroll
    for (int i = 0; i < 4; ++i)
#pragma unroll
        for (int j = 0; j < 4; ++j) acc[i][j] = (f32x4){0.f, 0.f, 0.f, 0.f};

    uint4 va0 = ld8<AF32>(A, eA0), va1 = ld8<AF32>(A, eA1);
    uint4 vb0 = ld8<false>(Bt, eB0), vb1 = ld8<false>(Bt, eB1);

    const int nk = K >> 5;
    for (int kk = 0; kk < nk; ++kk) {
        __syncthreads();
        *(uint4*)&As[c0 * 8] = va0;
        *(uint4*)&As[c1 * 8] = va1;
        *(uint4*)&Bs[c0 * 8] = vb0;
        *(uint4*)&Bs[c1 * 8] = vb1;
        if (kk + 1 < nk) {
            eA0 += 32; eA1 += 32; eB0 += 32; eB1 += 32;
            va0 = ld8<AF32>(A, eA0); va1 = ld8<AF32>(A, eA1);
            vb0 = ld8<false>(Bt, eB0); vb1 = ld8<false>(Bt, eB1);
        }
        __syncthreads();
        bf16x8 af[4], bfr[4];
#pragma unroll
        for (int i = 0; i < 4; ++i)
            af[i] = *(const bf16x8*)&As[(wm * 64 + i * 16 + l15) * 32 + quad * 8];
#pragma unroll
        for (int j = 0; j < 4; ++j)
            bfr[j] = *(const bf16x8*)&Bs[(wn * 64 + j * 16 + l15) * 32 + quad * 8];
#pragma unroll
        for (int i = 0; i < 4; ++i)
#pragma unroll
            for (int j = 0; j < 4; ++j)
                acc[i][j] = mfma16(af[i], bfr[j], acc[i][j]);
    }

    const int r0 = quad * 4;
#pragma unroll
    for (int j = 0; j < 4; ++j) {
        int col = n0 + wn * 64 + j * 16 + l15;
        float bv = bias[col];
#pragma unroll
        for (int i = 0; i < 4; ++i) {
            int rowb = m0 + wm * 64 + i * 16 + r0;
#pragma unroll
            for (int r = 0; r < 4; ++r) {
                float v = acc[i][j][r] + bv;
                if (do_relu) v = fmaxf(v, 0.f);
                C[(size_t)(rowb + r) * N + col] = f2b(v);
            }
        }
    }
}

// ---------------------------------------------------------------------------
// transpose_v: vectorized batched bf16 transpose, in [z][R][C] -> out [z][C][R].
// Tile 32 rows x 64 cols, 256 threads, uint4 global loads/stores.
// grid (C/64, R/32, nb).
// ---------------------------------------------------------------------------
__global__ __launch_bounds__(256) void transpose_v(
    const u16* __restrict__ in, u16* __restrict__ out, int R, int C)
{
    __shared__ u16 st[64][33];
    const u16* ip = in  + (size_t)blockIdx.z * R * C;
    u16*       op = out + (size_t)blockIdx.z * R * C;
    const int c0 = blockIdx.x * 64, r0 = blockIdx.y * 32;
    const int t = threadIdx.x;
    {
        const int row = t >> 3, ch = t & 7;       // 32 rows x 8 chunks
        uint4 v = *(const uint4*)&ip[(size_t)(r0 + row) * C + c0 + ch * 8];
        const u16* pv = (const u16*)&v;
#pragma unroll
        for (int k = 0; k < 8; ++k) st[ch * 8 + k][row] = pv[k];
    }
    __syncthreads();
    {
        const int oc = t >> 2, r4 = t & 3;        // 64 out-rows x 4 chunks
        uint4 v; u16* pv = (u16*)&v;
#pragma unroll
        for (int k = 0; k < 8; ++k) pv[k] = st[oc][r4 * 8 + k];
        *(uint4*)&op[(size_t)(c0 + oc) * R + r0 + r4 * 8] = v;
    }
}

// ---------------------------------------------------------------------------
// head: out[row,:] = log_softmax(o[row,:] @ W4 + b4). One wave per row,
// 4 rows per wave (16 rows/block) to amortize the W4 LDS staging.
// ---------------------------------------------------------------------------
__global__ __launch_bounds__(256) void head_logsoftmax(
    const u16* __restrict__ o, const float* __restrict__ W4,
    const float* __restrict__ b4, float* __restrict__ out)
{
    __shared__ float W4s[DIN * DOUT];
    __shared__ float b4s[DOUT];
    const int tid = threadIdx.x;
    for (int i = tid; i < DIN * DOUT; i += 256) W4s[i] = W4[i];
    if (tid < DOUT) b4s[tid] = b4[tid];
    __syncthreads();
    const int lane = tid & 63, w = tid >> 6;
    for (int rr = 0; rr < 4; ++rr) {
        const size_t row = (size_t)blockIdx.x * 16 + w * 4 + rr;
        const uint4 ov = *(const uint4*)&o[row * DIN + lane * 8];
        const u32* ou = (const u32*)&ov;
        float oc[8];
#pragma unroll
        for (int i = 0; i < 4; ++i) {
            oc[2*i]   = b2f((u16)(ou[i] & 0xFFFFu));
            oc[2*i+1] = b2f((u16)(ou[i] >> 16));
        }
        float acc[DOUT];
#pragma unroll
        for (int c = 0; c < DOUT; ++c) acc[c] = 0.f;
#pragma unroll
        for (int i = 0; i < 8; ++i) {
            int k = lane * 8 + i;
            float x = oc[i];
#pragma unroll
            for (int c = 0; c < DOUT; ++c) acc[c] += x * W4s[k * DOUT + c];
        }
#pragma unroll
        for (int off = 32; off >= 1; off >>= 1)
#pragma unroll
            for (int c = 0; c < DOUT; ++c) acc[c] += __shfl_xor(acc[c], off, 64);
        float mx = -1e30f;
#pragma unroll
        for (int c = 0; c < DOUT; ++c) { acc[c] += b4s[c]; mx = fmaxf(mx, acc[c]); }
        float sum = 0.f;
#pragma unroll
        for (int c = 0; c < DOUT; ++c) sum += __expf(acc[c] - mx);
        float lse = mx + logf(sum);
        if (lane == 0) {
#pragma unroll
            for (int c = 0; c < DOUT; ++c) out[row * DOUT + c] = acc[c] - lse;
        }
    }
}

// ---------------------------------------------------------------------------
extern "C" void kernel_launch(void* const* d_in, const int* in_sizes, int n_in,
                              void* d_out, int out_size, void* d_ws, size_t ws_size,
                              hipStream_t stream) {
    const float* x  = (const float*)d_in[0];
    const float* gv = (const float*)d_in[1];
    const float* uv = (const float*)d_in[2];
    const float* W1 = (const float*)d_in[3];
    const float* b1 = (const float*)d_in[4];
    const float* W2 = (const float*)d_in[5];
    const float* b2 = (const float*)d_in[6];
    const float* W3 = (const float*)d_in[7];
    const float* b3 = (const float*)d_in[8];
    const float* W4 = (const float*)d_in[9];
    const float* b4 = (const float*)d_in[10];
    float* out = (float*)d_out;

    char* ws = (char*)d_ws;
    const size_t MB64 = (size_t)67108864;
    const size_t MiB  = (size_t)1048576;
    const size_t TIER_A3 = 2 * MB64 + 80 * MiB + 4 * MiB;   // 212 MiB single-pass
    const size_t TIER_A2 = 2 * MB64 + 72 * MiB + 8 * MiB;   // 208 MiB gate
    const size_t TIER_B  = 3 * MB64 + 5 * MiB;              // 197 MiB

    if (ws_size >= TIER_A3) {
        // Single-pass, alias-packed layout (R5-verified):
        //  [0,64) h1 -> hT ; [64,128) h -> ctx ; [128,208) xb -> P -> o
        u16* h1  = (u16*)(ws);
        u16* hT  = h1;
        u16* h   = (u16*)(ws + MB64);
        u16* ctx = h;
        u16* xb  = (u16*)(ws + 2 * MB64);
        u16* P   = xb;
        u16* o   = xb;
        u16* W1t = (u16*)(ws + 2 * MB64 + 80 * MiB);
        u16* W2t = W1t + 512 * 1024;
        u16* W3t = W2t + 1024 * 1024;

        prep_all<<<10240, 256, 0, stream>>>(x, xb, W1, W2, W3, W1t, W2t, W3t);
        gemm8<<<dim3(128, 4), 512, 0, stream>>>(xb, W1t, b1, h1, 1024, 512, 1);
        gemm8<<<dim3(128, 4), 512, 0, stream>>>(h1, W2t, b2, h,  1024, 1024, 1);

        transpose_v<<<dim3(16, 64, 16), 256, 0, stream>>>(h, hT, 2048, 1024);
        score8<<<36 * 16, 512, 0, stream>>>(h, P, 16);    // 576 blocks, XCD swz
        softmax_rows<<<8192, 256, 0, stream>>>(P);
        pv8<<<32 * 16, 512, 0, stream>>>(P, hT, ctx, 16); // 512 blocks, LPT

        gemm8<<<dim3(128, 2), 512, 0, stream>>>(ctx, W3t, b3, o, 512, 1024, 1);
        head_logsoftmax<<<2048, 256, 0, stream>>>(o, W4, b4, out);
    } else if (ws_size >= TIER_A2) {
        u16* h1   = (u16*)(ws);
        u16* ctx  = h1;
        u16* h    = (u16*)(ws + MB64);
        u16* o    = h;
        u16* xb   = (u16*)(ws + 2 * MB64);
        u16* hT_c = xb;
        u16* P_c  = (u16*)(ws + 2 * MB64 + 32 * MiB);
        u16* W1t  = (u16*)(ws + 2 * MB64 + 72 * MiB);
        u16* W2t  = W1t + 512 * 1024;
        u16* W3t  = W2t + 1024 * 1024;

        prep_all<<<10240, 256, 0, stream>>>(x, xb, W1, W2, W3, W1t, W2t, W3t);
        gemm8<<<dim3(128, 4), 512, 0, stream>>>(xb, W1t, b1, h1, 1024, 512, 1);
        gemm8<<<dim3(128, 4), 512, 0, stream>>>(h1, W2t, b2, h,  1024, 1024, 1);

        for (int c = 0; c < 2; ++c) {
            const u16* hc  = h   + (size_t)c * 8 * S_ * DH;
            u16*       cxc = ctx + (size_t)c * 8 * S_ * DH;
            transpose_v<<<dim3(16, 64, 8), 256, 0, stream>>>(hc, hT_c, 2048, 1024);
            score8<<<36 * 8, 512, 0, stream>>>(hc, P_c, 8);
            softmax_rows<<<4096, 256, 0, stream>>>(P_c);
            pv_a<<<16 * 8 * 8, 256, 0, stream>>>(P_c, hT_c, cxc, 8);
        }

        gemm8<<<dim3(128, 2), 512, 0, stream>>>(ctx, W3t, b3, o, 512, 1024, 1);
        head_logsoftmax<<<2048, 256, 0, stream>>>(o, W4, b4, out);
    } else if (ws_size >= TIER_B) {
        u16* h1   = (u16*)(ws);
        u16* ctx  = h1;
        u16* h    = (u16*)(ws + MB64);
        u16* xb   = (u16*)(ws + 2 * MB64);
        u16* hT_c = xb;
        u16* P_c  = (u16*)(ws + 2 * MB64 + 16 * MiB);
        u16* o    = (u16*)(ws + 2 * MB64);
        u16* W1t  = (u16*)(ws + 3 * MB64);
        u16* W2t  = W1t + 512 * 1024;
        u16* W3t  = W2t + 1024 * 1024;

        prep_all<<<10240, 256, 0, stream>>>(x, xb, W1, W2, W3, W1t, W2t, W3t);
        gemm8<<<dim3(128, 4), 512, 0, stream>>>(xb, W1t, b1, h1, 1024, 512, 1);
        gemm8<<<dim3(128, 4), 512, 0, stream>>>(h1, W2t, b2, h,  1024, 1024, 1);

        for (int c = 0; c < 4; ++c) {
            const u16* hc  = h   + (size_t)c * 4 * S_ * DH;
            u16*       cxc = ctx + (size_t)c * 4 * S_ * DH;
            transpose_v<<<dim3(16, 64, 4), 256, 0, stream>>>(hc, hT_c, 2048, 1024);
            score8<<<36 * 4, 512, 0, stream>>>(hc, P_c, 4);
            softmax_rows<<<2048, 256, 0, stream>>>(P_c);
            pv_a<<<16 * 8 * 4, 256, 0, stream>>>(P_c, hT_c, cxc, 4);
        }

        gemm8<<<dim3(128, 2), 512, 0, stream>>>(ctx, W3t, b3, o, 512, 1024, 1);
        head_logsoftmax<<<2048, 256, 0, stream>>>(o, W4, b4, out);
    } else {
        u16* h    = (u16*)(ws);
        u16* hT_b = (u16*)(ws + MB64);
        u16* P_b  = (u16*)(ws + MB64 + 4 * MiB);
        u16* ctx_b= (u16*)(ws + MB64 + 12 * MiB);
        u16* o_b  = (u16*)(ws + MB64 + 16 * MiB);
        u16* W1t  = (u16*)(ws + MB64 + 18 * MiB);
        u16* W2t  = W1t + 512 * 1024;
        u16* W3t  = W2t + 1024 * 1024;
        u16* h1_b = P_b;

        wprep<<<2048, dim3(32, 8), 0, stream>>>(W1, W2, W3, W1t, W2t, W3t);

        for (int c = 0; c < 8; ++c) {
            const float* xc = x + (size_t)c * 4096 * DIN;
            u16*         hc = h + (size_t)c * 4096 * DH;
            gemm_bt_bias_relu<true ><<<dim3(32, 8), 256, 0, stream>>>(xc, W1t, b1, h1_b,
                                                                      4096, 1024, 512, 1);
            gemm_bt_bias_relu<false><<<dim3(32, 8), 256, 0, stream>>>(h1_b, W2t, b2, hc,
                                                                      4096, 1024, 1024, 1);
        }
        for (int b = 0; b < B_; ++b) {
            const u16* hb = h + (size_t)b * S_ * DH;
            transpose_v<<<dim3(16, 64, 1), 256, 0, stream>>>(hb, hT_b, 2048, 1024);
            score_a<<<dim3(16, 16, 1), 256, 0, stream>>>(hb, P_b);
            softmax_rows<<<512, 256, 0, stream>>>(P_b);
            pv_a<<<16 * 8, 256, 0, stream>>>(P_b, hT_b, ctx_b, 1);
            gemm_bt_bias_relu<false><<<dim3(16, 4), 256, 0, stream>>>(ctx_b, W3t, b3, o_b,
                                                                      2048, 512, 1024, 1);
            head_logsoftmax<<<128, 256, 0, stream>>>(o_b, W4, b4,
                                                     out + (size_t)b * S_ * DOUT);
        }
    }

    // pass-throughs (f32)
    size_t n_gv = (size_t)in_sizes[1], n_uv = (size_t)in_sizes[2];
    size_t o0 = (size_t)out_size - n_gv - n_uv;
    hipMemcpyAsync(out + o0,        gv, n_gv * 4, hipMemcpyDeviceToDevice, stream);
    hipMemcpyAsync(out + o0 + n_gv, uv, n_uv * 4, hipMemcpyDeviceToDevice, stream);
}

// Round 8
// 537.406 us; speedup vs baseline: 1.2701x; 1.0106x over previous
//
#include <hip/hip_runtime.h>
#include <stdint.h>

// Problem constants (fixed by reference)
#define B_   16
#define S_   2048
#define DIN  512
#define DH   1024
#define DOUT 10

typedef unsigned short u16;
typedef unsigned int   u32;

typedef __bf16 bf16_t;
typedef bf16_t bf16x8 __attribute__((ext_vector_type(8)));
typedef float  f32x4  __attribute__((ext_vector_type(4)));

#define MASKVAL (-3.0e4f)
// Packed-P geometry: row-block mi holds r4 = ((mi>>2)+1)*4 tiles of 128 cols.
// Tile-offset of row-block mi: S4(mi) = 4*(g+1)*(mi-2g), g = mi>>2.
// Pair property: rows [bi*256, bi*256+256) are CONTIGUOUS with lda = r4*128.
// Per-batch packed size = 160 tiles * 16384 u16 = 5 MiB.
// Pad tiles (ni > mi) are NEVER written by score8; softmax_rows synthesizes
// them (skip read, exp -> 0) and writes zeros there for pv to consume.
#define PZ_U16 ((size_t)160 * 16384)

__device__ __forceinline__ float b2f(u16 u) {
    union { u32 i; float f; } v; v.i = ((u32)u) << 16; return v.f;
}
__device__ __forceinline__ u16 f2b(float f) {
    union { float f; u32 i; } v; v.f = f;
    u32 u = v.i;
    u32 r = (u + 0x7FFFu + ((u >> 16) & 1u)) >> 16;  // RNE
    return (u16)r;
}
__device__ __forceinline__ u32 pack2(float a, float b) {
    return (u32)f2b(a) | ((u32)f2b(b) << 16);
}

__device__ __forceinline__ f32x4 mfma16(bf16x8 a, bf16x8 b, f32x4 c) {
    return __builtin_amdgcn_mfma_f32_16x16x32_bf16(a, b, c, 0, 0, 0);
}

// async global->LDS, 16B per lane; LDS dest = wave-uniform base + lane*16
__device__ __forceinline__ void load_lds16(const u16* g, u16* l) {
    __builtin_amdgcn_global_load_lds(
        (__attribute__((address_space(1))) u32*)(g),
        (__attribute__((address_space(3))) u32*)(l), 16, 0, 0);
}

// load 8 contiguous elements at element-index eidx as packed bf16x8 (uint4)
template<bool F32>
__device__ __forceinline__ uint4 ld8(const void* base, size_t eidx) {
    if constexpr (F32) {
        const float* p = (const float*)base + eidx;
        float4 f0 = *(const float4*)p;
        float4 f1 = *(const float4*)(p + 4);
        uint4 r;
        r.x = pack2(f0.x, f0.y); r.y = pack2(f0.z, f0.w);
        r.z = pack2(f1.x, f1.y); r.w = pack2(f1.z, f1.w);
        return r;
    } else {
        return *(const uint4*)((const u16*)base + eidx);
    }
}

// ---------------------------------------------------------------------------
// prep_all: fused input cvt (x f32->bf16, 8192 blocks) + weight prep
// (transpose+cvt W1/W2/W3, 2048 blocks). grid 10240 x 256.
// ---------------------------------------------------------------------------
__global__ __launch_bounds__(256) void prep_all(
    const float* __restrict__ x, u16* __restrict__ xb,
    const float* __restrict__ W1, const float* __restrict__ W2,
    const float* __restrict__ W3,
    u16* __restrict__ W1t, u16* __restrict__ W2t, u16* __restrict__ W3t)
{
    const int tid = threadIdx.x;
    if (blockIdx.x < 8192) {
        size_t e = ((size_t)blockIdx.x * 256 + tid) * 8;
        float4 f0 = *(const float4*)(x + e);
        float4 f1 = *(const float4*)(x + e + 4);
        uint4 r;
        r.x = pack2(f0.x, f0.y); r.y = pack2(f0.z, f0.w);
        r.z = pack2(f1.x, f1.y); r.w = pack2(f1.z, f1.w);
        *(uint4*)(xb + e) = r;
        return;
    }
    __shared__ u16 t[32][33];
    int i = blockIdx.x - 8192;
    const float* in; u16* out; int R, C, xt;
    if (i < 512)       { in = W1; out = W1t; R = 512;  C = 1024; xt = 32; }
    else if (i < 1536) { in = W2; out = W2t; R = 1024; C = 1024; xt = 32; i -= 512; }
    else               { in = W3; out = W3t; R = 1024; C = 512;  xt = 16; i -= 1536; }
    const int c0 = (i % xt) * 32, r0 = (i / xt) * 32;
    const int tx = tid & 31, ty = tid >> 5;
#pragma unroll
    for (int k = 0; k < 4; ++k)
        t[ty + k * 8][tx] = f2b(in[(size_t)(r0 + ty + k * 8) * C + c0 + tx]);
    __syncthreads();
#pragma unroll
    for (int k = 0; k < 4; ++k)
        out[(size_t)(c0 + ty + k * 8) * R + r0 + tx] = t[tx][ty + k * 8];
}

// wprep: standalone weight prep (tier-C). grid 2048 x (32,8).
__global__ __launch_bounds__(256) void wprep(
    const float* __restrict__ W1, const float* __restrict__ W2,
    const float* __restrict__ W3,
    u16* __restrict__ W1t, u16* __restrict__ W2t, u16* __restrict__ W3t)
{
    __shared__ u16 t[32][33];
    int i = blockIdx.x;
    const float* in; u16* out; int R, C, xt;
    if (i < 512)       { in = W1; out = W1t; R = 512;  C = 1024; xt = 32; }
    else if (i < 1536) { in = W2; out = W2t; R = 1024; C = 1024; xt = 32; i -= 512; }
    else               { in = W3; out = W3t; R = 1024; C = 512;  xt = 16; i -= 1536; }
    const int c0 = (i % xt) * 32, r0 = (i / xt) * 32;
    const int tx = threadIdx.x, ty = threadIdx.y;
#pragma unroll
    for (int k = 0; k < 4; ++k)
        t[ty + k * 8][tx] = f2b(in[(size_t)(r0 + ty + k * 8) * C + c0 + tx]);
    __syncthreads();
#pragma unroll
    for (int k = 0; k < 4; ++k)
        out[(size_t)(c0 + ty + k * 8) * R + r0 + tx] = t[tx][ty + k * 8];
}

// ===========================================================================
// 8-phase 256x256 machinery (T2 swizzle + T3/T4 counted vmcnt + T5 setprio).
// LDS: AS/BS[2 dbuf][256 rows][64 cols] bf16. Load-unit = 64 rows x 64 cols.
// Swizzle: linear slot (row, c) holds data chunk c ^ (row&7) (16B chunks);
// write side pre-swizzles the global source chunk, read side XORs the chunk.
// ===========================================================================
template<int QR>
__device__ __forceinline__ void rda(bf16x8 (&a)[4][2], const u16* T,
                                    int arow, int quad) {
#pragma unroll
    for (int mf = 0; mf < 4; ++mf) {
        const int row = arow + QR * 64 + mf * 16;
        const int sw = row & 7;
#pragma unroll
        for (int ks = 0; ks < 2; ++ks)
            a[mf][ks] = *(const bf16x8*)(T + row * 64 + (((ks * 4 + quad) ^ sw) << 3));
    }
}

template<int QC>
__device__ __forceinline__ void rdb(bf16x8 (&b)[2][2], const u16* T,
                                    int brow, int quad) {
#pragma unroll
    for (int nf = 0; nf < 2; ++nf) {
        const int row = brow + QC * 128 + nf * 16;
        const int sw = row & 7;
#pragma unroll
        for (int ks = 0; ks < 2; ++ks)
            b[nf][ks] = *(const bf16x8*)(T + row * 64 + (((ks * 4 + quad) ^ sw) << 3));
    }
}

template<int QR, int QC>
__device__ __forceinline__ void mmq(f32x4 (&acc)[2][2][4][2],
                                    const bf16x8 (&a)[4][2],
                                    const bf16x8 (&b)[2][2]) {
#pragma unroll
    for (int ks = 0; ks < 2; ++ks)
#pragma unroll
        for (int mf = 0; mf < 4; ++mf)
#pragma unroll
            for (int nf = 0; nf < 2; ++nf)
                acc[QR][QC][mf][nf] = mfma16(a[mf][ks], b[nf][ks], acc[QR][QC][mf][nf]);
}

#define G8BAR()  __builtin_amdgcn_s_barrier()
#define G8LGKM() do { asm volatile("s_waitcnt lgkmcnt(0)" ::: "memory"); \
                      __builtin_amdgcn_sched_barrier(0); } while (0)
#define G8VMC4() asm volatile("s_waitcnt vmcnt(4)" ::: "memory")

// The 8-phase K-loop body, parameterized on staging macros STGA/STGB.
// Phases P1-P4 consume buf0 (quadrants (0,0),(0,1),(1,0),(1,1)), P5-P8 buf1.
// Stage stream (2 units/phase), each unit staged >=1 end-barrier after its
// last reader retired; vmcnt(4) ONLY at P4/P8 end.
#define G8_LOOP_BODY(NT_)                                                     \
    const int NI = (NT_) >> 1;                                                \
    for (int i = 0; i < NI; ++i) {                                            \
        const int t1 = 2 * i + 1, t2 = 2 * i + 2, t3 = 2 * i + 3;             \
        rda<0>(a, AS_[0], arow, quad); rdb<0>(b0r, BS_[0], brow, quad);       \
        STGB(1, 2, t1); STGB(1, 3, t1);                                       \
        G8BAR(); G8LGKM();                                                    \
        __builtin_amdgcn_s_setprio(1); mmq<0, 0>(acc, a, b0r);                \
        __builtin_amdgcn_s_setprio(0); G8BAR();                               \
        rdb<1>(b1r, BS_[0], brow, quad);                                      \
        STGA(1, 1, t1); STGA(1, 3, t1);                                       \
        G8BAR(); G8LGKM();                                                    \
        __builtin_amdgcn_s_setprio(1); mmq<0, 1>(acc, a, b1r);                \
        __builtin_amdgcn_s_setprio(0); G8BAR();                               \
        rda<1>(a, AS_[0], arow, quad);                                        \
        if (t2 < (NT_)) { STGA(0, 0, t2); STGA(0, 2, t2); }                   \
        G8BAR(); G8LGKM();                                                    \
        __builtin_amdgcn_s_setprio(1); mmq<1, 0>(acc, a, b0r);                \
        __builtin_amdgcn_s_setprio(0); G8BAR();                               \
        if (t2 < (NT_)) { STGB(0, 0, t2); STGB(0, 1, t2); }                   \
        G8BAR();                                                              \
        __builtin_amdgcn_s_setprio(1); mmq<1, 1>(acc, a, b1r);                \
        __builtin_amdgcn_s_setprio(0);                                        \
        G8VMC4(); G8BAR();                                                    \
        rda<0>(a, AS_[1], arow, quad); rdb<0>(b0r, BS_[1], brow, quad);       \
        if (t2 < (NT_)) { STGB(0, 2, t2); STGB(0, 3, t2); }                   \
        G8BAR(); G8LGKM();                                                    \
        __builtin_amdgcn_s_setprio(1); mmq<0, 0>(acc, a, b0r);                \
        __builtin_amdgcn_s_setprio(0); G8BAR();                               \
        rdb<1>(b1r, BS_[1], brow, quad);                                      \
        if (t2 < (NT_)) { STGA(0, 1, t2); STGA(0, 3, t2); }                   \
        G8BAR(); G8LGKM();                                                    \
        __builtin_amdgcn_s_setprio(1); mmq<0, 1>(acc, a, b1r);                \
        __builtin_amdgcn_s_setprio(0); G8BAR();                               \
        rda<1>(a, AS_[1], arow, quad);                                        \
        if (t3 < (NT_)) { STGA(1, 0, t3); STGA(1, 2, t3); }                   \
        G8BAR(); G8LGKM();                                                    \
        __builtin_amdgcn_s_setprio(1); mmq<1, 0>(acc, a, b0r);                \
        __builtin_amdgcn_s_setprio(0); G8BAR();                               \
        if (t3 < (NT_)) { STGB(1, 0, t3); STGB(1, 1, t3); }                   \
        G8BAR();                                                              \
        __builtin_amdgcn_s_setprio(1); mmq<1, 1>(acc, a, b1r);                \
        __builtin_amdgcn_s_setprio(0);                                        \
        G8VMC4(); G8BAR();                                                    \
    }

// common per-thread decomposition + acc init for the 8-phase kernels
#define G8_SETUP()                                                            \
    const int tid  = threadIdx.x;                                             \
    const int lane = tid & 63;                                                \
    const int w    = tid >> 6;                                                \
    const int wm   = w >> 2, wn = w & 3;                                      \
    const int quad = lane >> 4, l15 = lane & 15;                              \
    const int rg = tid >> 3;                                                  \
    const int ch = (lane & 7) ^ ((lane >> 3) & 7);                            \
    const int wslot = w * 512;                                                \
    f32x4 acc[2][2][4][2];                                                    \
    _Pragma("unroll") for (int p_ = 0; p_ < 2; ++p_)                          \
    _Pragma("unroll") for (int q_ = 0; q_ < 2; ++q_)                          \
    _Pragma("unroll") for (int m_ = 0; m_ < 4; ++m_)                          \
    _Pragma("unroll") for (int n_ = 0; n_ < 2; ++n_)                          \
        acc[p_][q_][m_][n_] = (f32x4){0.f, 0.f, 0.f, 0.f};                    \
    bf16x8 a[4][2], b0r[2][2], b1r[2][2];                                     \
    const int arow = wm * 128 + l15;                                          \
    const int brow = wn * 32 + l15;

#define G8_PROLOGUE()                                                         \
    STGA(0, 0, 0); STGA(0, 1, 0); STGA(0, 2, 0); STGA(0, 3, 0);               \
    STGB(0, 0, 0); STGB(0, 1, 0); STGB(0, 2, 0); STGB(0, 3, 0);               \
    STGA(1, 0, 1); STGA(1, 2, 1);                                             \
    STGB(1, 0, 1); STGB(1, 1, 1);                                             \
    G8VMC4(); G8BAR();

// ===========================================================================
// gemm8: C[M,N] = relu(A[M,K] @ Bt[N,K]^T + bias[N]), bf16.
// grid = (M/256, N/256), block = 512. Requires K % 128 == 0.
// ===========================================================================
__global__ __launch_bounds__(512, 2) void gemm8(
    const u16* __restrict__ A, const u16* __restrict__ Bt,
    const float* __restrict__ bias, u16* __restrict__ C,
    int N, int K, int do_relu)
{
    __shared__ __attribute__((aligned(16))) u16 AS_[2][16384];
    __shared__ __attribute__((aligned(16))) u16 BS_[2][16384];

    G8_SETUP()
    const int m0 = blockIdx.x * 256, n0 = blockIdx.y * 256;
    const u16* gA = A  + (size_t)(m0 + rg) * K + ch * 8;
    const u16* gB = Bt + (size_t)(n0 + rg) * K + ch * 8;

#define STGA(BUF, U, T) load_lds16(gA + (size_t)(U) * 64 * K + (T) * 64, \
                                   &AS_[BUF][(U) * 4096 + wslot])
#define STGB(BUF, U, T) load_lds16(gB + (size_t)(U) * 64 * K + (T) * 64, \
                                   &BS_[BUF][(U) * 4096 + wslot])

    const int NT = K >> 6;
    G8_PROLOGUE()
    G8_LOOP_BODY(NT)
#undef STGA
#undef STGB

    // epilogue: bias + relu + bf16 store
    const int r0 = quad * 4;
#pragma unroll
    for (int qc = 0; qc < 2; ++qc)
#pragma unroll
    for (int nf = 0; nf < 2; ++nf) {
        const int col = n0 + qc * 128 + wn * 32 + nf * 16 + l15;
        const float bv = bias[col];
#pragma unroll
        for (int qr = 0; qr < 2; ++qr)
#pragma unroll
        for (int mf = 0; mf < 4; ++mf) {
            const int rowb = m0 + wm * 128 + qr * 64 + mf * 16 + r0;
#pragma unroll
            for (int r = 0; r < 4; ++r) {
                float v = acc[qr][qc][mf][nf][r] + bv;
                if (do_relu) v = fmaxf(v, 0.f);
                C[(size_t)(rowb + r) * N + col] = f2b(v);
            }
        }
    }
}

// ===========================================================================
// score8: causal score GEMM (8-phase 256x256 template) + MERGED hT transpose.
// Grid = 36*nb score blocks followed by 128*nb transpose blocks.
//   Score block (z, t): triangular (bi,bj), bj <= bi -> 256x256 score tile
//     into packed P (pad tiles NOT written; softmax synthesizes them).
//   Transpose block (z, r): 8 tiles of the h[z] (2048x1024) -> hT[z]
//     (1024x2048) bf16 transpose; cx = r&15 (64-col strip), ry0 = (r>>4)*8.
//     These dispatch LAST and backfill the idle CUs of score's partial
//     3rd round (576 blocks on 256 CUs); transpose traffic (~5200 CU-us)
//     fits inside the ~6500 CU-us of round-3 idle capacity.
// XCD swizzle (T1, when nb%8==0): p -> xcd=p&7, slot=p>>3. Score AND
// transpose blocks of batch z map to the SAME XCD (z === xcd mod 8), so
// transpose reads of h[z] hit the XCD L2 warmed by the score blocks.
// ===========================================================================
__global__ __launch_bounds__(512, 2) void score8(
    const u16* __restrict__ h, u16* __restrict__ P, u16* __restrict__ hT,
    int nbb)
{
    __shared__ __attribute__((aligned(16))) u16 AS_[2][16384];
    __shared__ __attribute__((aligned(16))) u16 BS_[2][16384];

    int z, t = 0, r = 0;
    bool isT = false;
    if ((nbb & 7) == 0) {
        const int xcd = blockIdx.x & 7, slot = blockIdx.x >> 3;
        const int sth = (36 * nbb) >> 3;         // score slots per xcd
        if (slot < sth) { z = (slot / 36) * 8 + xcd; t = slot % 36; }
        else { const int ql = slot - sth; z = (ql >> 7) * 8 + xcd; r = ql & 127; isT = true; }
    } else {
        const int ns = 36 * nbb;
        if ((int)blockIdx.x < ns) { z = blockIdx.x / 36; t = blockIdx.x % 36; }
        else { const int q = blockIdx.x - ns; z = q >> 7; r = q & 127; isT = true; }
    }

    if (isT) {
        // ---- transpose tail: 8 tiles (32 rows x 64 cols each), 2 per pass
        const int cx = r & 15, ry0 = (r >> 4) * 8;
        const u16* hz  = h  + (size_t)z * S_ * DH;
        u16*       hTz = hT + (size_t)z * DH * S_;
        const int th  = threadIdx.x;
        const int sel = th >> 8, tt = th & 255;
        u16* st = (u16*)AS_[0] + sel * 2112;     // [64][33] u16 per tile
#pragma unroll
        for (int jj = 0; jj < 4; ++jj) {
            const int ry = ry0 + 2 * jj + sel;
            {
                const int row = tt >> 3, chv = tt & 7;
                uint4 v = *(const uint4*)&hz[(size_t)(ry * 32 + row) * DH
                                             + cx * 64 + chv * 8];
                const u16* pv = (const u16*)&v;
#pragma unroll
                for (int k = 0; k < 8; ++k) st[(chv * 8 + k) * 33 + row] = pv[k];
            }
            __syncthreads();
            {
                const int oc = tt >> 2, r4 = tt & 3;
                uint4 v; u16* pv = (u16*)&v;
#pragma unroll
                for (int k = 0; k < 8; ++k) pv[k] = st[oc * 33 + r4 * 8 + k];
                *(uint4*)&hTz[(size_t)(cx * 64 + oc) * S_ + ry * 32 + r4 * 8] = v;
            }
            __syncthreads();
        }
        return;
    }

    int bi = 0;
    while ((bi + 1) * (bi + 2) / 2 <= t) ++bi;
    const int bj = t - bi * (bi + 1) / 2;
    const bool diag = (bi == bj);

    G8_SETUP()
    const int m0 = bi * 256, n0 = bj * 256;
    const u16* hz = h + (size_t)z * S_ * DH;
    const u16* gA = hz + (size_t)(m0 + rg) * DH + ch * 8;
    const u16* gB = hz + (size_t)(n0 + rg) * DH + ch * 8;

#define STGA(BUF, U, T) load_lds16(gA + (size_t)(U) * 64 * DH + (T) * 64, \
                                   &AS_[BUF][(U) * 4096 + wslot])
#define STGB(BUF, U, T) load_lds16(gB + (size_t)(U) * 64 * DH + (T) * 64, \
                                   &BS_[BUF][(U) * 4096 + wslot])

    const int NT = DH >> 6;      // 16
    G8_PROLOGUE()
    G8_LOOP_BODY(NT)
#undef STGA
#undef STGB

    // epilogue: scatter into packed P with causal mask on diagonal blocks.
    const int mi = 2 * bi + wm;
    const int g  = mi >> 2;
    u16* Pz = P + (size_t)z * PZ_U16
                + (size_t)(4 * (g + 1) * (mi - 2 * g)) * 16384;
    const size_t rstride = (size_t)(4 * (g + 1)) * 128;

    const int r0 = quad * 4;
#pragma unroll
    for (int qc = 0; qc < 2; ++qc) {
        const int ni = 2 * bj + qc;
#pragma unroll
        for (int nf = 0; nf < 2; ++nf) {
            const int cl = wn * 32 + nf * 16 + l15;
            const int colg = n0 + qc * 128 + cl;
#pragma unroll
            for (int qr = 0; qr < 2; ++qr)
#pragma unroll
            for (int mf = 0; mf < 4; ++mf) {
                const int rl = qr * 64 + mf * 16 + r0;
                const int rowg = m0 + wm * 128 + rl;
#pragma unroll
                for (int rr = 0; rr < 4; ++rr) {
                    float v = acc[qr][qc][mf][nf][rr];
                    if (diag && colg > rowg + rr) v = MASKVAL;
                    Pz[(size_t)(rl + rr) * rstride + ni * 128 + cl] = f2b(v);
                }
            }
        }
    }
}

// ===========================================================================
// pv8: ctx[z] = P[z] @ V[z] on the 8-phase 256x256 template.
// Packed-P pair-contiguity: rows [bi*256, bi*256+256) form a dense row-major
// matrix with lda = K = ((bi>>1)+1)*512. Pad tiles hold exact zeros (written
// by softmax) -> including them is bitwise-identical to skipping.
// grid.x = nb*32, LPT: bi = 7 - idx/(4*nb); rem: nj = rem&3, z = rem>>2.
// NT in {8,16,24,32}: with nb=16 (512 blocks), 32+8 and 24+16 pair to a
// balanced 40-NT makespan on 256 CUs.
// ===========================================================================
__global__ __launch_bounds__(512, 2) void pv8(
    const u16* __restrict__ P, const u16* __restrict__ hT,
    u16* __restrict__ ctx, int nb)
{
    __shared__ __attribute__((aligned(16))) u16 AS_[2][16384];
    __shared__ __attribute__((aligned(16))) u16 BS_[2][16384];

    const int per_bi = 4 * nb;
    const int bi  = 7 - (int)(blockIdx.x / per_bi);  // LPT heavy-first
    const int rem = blockIdx.x % per_bi;
    const int nj  = rem & 3;
    const int z   = rem >> 2;

    const int g  = bi >> 1;
    const int K  = (g + 1) * 512;                // = r4*128 = lda
    const int NT = K >> 6;                       // 8/16/24/32 (all even)
    const int n0 = nj * 256;

    const u16* Az = P + (size_t)z * PZ_U16
                      + (size_t)(4 * (g + 1) * (2 * bi - 2 * g)) * 16384;
    const u16* Bz = hT + (size_t)z * DH * S_;
    u16*       C  = ctx + (size_t)z * S_ * DH;

    G8_SETUP()
    const u16* gA = Az + (size_t)rg * K + ch * 8;
    const u16* gB = Bz + (size_t)(n0 + rg) * S_ + ch * 8;

#define STGA(BUF, U, T) load_lds16(gA + (size_t)(U) * 64 * K + (T) * 64, \
                                   &AS_[BUF][(U) * 4096 + wslot])
#define STGB(BUF, U, T) load_lds16(gB + (size_t)(U) * 64 * S_ + (T) * 64, \
                                   &BS_[BUF][(U) * 4096 + wslot])

    G8_PROLOGUE()
    G8_LOOP_BODY(NT)
#undef STGA
#undef STGB

    // epilogue: plain bf16 store into ctx
    const int r0 = quad * 4;
#pragma unroll
    for (int qc = 0; qc < 2; ++qc)
#pragma unroll
    for (int nf = 0; nf < 2; ++nf) {
        const int col = n0 + qc * 128 + wn * 32 + nf * 16 + l15;
#pragma unroll
        for (int qr = 0; qr < 2; ++qr)
#pragma unroll
        for (int mf = 0; mf < 4; ++mf) {
            const int rowb = bi * 256 + wm * 128 + qr * 64 + mf * 16 + r0;
#pragma unroll
            for (int r = 0; r < 4; ++r)
                C[(size_t)(rowb + r) * DH + col] = f2b(acc[qr][qc][mf][nf][r]);
        }
    }
}

// ---------------------------------------------------------------------------
// ASYNC score GEMM into PACKED P (tier-C fallback): row-block mi = causal
// tiles ni<=mi, padded to r4 tiles; pad tiles get MASKVAL. grid (16, 16, nb).
// ---------------------------------------------------------------------------
__global__ __launch_bounds__(256) void score_a(
    const u16* __restrict__ h, u16* __restrict__ P)
{
    __shared__ __attribute__((aligned(16))) u16 As[128 * 32];
    __shared__ __attribute__((aligned(16))) u16 Bs[128 * 32];

    const int mi = 15 - blockIdx.x;              // LPT: heavy rows first
    const int ni = blockIdx.y;
    const int g  = mi >> 2;
    const int r4 = (g + 1) * 4;
    if (ni >= r4) return;

    const int tid = threadIdx.x;
    u16* Pz = P + (size_t)blockIdx.z * PZ_U16
                + (size_t)(4 * (g + 1) * (mi - 2 * g)) * 16384;
    const size_t rstride = (size_t)r4 * 128;

    if (ni > mi) {                               // pad tile: MASKVAL fill
        const u16 mb = f2b(MASKVAL);
        const u32 m2 = (u32)mb | ((u32)mb << 16);
        uint4 mv; mv.x = m2; mv.y = m2; mv.z = m2; mv.w = m2;
#pragma unroll
        for (int i = 0; i < 8; ++i) {
            int q = tid + i * 256;
            int row = q >> 4, cl = (q & 15) * 8;
            *(uint4*)&Pz[(size_t)row * rstride + ni * 128 + cl] = mv;
        }
        return;
    }

    const int m0 = mi * 128, n0 = ni * 128;
    const u16* A = h + (size_t)blockIdx.z * S_ * DH;

    const int lane = tid & 63;
    const int w    = tid >> 6;
    const int wm   = w >> 1, wn = w & 1;
    const int quad = lane >> 4, l15 = lane & 15;

    const int c0 = tid, c1 = tid + 256;
    const u16* gA0 = A + ((size_t)(m0 + (c0 >> 2)) * DH + (c0 & 3) * 8);
    const u16* gA1 = A + ((size_t)(m0 + (c1 >> 2)) * DH + (c1 & 3) * 8);
    const u16* gB0 = A + ((size_t)(n0 + (c0 >> 2)) * DH + (c0 & 3) * 8);
    const u16* gB1 = A + ((size_t)(n0 + (c1 >> 2)) * DH + (c1 & 3) * 8);
    u16* lA0 = &As[(w * 64) * 8];
    u16* lA1 = &As[(256 + w * 64) * 8];
    u16* lB0 = &Bs[(w * 64) * 8];
    u16* lB1 = &Bs[(256 + w * 64) * 8];

    f32x4 acc[4][4];
#pragma unroll
    for (int i = 0; i < 4; ++i)
#pragma unroll
        for (int j = 0; j < 4; ++j) acc[i][j] = (f32x4){0.f, 0.f, 0.f, 0.f};

    const int nk = DH >> 5;
    for (int kk = 0; kk < nk; ++kk) {
        load_lds16(gA0, lA0); load_lds16(gA1, lA1);
        load_lds16(gB0, lB0); load_lds16(gB1, lB1);
        gA0 += 32; gA1 += 32; gB0 += 32; gB1 += 32;
        __syncthreads();
        bf16x8 af[4], bfr[4];
#pragma unroll
        for (int i = 0; i < 4; ++i)
            af[i] = *(const bf16x8*)&As[(wm * 64 + i * 16 + l15) * 32 + quad * 8];
#pragma unroll
        for (int j = 0; j < 4; ++j)
            bfr[j] = *(const bf16x8*)&Bs[(wn * 64 + j * 16 + l15) * 32 + quad * 8];
#pragma unroll
        for (int i = 0; i < 4; ++i)
#pragma unroll
            for (int j = 0; j < 4; ++j)
                acc[i][j] = mfma16(af[i], bfr[j], acc[i][j]);
        __syncthreads();
    }

    const int r0 = quad * 4;
#pragma unroll
    for (int j = 0; j < 4; ++j) {
        int cl = wn * 64 + j * 16 + l15;
#pragma unroll
        for (int i = 0; i < 4; ++i) {
            int rl = wm * 64 + i * 16 + r0;
#pragma unroll
            for (int r = 0; r < 4; ++r) {
                int row = rl + r;
                float v = (n0 + cl <= m0 + row) ? acc[i][j][r] : MASKVAL;
                Pz[(size_t)row * rstride + ni * 128 + cl] = f2b(v);
            }
        }
    }
}

// ---------------------------------------------------------------------------
// softmax_rows: in-place row softmax of packed P. One wave per row.
// Pad tiles (ni > mi) are SYNTHESIZED: no read (v = MASKVAL -> exp = 0.0f,
// identical bits to reading a stored MASKVAL), but zeros ARE written so
// pv8/pv_a can read them. Row max >= diagonal >= 0 > MASKVAL always.
// ---------------------------------------------------------------------------
__global__ __launch_bounds__(256) void softmax_rows(u16* __restrict__ P)
{
    const int tid = threadIdx.x;
    const int lane = tid & 63, w = tid >> 6;
    const int quad = lane >> 4;
    const size_t row = (size_t)blockIdx.x * 4 + w;
    const int z    = (int)(row >> 11);
    const int rloc = (int)(row & (S_ - 1));
    const int mi = rloc >> 7, g = mi >> 2;
    const int kb = g + 1;
    u16* p = P + (size_t)z * PZ_U16
               + (size_t)(4 * (g + 1) * (mi - 2 * g)) * 16384
               + (size_t)(rloc & 127) * ((g + 1) * 4 * 128);
    float v[32];
    float m = -1e30f;
    for (int k = 0; k < kb; ++k) {
        if (k * 4 + quad <= mi) {                // real tile for this lane
            uint4 u = *(const uint4*)&p[k * 512 + lane * 8];
            const u32* uu = (const u32*)&u;
#pragma unroll
            for (int i = 0; i < 4; ++i) {
                float a = b2f((u16)(uu[i] & 0xFFFFu));
                float b = b2f((u16)(uu[i] >> 16));
                v[k * 8 + 2 * i] = a; v[k * 8 + 2 * i + 1] = b;
                m = fmaxf(m, fmaxf(a, b));
            }
        } else {                                 // pad tile: synthesize
#pragma unroll
            for (int i = 0; i < 8; ++i) v[k * 8 + i] = MASKVAL;
        }
    }
#pragma unroll
    for (int off = 32; off >= 1; off >>= 1) m = fmaxf(m, __shfl_xor(m, off, 64));
    float s = 0.f;
    for (int k = 0; k < kb; ++k)
#pragma unroll
        for (int i = 0; i < 8; ++i) {
            float e = __expf(v[k * 8 + i] - m);
            v[k * 8 + i] = e; s += e;
        }
#pragma unroll
    for (int off = 32; off >= 1; off >>= 1) s += __shfl_xor(s, off, 64);
    float inv = 1.0f / s;
    for (int k = 0; k < kb; ++k) {
        uint4 u; u32* uu = (u32*)&u;
#pragma unroll
        for (int i = 0; i < 4; ++i)
            uu[i] = pack2(v[k * 8 + 2 * i] * inv, v[k * 8 + 2 * i + 1] * inv);
        *(uint4*)&p[k * 512 + lane * 8] = u;
    }
}

// ---------------------------------------------------------------------------
// ASYNC pv GEMM (128x128 tile, A2/B/C fallback), LPT 1D grid.
// grid.x = 16*8*nb; idx -> mi = 15 - idx/(8*nb); sub = idx%(8*nb):
// n = sub&7, z = sub>>3. nk = (mi+1)*4.
// ---------------------------------------------------------------------------
__global__ __launch_bounds__(256) void pv_a(
    const u16* __restrict__ P, const u16* __restrict__ hT, u16* __restrict__ ctx,
    int nb)
{
    __shared__ __attribute__((aligned(16))) u16 As[128 * 32];
    __shared__ __attribute__((aligned(16))) u16 Bs[128 * 32];

    const int idx = blockIdx.x;
    const int per_mi = 8 * nb;
    const int mi = 15 - (idx / per_mi);          // LPT: heavy row-blocks first
    const int sub = idx % per_mi;
    const int nblk = sub & 7;
    const int z    = sub >> 3;
    const int g = mi >> 2;
    const int m0 = mi * 128;
    const int n0 = nblk * 128;
    const size_t rstride = (size_t)((g + 1) * 4) * 128;
    const u16* A  = P  + (size_t)z * PZ_U16
                       + (size_t)(4 * (g + 1) * (mi - 2 * g)) * 16384;
    const u16* Bt = hT + (size_t)z * DH * S_;
    u16*      C   = ctx + (size_t)z * S_ * DH;

    const int tid  = threadIdx.x;
    const int lane = tid & 63;
    const int w    = tid >> 6;
    const int wm   = w >> 1, wn = w & 1;
    const int quad = lane >> 4, l15 = lane & 15;

    const int c0 = tid, c1 = tid + 256;
    const u16* gA0 = A  + ((size_t)(c0 >> 2) * rstride + (c0 & 3) * 8);
    const u16* gA1 = A  + ((size_t)(c1 >> 2) * rstride + (c1 & 3) * 8);
    const u16* gB0 = Bt + ((size_t)(n0 + (c0 >> 2)) * S_ + (c0 & 3) * 8);
    const u16* gB1 = Bt + ((size_t)(n0 + (c1 >> 2)) * S_ + (c1 & 3) * 8);
    u16* lA0 = &As[(w * 64) * 8];
    u16* lA1 = &As[(256 + w * 64) * 8];
    u16* lB0 = &Bs[(w * 64) * 8];
    u16* lB1 = &Bs[(256 + w * 64) * 8];

    f32x4 acc[4][4];
#pragma unroll
    for (int i = 0; i < 4; ++i)
#pragma unroll
        for (int j = 0; j < 4; ++j) acc[i][j] = (f32x4){0.f, 0.f, 0.f, 0.f};

    const int nk = (mi + 1) * 4;
    for (int kk = 0; kk < nk; ++kk) {
        load_lds16(gA0, lA0); load_lds16(gA1, lA1);
        load_lds16(gB0, lB0); load_lds16(gB1, lB1);
        gA0 += 32; gA1 += 32; gB0 += 32; gB1 += 32;
        __syncthreads();
        bf16x8 af[4], bfr[4];
#pragma unroll
        for (int i = 0; i < 4; ++i)
            af[i] = *(const bf16x8*)&As[(wm * 64 + i * 16 + l15) * 32 + quad * 8];
#pragma unroll
        for (int j = 0; j < 4; ++j)
            bfr[j] = *(const bf16x8*)&Bs[(wn * 64 + j * 16 + l15) * 32 + quad * 8];
#pragma unroll
        for (int i = 0; i < 4; ++i)
#pragma unroll
            for (int j = 0; j < 4; ++j)
                acc[i][j] = mfma16(af[i], bfr[j], acc[i][j]);
        __syncthreads();
    }

    const int r0 = quad * 4;
#pragma unroll
    for (int j = 0; j < 4; ++j) {
        int col = n0 + wn * 64 + j * 16 + l15;
#pragma unroll
        for (int i = 0; i < 4; ++i) {
            int rowb = m0 + wm * 64 + i * 16 + r0;
#pragma unroll
            for (int r = 0; r < 4; ++r)
                C[(size_t)(rowb + r) * DH + col] = f2b(acc[i][j][r]);
        }
    }
}

// ---------------------------------------------------------------------------
// SYNC-staged GEMM (tier-C fallback only; A may be f32)
// ---------------------------------------------------------------------------
template<bool AF32>
__global__ __launch_bounds__(256) void gemm_bt_bias_relu(
    const void* __restrict__ A, const u16* __restrict__ Bt,
    const float* __restrict__ bias, u16* __restrict__ C,
    int M, int N, int K, int do_relu)
{
    __shared__ __attribute__((aligned(16))) u16 As[128 * 32];
    __shared__ __attribute__((aligned(16))) u16 Bs[128 * 32];

    const int tid  = threadIdx.x;
    const int lane = tid & 63;
    const int w    = tid >> 6;
    const int wm   = w >> 1, wn = w & 1;
    const int quad = lane >> 4, l15 = lane & 15;

    const int m0 = blockIdx.x * 128;
    const int n0 = blockIdx.y * 128;

    const int c0 = tid, c1 = tid + 256;
    size_t eA0 = (size_t)(m0 + (c0 >> 2)) * K + (c0 & 3) * 8;
    size_t eA1 = (size_t)(m0 + (c1 >> 2)) * K + (c1 & 3) * 8;
    size_t eB0 = (size_t)(n0 + (c0 >> 2)) * K + (c0 & 3) * 8;
    size_t eB1 = (size_t)(n0 + (c1 >> 2)) * K + (c1 & 3) * 8;

    f32x4 acc[4][4];
#pragma unroll
    for (int i = 0; i < 4; ++i)
#pragma unroll
        for (int j = 0; j < 4; ++j) acc[i][j] = (f32x4){0.f, 0.f, 0.f, 0.f};

    uint4 va0 = ld8<AF32>(A, eA0), va1 = ld8<AF32>(A, eA1);
    uint4 vb0 = ld8<false>(Bt, eB0), vb1 = ld8<false>(Bt, eB1);

    const int nk = K >> 5;
    for (int kk = 0; kk < nk; ++kk) {
        __syncthreads();
        *(uint4*)&As[c0 * 8] = va0;
        *(uint4*)&As[c1 * 8] = va1;
        *(uint4*)&Bs[c0 * 8] = vb0;
        *(uint4*)&Bs[c1 * 8] = vb1;
        if (kk + 1 < nk) {
            eA0 += 32; eA1 += 32; eB0 += 32; eB1 += 32;
            va0 = ld8<AF32>(A, eA0); va1 = ld8<AF32>(A, eA1);
            vb0 = ld8<false>(Bt, eB0); vb1 = ld8<false>(Bt, eB1);
        }
        __syncthreads();
        bf16x8 af[4], bfr[4];
#pragma unroll
        for (int i = 0; i < 4; ++i)
            af[i] = *(const bf16x8*)&As[(wm * 64 + i * 16 + l15) * 32 + quad * 8];
#pragma unroll
        for (int j = 0; j < 4; ++j)
            bfr[j] = *(const bf16x8*)&Bs[(wn * 64 + j * 16 + l15) * 32 + quad * 8];
#pragma unroll
        for (int i = 0; i < 4; ++i)
#pragma unroll
            for (int j = 0; j < 4; ++j)
                acc[i][j] = mfma16(af[i], bfr[j], acc[i][j]);
    }

    const int r0 = quad * 4;
#pragma unroll
    for (int j = 0; j < 4; ++j) {
        int col = n0 + wn * 64 + j * 16 + l15;
        float bv = bias[col];
#pragma unroll
        for (int i = 0; i < 4; ++i) {
            int rowb = m0 + wm * 64 + i * 16 + r0;
#pragma unroll
            for (int r = 0; r < 4; ++r) {
                float v = acc[i][j][r] + bv;
                if (do_relu) v = fmaxf(v, 0.f);
                C[(size_t)(rowb + r) * N + col] = f2b(v);
            }
        }
    }
}

// ---------------------------------------------------------------------------
// transpose_v: vectorized batched bf16 transpose, in [z][R][C] -> out [z][C][R].
// Tile 32 rows x 64 cols, 256 threads, uint4 global loads/stores.
// grid (C/64, R/32, nb). (tier-C only; A-tiers use the merged score8 tail)
// ---------------------------------------------------------------------------
__global__ __launch_bounds__(256) void transpose_v(
    const u16* __restrict__ in, u16* __restrict__ out, int R, int C)
{
    __shared__ u16 st[64][33];
    const u16* ip = in  + (size_t)blockIdx.z * R * C;
    u16*       op = out + (size_t)blockIdx.z * R * C;
    const int c0 = blockIdx.x * 64, r0 = blockIdx.y * 32;
    const int t = threadIdx.x;
    {
        const int row = t >> 3, ch = t & 7;       // 32 rows x 8 chunks
        uint4 v = *(const uint4*)&ip[(size_t)(r0 + row) * C + c0 + ch * 8];
        const u16* pv = (const u16*)&v;
#pragma unroll
        for (int k = 0; k < 8; ++k) st[ch * 8 + k][row] = pv[k];
    }
    __syncthreads();
    {
        const int oc = t >> 2, r4 = t & 3;        // 64 out-rows x 4 chunks
        uint4 v; u16* pv = (u16*)&v;
#pragma unroll
        for (int k = 0; k < 8; ++k) pv[k] = st[oc][r4 * 8 + k];
        *(uint4*)&op[(size_t)(c0 + oc) * R + r0 + r4 * 8] = v;
    }
}

// ---------------------------------------------------------------------------
// head: out[row,:] = log_softmax(o[row,:] @ W4 + b4). One wave per row,
// 4 rows per wave (16 rows/block) to amortize the W4 LDS staging.
// ---------------------------------------------------------------------------
__global__ __launch_bounds__(256) void head_logsoftmax(
    const u16* __restrict__ o, const float* __restrict__ W4,
    const float* __restrict__ b4, float* __restrict__ out)
{
    __shared__ float W4s[DIN * DOUT];
    __shared__ float b4s[DOUT];
    const int tid = threadIdx.x;
    for (int i = tid; i < DIN * DOUT; i += 256) W4s[i] = W4[i];
    if (tid < DOUT) b4s[tid] = b4[tid];
    __syncthreads();
    const int lane = tid & 63, w = tid >> 6;
    for (int rr = 0; rr < 4; ++rr) {
        const size_t row = (size_t)blockIdx.x * 16 + w * 4 + rr;
        const uint4 ov = *(const uint4*)&o[row * DIN + lane * 8];
        const u32* ou = (const u32*)&ov;
        float oc[8];
#pragma unroll
        for (int i = 0; i < 4; ++i) {
            oc[2*i]   = b2f((u16)(ou[i] & 0xFFFFu));
            oc[2*i+1] = b2f((u16)(ou[i] >> 16));
        }
        float acc[DOUT];
#pragma unroll
        for (int c = 0; c < DOUT; ++c) acc[c] = 0.f;
#pragma unroll
        for (int i = 0; i < 8; ++i) {
            int k = lane * 8 + i;
            float x = oc[i];
#pragma unroll
            for (int c = 0; c < DOUT; ++c) acc[c] += x * W4s[k * DOUT + c];
        }
#pragma unroll
        for (int off = 32; off >= 1; off >>= 1)
#pragma unroll
            for (int c = 0; c < DOUT; ++c) acc[c] += __shfl_xor(acc[c], off, 64);
        float mx = -1e30f;
#pragma unroll
        for (int c = 0; c < DOUT; ++c) { acc[c] += b4s[c]; mx = fmaxf(mx, acc[c]); }
        float sum = 0.f;
#pragma unroll
        for (int c = 0; c < DOUT; ++c) sum += __expf(acc[c] - mx);
        float lse = mx + logf(sum);
        if (lane == 0) {
#pragma unroll
            for (int c = 0; c < DOUT; ++c) out[row * DOUT + c] = acc[c] - lse;
        }
    }
}

// ---------------------------------------------------------------------------
extern "C" void kernel_launch(void* const* d_in, const int* in_sizes, int n_in,
                              void* d_out, int out_size, void* d_ws, size_t ws_size,
                              hipStream_t stream) {
    const float* x  = (const float*)d_in[0];
    const float* gv = (const float*)d_in[1];
    const float* uv = (const float*)d_in[2];
    const float* W1 = (const float*)d_in[3];
    const float* b1 = (const float*)d_in[4];
    const float* W2 = (const float*)d_in[5];
    const float* b2 = (const float*)d_in[6];
    const float* W3 = (const float*)d_in[7];
    const float* b3 = (const float*)d_in[8];
    const float* W4 = (const float*)d_in[9];
    const float* b4 = (const float*)d_in[10];
    float* out = (float*)d_out;

    char* ws = (char*)d_ws;
    const size_t MB64 = (size_t)67108864;
    const size_t MiB  = (size_t)1048576;
    const size_t TIER_A3 = 2 * MB64 + 80 * MiB + 4 * MiB;   // 212 MiB single-pass
    const size_t TIER_A2 = 2 * MB64 + 72 * MiB + 8 * MiB;   // 208 MiB gate
    const size_t TIER_B  = 3 * MB64 + 5 * MiB;              // 197 MiB

    if (ws_size >= TIER_A3) {
        // Single-pass, alias-packed layout (R5-verified):
        //  [0,64) h1 -> hT ; [64,128) h -> ctx ; [128,208) xb -> P -> o
        u16* h1  = (u16*)(ws);
        u16* hT  = h1;
        u16* h   = (u16*)(ws + MB64);
        u16* ctx = h;
        u16* xb  = (u16*)(ws + 2 * MB64);
        u16* P   = xb;
        u16* o   = xb;
        u16* W1t = (u16*)(ws + 2 * MB64 + 80 * MiB);
        u16* W2t = W1t + 512 * 1024;
        u16* W3t = W2t + 1024 * 1024;

        prep_all<<<10240, 256, 0, stream>>>(x, xb, W1, W2, W3, W1t, W2t, W3t);
        gemm8<<<dim3(128, 4), 512, 0, stream>>>(xb, W1t, b1, h1, 1024, 512, 1);
        gemm8<<<dim3(128, 4), 512, 0, stream>>>(h1, W2t, b2, h,  1024, 1024, 1);

        // merged score + hT transpose: 576 score blocks + 2048 transpose
        // blocks that backfill score's partial 3rd round.
        score8<<<(36 + 128) * 16, 512, 0, stream>>>(h, P, hT, 16);
        softmax_rows<<<8192, 256, 0, stream>>>(P);
        pv8<<<32 * 16, 512, 0, stream>>>(P, hT, ctx, 16); // 512 blocks, LPT

        gemm8<<<dim3(128, 2), 512, 0, stream>>>(ctx, W3t, b3, o, 512, 1024, 1);
        head_logsoftmax<<<2048, 256, 0, stream>>>(o, W4, b4, out);
    } else if (ws_size >= TIER_A2) {
        u16* h1   = (u16*)(ws);
        u16* ctx  = h1;
        u16* h    = (u16*)(ws + MB64);
        u16* o    = h;
        u16* xb   = (u16*)(ws + 2 * MB64);
        u16* hT_c = xb;
        u16* P_c  = (u16*)(ws + 2 * MB64 + 32 * MiB);
        u16* W1t  = (u16*)(ws + 2 * MB64 + 72 * MiB);
        u16* W2t  = W1t + 512 * 1024;
        u16* W3t  = W2t + 1024 * 1024;

        prep_all<<<10240, 256, 0, stream>>>(x, xb, W1, W2, W3, W1t, W2t, W3t);
        gemm8<<<dim3(128, 4), 512, 0, stream>>>(xb, W1t, b1, h1, 1024, 512, 1);
        gemm8<<<dim3(128, 4), 512, 0, stream>>>(h1, W2t, b2, h,  1024, 1024, 1);

        for (int c = 0; c < 2; ++c) {
            const u16* hc  = h   + (size_t)c * 8 * S_ * DH;
            u16*       cxc = ctx + (size_t)c * 8 * S_ * DH;
            score8<<<(36 + 128) * 8, 512, 0, stream>>>(hc, P_c, hT_c, 8);
            softmax_rows<<<4096, 256, 0, stream>>>(P_c);
            pv_a<<<16 * 8 * 8, 256, 0, stream>>>(P_c, hT_c, cxc, 8);
        }

        gemm8<<<dim3(128, 2), 512, 0, stream>>>(ctx, W3t, b3, o, 512, 1024, 1);
        head_logsoftmax<<<2048, 256, 0, stream>>>(o, W4, b4, out);
    } else if (ws_size >= TIER_B) {
        u16* h1   = (u16*)(ws);
        u16* ctx  = h1;
        u16* h    = (u16*)(ws + MB64);
        u16* xb   = (u16*)(ws + 2 * MB64);
        u16* hT_c = xb;
        u16* P_c  = (u16*)(ws + 2 * MB64 + 16 * MiB);
        u16* o    = (u16*)(ws + 2 * MB64);
        u16* W1t  = (u16*)(ws + 3 * MB64);
        u16* W2t  = W1t + 512 * 1024;
        u16* W3t  = W2t + 1024 * 1024;

        prep_all<<<10240, 256, 0, stream>>>(x, xb, W1, W2, W3, W1t, W2t, W3t);
        gemm8<<<dim3(128, 4), 512, 0, stream>>>(xb, W1t, b1, h1, 1024, 512, 1);
        gemm8<<<dim3(128, 4), 512, 0, stream>>>(h1, W2t, b2, h,  1024, 1024, 1);

        for (int c = 0; c < 4; ++c) {
            const u16* hc  = h   + (size_t)c * 4 * S_ * DH;
            u16*       cxc = ctx + (size_t)c * 4 * S_ * DH;
            score8<<<(36 + 128) * 4, 512, 0, stream>>>(hc, P_c, hT_c, 4);
            softmax_rows<<<2048, 256, 0, stream>>>(P_c);
            pv_a<<<16 * 8 * 4, 256, 0, stream>>>(P_c, hT_c, cxc, 4);
        }

        gemm8<<<dim3(128, 2), 512, 0, stream>>>(ctx, W3t, b3, o, 512, 1024, 1);
        head_logsoftmax<<<2048, 256, 0, stream>>>(o, W4, b4, out);
    } else {
        u16* h    = (u16*)(ws);
        u16* hT_b = (u16*)(ws + MB64);
        u16* P_b  = (u16*)(ws + MB64 + 4 * MiB);
        u16* ctx_b= (u16*)(ws + MB64 + 12 * MiB);
        u16* o_b  = (u16*)(ws + MB64 + 16 * MiB);
        u16* W1t  = (u16*)(ws + MB64 + 18 * MiB);
        u16* W2t  = W1t + 512 * 1024;
        u16* W3t  = W2t + 1024 * 1024;
        u16* h1_b = P_b;

        wprep<<<2048, dim3(32, 8), 0, stream>>>(W1, W2, W3, W1t, W2t, W3t);

        for (int c = 0; c < 8; ++c) {
            const float* xc = x + (size_t)c * 4096 * DIN;
            u16*         hc = h + (size_t)c * 4096 * DH;
            gemm_bt_bias_relu<true ><<<dim3(32, 8), 256, 0, stream>>>(xc, W1t, b1, h1_b,
                                                                      4096, 1024, 512, 1);
            gemm_bt_bias_relu<false><<<dim3(32, 8), 256, 0, stream>>>(h1_b, W2t, b2, hc,
                                                                      4096, 1024, 1024, 1);
        }
        for (int b = 0; b < B_; ++b) {
            const u16* hb = h + (size_t)b * S_ * DH;
            transpose_v<<<dim3(16, 64, 1), 256, 0, stream>>>(hb, hT_b, 2048, 1024);
            score_a<<<dim3(16, 16, 1), 256, 0, stream>>>(hb, P_b);
            softmax_rows<<<512, 256, 0, stream>>>(P_b);
            pv_a<<<16 * 8, 256, 0, stream>>>(P_b, hT_b, ctx_b, 1);
            gemm_bt_bias_relu<false><<<dim3(16, 4), 256, 0, stream>>>(ctx_b, W3t, b3, o_b,
                                                                      2048, 512, 1024, 1);
            head_logsoftmax<<<128, 256, 0, stream>>>(o_b, W4, b4,
                                                     out + (size_t)b * S_ * DOUT);
        }
    }

    // pass-throughs (f32)
    size_t n_gv = (size_t)in_sizes[1], n_uv = (size_t)in_sizes[2];
    size_t o0 = (size_t)out_size - n_gv - n_uv;
    hipMemcpyAsync(out + o0,        gv, n_gv * 4, hipMemcpyDeviceToDevice, stream);
    hipMemcpyAsync(out + o0 + n_gv, uv, n_uv * 4, hipMemcpyDeviceToDevice, stream);
}

// Round 9
// 524.285 us; speedup vs baseline: 1.3019x; 1.0250x over previous
//
#include <hip/hip_runtime.h>
#include <stdint.h>

// Problem constants (fixed by reference)
#define B_   16
#define S_   2048
#define DIN  512
#define DH   1024
#define DOUT 10

typedef unsigned short u16;
typedef unsigned int   u32;

typedef __bf16 bf16_t;
typedef bf16_t bf16x8 __attribute__((ext_vector_type(8)));
typedef float  f32x4  __attribute__((ext_vector_type(4)));

#define MASKVAL (-3.0e4f)
// Packed-P geometry: row-block mi holds r4 = ((mi>>2)+1)*4 tiles of 128 cols.
// Tile-offset of row-block mi: S4(mi) = 4*(g+1)*(mi-2g), g = mi>>2.
// Pair property: rows [bi*256, bi*256+256) are CONTIGUOUS with lda = r4*128.
// Per-batch packed size = 160 tiles * 16384 u16 = 5 MiB.
// Pad-tile contract: score8 never writes pads. softmax_rows synthesizes pads
// on read (exp -> 0) and writes ZEROS only to tiles tj <= (mi|1) — the
// superset of what pv8 (pair-union: tiles 0..(mi|1)) and pv_a (tiles 0..mi)
// ever read. Tiles tj > (mi|1) are never read by anyone.
#define PZ_U16 ((size_t)160 * 16384)

__device__ __forceinline__ float b2f(u16 u) {
    union { u32 i; float f; } v; v.i = ((u32)u) << 16; return v.f;
}
__device__ __forceinline__ u16 f2b(float f) {
    union { float f; u32 i; } v; v.f = f;
    u32 u = v.i;
    u32 r = (u + 0x7FFFu + ((u >> 16) & 1u)) >> 16;  // RNE
    return (u16)r;
}
__device__ __forceinline__ u32 pack2(float a, float b) {
    return (u32)f2b(a) | ((u32)f2b(b) << 16);
}

__device__ __forceinline__ f32x4 mfma16(bf16x8 a, bf16x8 b, f32x4 c) {
    return __builtin_amdgcn_mfma_f32_16x16x32_bf16(a, b, c, 0, 0, 0);
}

// async global->LDS, 16B per lane; LDS dest = wave-uniform base + lane*16
__device__ __forceinline__ void load_lds16(const u16* g, u16* l) {
    __builtin_amdgcn_global_load_lds(
        (__attribute__((address_space(1))) u32*)(g),
        (__attribute__((address_space(3))) u32*)(l), 16, 0, 0);
}

// load 8 contiguous elements at element-index eidx as packed bf16x8 (uint4)
template<bool F32>
__device__ __forceinline__ uint4 ld8(const void* base, size_t eidx) {
    if constexpr (F32) {
        const float* p = (const float*)base + eidx;
        float4 f0 = *(const float4*)p;
        float4 f1 = *(const float4*)(p + 4);
        uint4 r;
        r.x = pack2(f0.x, f0.y); r.y = pack2(f0.z, f0.w);
        r.z = pack2(f1.x, f1.y); r.w = pack2(f1.z, f1.w);
        return r;
    } else {
        return *(const uint4*)((const u16*)base + eidx);
    }
}

// ---------------------------------------------------------------------------
// prep_all: fused input cvt (x f32->bf16, 8192 blocks) + weight prep
// (transpose+cvt W1/W2/W3, 2048 blocks). grid 10240 x 256.
// ---------------------------------------------------------------------------
__global__ __launch_bounds__(256) void prep_all(
    const float* __restrict__ x, u16* __restrict__ xb,
    const float* __restrict__ W1, const float* __restrict__ W2,
    const float* __restrict__ W3,
    u16* __restrict__ W1t, u16* __restrict__ W2t, u16* __restrict__ W3t)
{
    const int tid = threadIdx.x;
    if (blockIdx.x < 8192) {
        size_t e = ((size_t)blockIdx.x * 256 + tid) * 8;
        float4 f0 = *(const float4*)(x + e);
        float4 f1 = *(const float4*)(x + e + 4);
        uint4 r;
        r.x = pack2(f0.x, f0.y); r.y = pack2(f0.z, f0.w);
        r.z = pack2(f1.x, f1.y); r.w = pack2(f1.z, f1.w);
        *(uint4*)(xb + e) = r;
        return;
    }
    __shared__ u16 t[32][33];
    int i = blockIdx.x - 8192;
    const float* in; u16* out; int R, C, xt;
    if (i < 512)       { in = W1; out = W1t; R = 512;  C = 1024; xt = 32; }
    else if (i < 1536) { in = W2; out = W2t; R = 1024; C = 1024; xt = 32; i -= 512; }
    else               { in = W3; out = W3t; R = 1024; C = 512;  xt = 16; i -= 1536; }
    const int c0 = (i % xt) * 32, r0 = (i / xt) * 32;
    const int tx = tid & 31, ty = tid >> 5;
#pragma unroll
    for (int k = 0; k < 4; ++k)
        t[ty + k * 8][tx] = f2b(in[(size_t)(r0 + ty + k * 8) * C + c0 + tx]);
    __syncthreads();
#pragma unroll
    for (int k = 0; k < 4; ++k)
        out[(size_t)(c0 + ty + k * 8) * R + r0 + tx] = t[tx][ty + k * 8];
}

// wprep: standalone weight prep (tier-C). grid 2048 x (32,8).
__global__ __launch_bounds__(256) void wprep(
    const float* __restrict__ W1, const float* __restrict__ W2,
    const float* __restrict__ W3,
    u16* __restrict__ W1t, u16* __restrict__ W2t, u16* __restrict__ W3t)
{
    __shared__ u16 t[32][33];
    int i = blockIdx.x;
    const float* in; u16* out; int R, C, xt;
    if (i < 512)       { in = W1; out = W1t; R = 512;  C = 1024; xt = 32; }
    else if (i < 1536) { in = W2; out = W2t; R = 1024; C = 1024; xt = 32; i -= 512; }
    else               { in = W3; out = W3t; R = 1024; C = 512;  xt = 16; i -= 1536; }
    const int c0 = (i % xt) * 32, r0 = (i / xt) * 32;
    const int tx = threadIdx.x, ty = threadIdx.y;
#pragma unroll
    for (int k = 0; k < 4; ++k)
        t[ty + k * 8][tx] = f2b(in[(size_t)(r0 + ty + k * 8) * C + c0 + tx]);
    __syncthreads();
#pragma unroll
    for (int k = 0; k < 4; ++k)
        out[(size_t)(c0 + ty + k * 8) * R + r0 + tx] = t[tx][ty + k * 8];
}

// ===========================================================================
// 8-phase 256x256 machinery (T2 swizzle + T3/T4 counted vmcnt + T5 setprio).
// LDS: AS/BS[2 dbuf][256 rows][64 cols] bf16. Load-unit = 64 rows x 64 cols.
// Swizzle: linear slot (row, c) holds data chunk c ^ (row&7) (16B chunks);
// write side pre-swizzles the global source chunk, read side XORs the chunk.
// ===========================================================================
template<int QR>
__device__ __forceinline__ void rda(bf16x8 (&a)[4][2], const u16* T,
                                    int arow, int quad) {
#pragma unroll
    for (int mf = 0; mf < 4; ++mf) {
        const int row = arow + QR * 64 + mf * 16;
        const int sw = row & 7;
#pragma unroll
        for (int ks = 0; ks < 2; ++ks)
            a[mf][ks] = *(const bf16x8*)(T + row * 64 + (((ks * 4 + quad) ^ sw) << 3));
    }
}

template<int QC>
__device__ __forceinline__ void rdb(bf16x8 (&b)[2][2], const u16* T,
                                    int brow, int quad) {
#pragma unroll
    for (int nf = 0; nf < 2; ++nf) {
        const int row = brow + QC * 128 + nf * 16;
        const int sw = row & 7;
#pragma unroll
        for (int ks = 0; ks < 2; ++ks)
            b[nf][ks] = *(const bf16x8*)(T + row * 64 + (((ks * 4 + quad) ^ sw) << 3));
    }
}

template<int QR, int QC>
__device__ __forceinline__ void mmq(f32x4 (&acc)[2][2][4][2],
                                    const bf16x8 (&a)[4][2],
                                    const bf16x8 (&b)[2][2]) {
#pragma unroll
    for (int ks = 0; ks < 2; ++ks)
#pragma unroll
        for (int mf = 0; mf < 4; ++mf)
#pragma unroll
            for (int nf = 0; nf < 2; ++nf)
                acc[QR][QC][mf][nf] = mfma16(a[mf][ks], b[nf][ks], acc[QR][QC][mf][nf]);
}

#define G8BAR()  __builtin_amdgcn_s_barrier()
#define G8LGKM() do { asm volatile("s_waitcnt lgkmcnt(0)" ::: "memory"); \
                      __builtin_amdgcn_sched_barrier(0); } while (0)
#define G8VMC4() asm volatile("s_waitcnt vmcnt(4)" ::: "memory")

// The 8-phase K-loop body, parameterized on staging macros STGA/STGB.
// Phases P1-P4 consume buf0 (quadrants (0,0),(0,1),(1,0),(1,1)), P5-P8 buf1.
// Stage stream (2 units/phase), each unit staged >=1 end-barrier after its
// last reader retired; vmcnt(4) ONLY at P4/P8 end.
#define G8_LOOP_BODY(NT_)                                                     \
    const int NI = (NT_) >> 1;                                                \
    for (int i = 0; i < NI; ++i) {                                            \
        const int t1 = 2 * i + 1, t2 = 2 * i + 2, t3 = 2 * i + 3;             \
        rda<0>(a, AS_[0], arow, quad); rdb<0>(b0r, BS_[0], brow, quad);       \
        STGB(1, 2, t1); STGB(1, 3, t1);                                       \
        G8BAR(); G8LGKM();                                                    \
        __builtin_amdgcn_s_setprio(1); mmq<0, 0>(acc, a, b0r);                \
        __builtin_amdgcn_s_setprio(0); G8BAR();                               \
        rdb<1>(b1r, BS_[0], brow, quad);                                      \
        STGA(1, 1, t1); STGA(1, 3, t1);                                       \
        G8BAR(); G8LGKM();                                                    \
        __builtin_amdgcn_s_setprio(1); mmq<0, 1>(acc, a, b1r);                \
        __builtin_amdgcn_s_setprio(0); G8BAR();                               \
        rda<1>(a, AS_[0], arow, quad);                                        \
        if (t2 < (NT_)) { STGA(0, 0, t2); STGA(0, 2, t2); }                   \
        G8BAR(); G8LGKM();                                                    \
        __builtin_amdgcn_s_setprio(1); mmq<1, 0>(acc, a, b0r);                \
        __builtin_amdgcn_s_setprio(0); G8BAR();                               \
        if (t2 < (NT_)) { STGB(0, 0, t2); STGB(0, 1, t2); }                   \
        G8BAR();                                                              \
        __builtin_amdgcn_s_setprio(1); mmq<1, 1>(acc, a, b1r);                \
        __builtin_amdgcn_s_setprio(0);                                        \
        G8VMC4(); G8BAR();                                                    \
        rda<0>(a, AS_[1], arow, quad); rdb<0>(b0r, BS_[1], brow, quad);       \
        if (t2 < (NT_)) { STGB(0, 2, t2); STGB(0, 3, t2); }                   \
        G8BAR(); G8LGKM();                                                    \
        __builtin_amdgcn_s_setprio(1); mmq<0, 0>(acc, a, b0r);                \
        __builtin_amdgcn_s_setprio(0); G8BAR();                               \
        rdb<1>(b1r, BS_[1], brow, quad);                                      \
        if (t2 < (NT_)) { STGA(0, 1, t2); STGA(0, 3, t2); }                   \
        G8BAR(); G8LGKM();                                                    \
        __builtin_amdgcn_s_setprio(1); mmq<0, 1>(acc, a, b1r);                \
        __builtin_amdgcn_s_setprio(0); G8BAR();                               \
        rda<1>(a, AS_[1], arow, quad);                                        \
        if (t3 < (NT_)) { STGA(1, 0, t3); STGA(1, 2, t3); }                   \
        G8BAR(); G8LGKM();                                                    \
        __builtin_amdgcn_s_setprio(1); mmq<1, 0>(acc, a, b0r);                \
        __builtin_amdgcn_s_setprio(0); G8BAR();                               \
        if (t3 < (NT_)) { STGB(1, 0, t3); STGB(1, 1, t3); }                   \
        G8BAR();                                                              \
        __builtin_amdgcn_s_setprio(1); mmq<1, 1>(acc, a, b1r);                \
        __builtin_amdgcn_s_setprio(0);                                        \
        G8VMC4(); G8BAR();                                                    \
    }

// common per-thread decomposition + acc init for the 8-phase kernels
#define G8_SETUP()                                                            \
    const int tid  = threadIdx.x;                                             \
    const int lane = tid & 63;                                                \
    const int w    = tid >> 6;                                                \
    const int wm   = w >> 2, wn = w & 3;                                      \
    const int quad = lane >> 4, l15 = lane & 15;                              \
    const int rg = tid >> 3;                                                  \
    const int ch = (lane & 7) ^ ((lane >> 3) & 7);                            \
    const int wslot = w * 512;                                                \
    f32x4 acc[2][2][4][2];                                                    \
    _Pragma("unroll") for (int p_ = 0; p_ < 2; ++p_)                          \
    _Pragma("unroll") for (int q_ = 0; q_ < 2; ++q_)                          \
    _Pragma("unroll") for (int m_ = 0; m_ < 4; ++m_)                          \
    _Pragma("unroll") for (int n_ = 0; n_ < 2; ++n_)                          \
        acc[p_][q_][m_][n_] = (f32x4){0.f, 0.f, 0.f, 0.f};                    \
    bf16x8 a[4][2], b0r[2][2], b1r[2][2];                                     \
    const int arow = wm * 128 + l15;                                          \
    const int brow = wn * 32 + l15;

#define G8_PROLOGUE()                                                         \
    STGA(0, 0, 0); STGA(0, 1, 0); STGA(0, 2, 0); STGA(0, 3, 0);               \
    STGB(0, 0, 0); STGB(0, 1, 0); STGB(0, 2, 0); STGB(0, 3, 0);               \
    STGA(1, 0, 1); STGA(1, 2, 1);                                             \
    STGB(1, 0, 1); STGB(1, 1, 1);                                             \
    G8VMC4(); G8BAR();

// ===========================================================================
// gemm8: C[M,N] = relu(A[M,K] @ Bt[N,K]^T + bias[N]), bf16.
// grid = (M/256, N/256), block = 512. Requires K % 128 == 0.
// ===========================================================================
__global__ __launch_bounds__(512, 2) void gemm8(
    const u16* __restrict__ A, const u16* __restrict__ Bt,
    const float* __restrict__ bias, u16* __restrict__ C,
    int N, int K, int do_relu)
{
    __shared__ __attribute__((aligned(16))) u16 AS_[2][16384];
    __shared__ __attribute__((aligned(16))) u16 BS_[2][16384];

    G8_SETUP()
    const int m0 = blockIdx.x * 256, n0 = blockIdx.y * 256;
    const u16* gA = A  + (size_t)(m0 + rg) * K + ch * 8;
    const u16* gB = Bt + (size_t)(n0 + rg) * K + ch * 8;

#define STGA(BUF, U, T) load_lds16(gA + (size_t)(U) * 64 * K + (T) * 64, \
                                   &AS_[BUF][(U) * 4096 + wslot])
#define STGB(BUF, U, T) load_lds16(gB + (size_t)(U) * 64 * K + (T) * 64, \
                                   &BS_[BUF][(U) * 4096 + wslot])

    const int NT = K >> 6;
    G8_PROLOGUE()
    G8_LOOP_BODY(NT)
#undef STGA
#undef STGB

    // epilogue: bias + relu + bf16 store
    const int r0 = quad * 4;
#pragma unroll
    for (int qc = 0; qc < 2; ++qc)
#pragma unroll
    for (int nf = 0; nf < 2; ++nf) {
        const int col = n0 + qc * 128 + wn * 32 + nf * 16 + l15;
        const float bv = bias[col];
#pragma unroll
        for (int qr = 0; qr < 2; ++qr)
#pragma unroll
        for (int mf = 0; mf < 4; ++mf) {
            const int rowb = m0 + wm * 128 + qr * 64 + mf * 16 + r0;
#pragma unroll
            for (int r = 0; r < 4; ++r) {
                float v = acc[qr][qc][mf][nf][r] + bv;
                if (do_relu) v = fmaxf(v, 0.f);
                C[(size_t)(rowb + r) * N + col] = f2b(v);
            }
        }
    }
}

// ===========================================================================
// score8: causal score GEMM (8-phase 256x256 template) + MERGED hT transpose.
// Grid = 36*nb score blocks followed by 128*nb transpose blocks.
//   Score block (z, t): triangular (bi,bj), bj <= bi -> 256x256 score tile
//     into packed P (pad tiles NOT written; softmax synthesizes them).
//   Transpose block (z, r): 8 tiles of the h[z] (2048x1024) -> hT[z]
//     (1024x2048) bf16 transpose; cx = r&15 (64-col strip), ry0 = (r>>4)*8.
//     These dispatch LAST and backfill the idle CUs of score's partial
//     3rd round (576 blocks on 256 CUs).
// XCD swizzle (T1, when nb%8==0): p -> xcd=p&7, slot=p>>3. Score AND
// transpose blocks of batch z map to the SAME XCD (z === xcd mod 8), so
// transpose reads of h[z] hit the XCD L2 warmed by the score blocks.
// ===========================================================================
__global__ __launch_bounds__(512, 2) void score8(
    const u16* __restrict__ h, u16* __restrict__ P, u16* __restrict__ hT,
    int nbb)
{
    __shared__ __attribute__((aligned(16))) u16 AS_[2][16384];
    __shared__ __attribute__((aligned(16))) u16 BS_[2][16384];

    int z, t = 0, r = 0;
    bool isT = false;
    if ((nbb & 7) == 0) {
        const int xcd = blockIdx.x & 7, slot = blockIdx.x >> 3;
        const int sth = (36 * nbb) >> 3;         // score slots per xcd
        if (slot < sth) { z = (slot / 36) * 8 + xcd; t = slot % 36; }
        else { const int ql = slot - sth; z = (ql >> 7) * 8 + xcd; r = ql & 127; isT = true; }
    } else {
        const int ns = 36 * nbb;
        if ((int)blockIdx.x < ns) { z = blockIdx.x / 36; t = blockIdx.x % 36; }
        else { const int q = blockIdx.x - ns; z = q >> 7; r = q & 127; isT = true; }
    }

    if (isT) {
        // ---- transpose tail: 8 tiles (32 rows x 64 cols each), 2 per pass
        const int cx = r & 15, ry0 = (r >> 4) * 8;
        const u16* hz  = h  + (size_t)z * S_ * DH;
        u16*       hTz = hT + (size_t)z * DH * S_;
        const int th  = threadIdx.x;
        const int sel = th >> 8, tt = th & 255;
        u16* st = (u16*)AS_[0] + sel * 2112;     // [64][33] u16 per tile
#pragma unroll
        for (int jj = 0; jj < 4; ++jj) {
            const int ry = ry0 + 2 * jj + sel;
            {
                const int row = tt >> 3, chv = tt & 7;
                uint4 v = *(const uint4*)&hz[(size_t)(ry * 32 + row) * DH
                                             + cx * 64 + chv * 8];
                const u16* pv = (const u16*)&v;
#pragma unroll
                for (int k = 0; k < 8; ++k) st[(chv * 8 + k) * 33 + row] = pv[k];
            }
            __syncthreads();
            {
                const int oc = tt >> 2, r4 = tt & 3;
                uint4 v; u16* pv = (u16*)&v;
#pragma unroll
                for (int k = 0; k < 8; ++k) pv[k] = st[oc * 33 + r4 * 8 + k];
                *(uint4*)&hTz[(size_t)(cx * 64 + oc) * S_ + ry * 32 + r4 * 8] = v;
            }
            __syncthreads();
        }
        return;
    }

    int bi = 0;
    while ((bi + 1) * (bi + 2) / 2 <= t) ++bi;
    const int bj = t - bi * (bi + 1) / 2;
    const bool diag = (bi == bj);

    G8_SETUP()
    const int m0 = bi * 256, n0 = bj * 256;
    const u16* hz = h + (size_t)z * S_ * DH;
    const u16* gA = hz + (size_t)(m0 + rg) * DH + ch * 8;
    const u16* gB = hz + (size_t)(n0 + rg) * DH + ch * 8;

#define STGA(BUF, U, T) load_lds16(gA + (size_t)(U) * 64 * DH + (T) * 64, \
                                   &AS_[BUF][(U) * 4096 + wslot])
#define STGB(BUF, U, T) load_lds16(gB + (size_t)(U) * 64 * DH + (T) * 64, \
                                   &BS_[BUF][(U) * 4096 + wslot])

    const int NT = DH >> 6;      // 16
    G8_PROLOGUE()
    G8_LOOP_BODY(NT)
#undef STGA
#undef STGB

    // epilogue: scatter into packed P with causal mask on diagonal blocks.
    const int mi = 2 * bi + wm;
    const int g  = mi >> 2;
    u16* Pz = P + (size_t)z * PZ_U16
                + (size_t)(4 * (g + 1) * (mi - 2 * g)) * 16384;
    const size_t rstride = (size_t)(4 * (g + 1)) * 128;

    const int r0 = quad * 4;
#pragma unroll
    for (int qc = 0; qc < 2; ++qc) {
        const int ni = 2 * bj + qc;
#pragma unroll
        for (int nf = 0; nf < 2; ++nf) {
            const int cl = wn * 32 + nf * 16 + l15;
            const int colg = n0 + qc * 128 + cl;
#pragma unroll
            for (int qr = 0; qr < 2; ++qr)
#pragma unroll
            for (int mf = 0; mf < 4; ++mf) {
                const int rl = qr * 64 + mf * 16 + r0;
                const int rowg = m0 + wm * 128 + rl;
#pragma unroll
                for (int rr = 0; rr < 4; ++rr) {
                    float v = acc[qr][qc][mf][nf][rr];
                    if (diag && colg > rowg + rr) v = MASKVAL;
                    Pz[(size_t)(rl + rr) * rstride + ni * 128 + cl] = f2b(v);
                }
            }
        }
    }
}

// ===========================================================================
// pv8: ctx[z] = P[z] @ V[z] on the 8-phase 256x256 template.
// Packed-P pair-contiguity: rows [bi*256, bi*256+256) form a dense row-major
// matrix with lda = ((bi>>1)+1)*512. REAL-K TRIM: only tiles 0..(2bi+1) can
// be nonzero (union of the pair's causal rows + the one written pad column),
// so the K-loop runs NT = 4*(bi+1) 64-wide tiles (all even) instead of the
// padded lda/64 — trailing pad tiles are exact zeros and are skipped
// (bitwise-identical: x + 0*V = x, ascending-K order preserved).
// grid.x = nb*32, LPT: bi = 7 - idx/(4*nb); rem: nj = rem&3, z = rem>>2.
// ===========================================================================
__global__ __launch_bounds__(512, 2) void pv8(
    const u16* __restrict__ P, const u16* __restrict__ hT,
    u16* __restrict__ ctx, int nb)
{
    __shared__ __attribute__((aligned(16))) u16 AS_[2][16384];
    __shared__ __attribute__((aligned(16))) u16 BS_[2][16384];

    const int per_bi = 4 * nb;
    const int bi  = 7 - (int)(blockIdx.x / per_bi);  // LPT heavy-first
    const int rem = blockIdx.x % per_bi;
    const int nj  = rem & 3;
    const int z   = rem >> 2;

    const int g   = bi >> 1;
    const int lda = (g + 1) * 512;               // padded row stride (r4*128)
    const int NT  = 4 * (bi + 1);                // real K tiles: 4,8,...,32
    const int n0  = nj * 256;

    const u16* Az = P + (size_t)z * PZ_U16
                      + (size_t)(4 * (g + 1) * (2 * bi - 2 * g)) * 16384;
    const u16* Bz = hT + (size_t)z * DH * S_;
    u16*       C  = ctx + (size_t)z * S_ * DH;

    G8_SETUP()
    const u16* gA = Az + (size_t)rg * lda + ch * 8;
    const u16* gB = Bz + (size_t)(n0 + rg) * S_ + ch * 8;

#define STGA(BUF, U, T) load_lds16(gA + (size_t)(U) * 64 * lda + (T) * 64, \
                                   &AS_[BUF][(U) * 4096 + wslot])
#define STGB(BUF, U, T) load_lds16(gB + (size_t)(U) * 64 * S_ + (T) * 64, \
                                   &BS_[BUF][(U) * 4096 + wslot])

    G8_PROLOGUE()
    G8_LOOP_BODY(NT)
#undef STGA
#undef STGB

    // epilogue: plain bf16 store into ctx
    const int r0 = quad * 4;
#pragma unroll
    for (int qc = 0; qc < 2; ++qc)
#pragma unroll
    for (int nf = 0; nf < 2; ++nf) {
        const int col = n0 + qc * 128 + wn * 32 + nf * 16 + l15;
#pragma unroll
        for (int qr = 0; qr < 2; ++qr)
#pragma unroll
        for (int mf = 0; mf < 4; ++mf) {
            const int rowb = bi * 256 + wm * 128 + qr * 64 + mf * 16 + r0;
#pragma unroll
            for (int r = 0; r < 4; ++r)
                C[(size_t)(rowb + r) * DH + col] = f2b(acc[qr][qc][mf][nf][r]);
        }
    }
}

// ---------------------------------------------------------------------------
// ASYNC score GEMM into PACKED P (tier-C fallback): row-block mi = causal
// tiles ni<=mi, padded to r4 tiles; pad tiles get MASKVAL. grid (16, 16, nb).
// ---------------------------------------------------------------------------
__global__ __launch_bounds__(256) void score_a(
    const u16* __restrict__ h, u16* __restrict__ P)
{
    __shared__ __attribute__((aligned(16))) u16 As[128 * 32];
    __shared__ __attribute__((aligned(16))) u16 Bs[128 * 32];

    const int mi = 15 - blockIdx.x;              // LPT: heavy rows first
    const int ni = blockIdx.y;
    const int g  = mi >> 2;
    const int r4 = (g + 1) * 4;
    if (ni >= r4) return;

    const int tid = threadIdx.x;
    u16* Pz = P + (size_t)blockIdx.z * PZ_U16
                + (size_t)(4 * (g + 1) * (mi - 2 * g)) * 16384;
    const size_t rstride = (size_t)r4 * 128;

    if (ni > mi) {                               // pad tile: MASKVAL fill
        const u16 mb = f2b(MASKVAL);
        const u32 m2 = (u32)mb | ((u32)mb << 16);
        uint4 mv; mv.x = m2; mv.y = m2; mv.z = m2; mv.w = m2;
#pragma unroll
        for (int i = 0; i < 8; ++i) {
            int q = tid + i * 256;
            int row = q >> 4, cl = (q & 15) * 8;
            *(uint4*)&Pz[(size_t)row * rstride + ni * 128 + cl] = mv;
        }
        return;
    }

    const int m0 = mi * 128, n0 = ni * 128;
    const u16* A = h + (size_t)blockIdx.z * S_ * DH;

    const int lane = tid & 63;
    const int w    = tid >> 6;
    const int wm   = w >> 1, wn = w & 1;
    const int quad = lane >> 4, l15 = lane & 15;

    const int c0 = tid, c1 = tid + 256;
    const u16* gA0 = A + ((size_t)(m0 + (c0 >> 2)) * DH + (c0 & 3) * 8);
    const u16* gA1 = A + ((size_t)(m0 + (c1 >> 2)) * DH + (c1 & 3) * 8);
    const u16* gB0 = A + ((size_t)(n0 + (c0 >> 2)) * DH + (c0 & 3) * 8);
    const u16* gB1 = A + ((size_t)(n0 + (c1 >> 2)) * DH + (c1 & 3) * 8);
    u16* lA0 = &As[(w * 64) * 8];
    u16* lA1 = &As[(256 + w * 64) * 8];
    u16* lB0 = &Bs[(w * 64) * 8];
    u16* lB1 = &Bs[(256 + w * 64) * 8];

    f32x4 acc[4][4];
#pragma unroll
    for (int i = 0; i < 4; ++i)
#pragma unroll
        for (int j = 0; j < 4; ++j) acc[i][j] = (f32x4){0.f, 0.f, 0.f, 0.f};

    const int nk = DH >> 5;
    for (int kk = 0; kk < nk; ++kk) {
        load_lds16(gA0, lA0); load_lds16(gA1, lA1);
        load_lds16(gB0, lB0); load_lds16(gB1, lB1);
        gA0 += 32; gA1 += 32; gB0 += 32; gB1 += 32;
        __syncthreads();
        bf16x8 af[4], bfr[4];
#pragma unroll
        for (int i = 0; i < 4; ++i)
            af[i] = *(const bf16x8*)&As[(wm * 64 + i * 16 + l15) * 32 + quad * 8];
#pragma unroll
        for (int j = 0; j < 4; ++j)
            bfr[j] = *(const bf16x8*)&Bs[(wn * 64 + j * 16 + l15) * 32 + quad * 8];
#pragma unroll
        for (int i = 0; i < 4; ++i)
#pragma unroll
            for (int j = 0; j < 4; ++j)
                acc[i][j] = mfma16(af[i], bfr[j], acc[i][j]);
        __syncthreads();
    }

    const int r0 = quad * 4;
#pragma unroll
    for (int j = 0; j < 4; ++j) {
        int cl = wn * 64 + j * 16 + l15;
#pragma unroll
        for (int i = 0; i < 4; ++i) {
            int rl = wm * 64 + i * 16 + r0;
#pragma unroll
            for (int r = 0; r < 4; ++r) {
                int row = rl + r;
                float v = (n0 + cl <= m0 + row) ? acc[i][j][r] : MASKVAL;
                Pz[(size_t)row * rstride + ni * 128 + cl] = f2b(v);
            }
        }
    }
}

// ---------------------------------------------------------------------------
// softmax_rows: in-place row softmax of packed P. One wave per row.
// Pad tiles (ni > mi) are SYNTHESIZED on read (v = MASKVAL -> exp = 0.0f).
// WRITE TRIM: zeros are written only to tiles tj <= (mi|1) — the superset of
// what pv8 (pair-union 0..(mi|1)) and pv_a (0..mi) read; tiles beyond that
// are never read by any consumer.
// ---------------------------------------------------------------------------
__global__ __launch_bounds__(256) void softmax_rows(u16* __restrict__ P)
{
    const int tid = threadIdx.x;
    const int lane = tid & 63, w = tid >> 6;
    const int quad = lane >> 4;
    const size_t row = (size_t)blockIdx.x * 4 + w;
    const int z    = (int)(row >> 11);
    const int rloc = (int)(row & (S_ - 1));
    const int mi = rloc >> 7, g = mi >> 2;
    const int kb = g + 1;
    u16* p = P + (size_t)z * PZ_U16
               + (size_t)(4 * (g + 1) * (mi - 2 * g)) * 16384
               + (size_t)(rloc & 127) * ((g + 1) * 4 * 128);
    float v[32];
    float m = -1e30f;
    for (int k = 0; k < kb; ++k) {
        if (k * 4 + quad <= mi) {                // real tile for this lane
            uint4 u = *(const uint4*)&p[k * 512 + lane * 8];
            const u32* uu = (const u32*)&u;
#pragma unroll
            for (int i = 0; i < 4; ++i) {
                float a = b2f((u16)(uu[i] & 0xFFFFu));
                float b = b2f((u16)(uu[i] >> 16));
                v[k * 8 + 2 * i] = a; v[k * 8 + 2 * i + 1] = b;
                m = fmaxf(m, fmaxf(a, b));
            }
        } else {                                 // pad tile: synthesize
#pragma unroll
            for (int i = 0; i < 8; ++i) v[k * 8 + i] = MASKVAL;
        }
    }
#pragma unroll
    for (int off = 32; off >= 1; off >>= 1) m = fmaxf(m, __shfl_xor(m, off, 64));
    float s = 0.f;
    for (int k = 0; k < kb; ++k)
#pragma unroll
        for (int i = 0; i < 8; ++i) {
            float e = __expf(v[k * 8 + i] - m);
            v[k * 8 + i] = e; s += e;
        }
#pragma unroll
    for (int off = 32; off >= 1; off >>= 1) s += __shfl_xor(s, off, 64);
    float inv = 1.0f / s;
    const int wlim = mi | 1;                     // last tile any consumer reads
    for (int k = 0; k < kb; ++k) {
        if (k * 4 + quad <= wlim) {
            uint4 u; u32* uu = (u32*)&u;
#pragma unroll
            for (int i = 0; i < 4; ++i)
                uu[i] = pack2(v[k * 8 + 2 * i] * inv, v[k * 8 + 2 * i + 1] * inv);
            *(uint4*)&p[k * 512 + lane * 8] = u;
        }
    }
}

// ---------------------------------------------------------------------------
// ASYNC pv GEMM (128x128 tile, A2/B/C fallback), LPT 1D grid.
// grid.x = 16*8*nb; idx -> mi = 15 - idx/(8*nb); sub = idx%(8*nb):
// n = sub&7, z = sub>>3. nk = (mi+1)*4 (reads ONLY real tiles 0..mi).
// ---------------------------------------------------------------------------
__global__ __launch_bounds__(256) void pv_a(
    const u16* __restrict__ P, const u16* __restrict__ hT, u16* __restrict__ ctx,
    int nb)
{
    __shared__ __attribute__((aligned(16))) u16 As[128 * 32];
    __shared__ __attribute__((aligned(16))) u16 Bs[128 * 32];

    const int idx = blockIdx.x;
    const int per_mi = 8 * nb;
    const int mi = 15 - (idx / per_mi);          // LPT: heavy row-blocks first
    const int sub = idx % per_mi;
    const int nblk = sub & 7;
    const int z    = sub >> 3;
    const int g = mi >> 2;
    const int m0 = mi * 128;
    const int n0 = nblk * 128;
    const size_t rstride = (size_t)((g + 1) * 4) * 128;
    const u16* A  = P  + (size_t)z * PZ_U16
                       + (size_t)(4 * (g + 1) * (mi - 2 * g)) * 16384;
    const u16* Bt = hT + (size_t)z * DH * S_;
    u16*      C   = ctx + (size_t)z * S_ * DH;

    const int tid  = threadIdx.x;
    const int lane = tid & 63;
    const int w    = tid >> 6;
    const int wm   = w >> 1, wn = w & 1;
    const int quad = lane >> 4, l15 = lane & 15;

    const int c0 = tid, c1 = tid + 256;
    const u16* gA0 = A  + ((size_t)(c0 >> 2) * rstride + (c0 & 3) * 8);
    const u16* gA1 = A  + ((size_t)(c1 >> 2) * rstride + (c1 & 3) * 8);
    const u16* gB0 = Bt + ((size_t)(n0 + (c0 >> 2)) * S_ + (c0 & 3) * 8);
    const u16* gB1 = Bt + ((size_t)(n0 + (c1 >> 2)) * S_ + (c1 & 3) * 8);
    u16* lA0 = &As[(w * 64) * 8];
    u16* lA1 = &As[(256 + w * 64) * 8];
    u16* lB0 = &Bs[(w * 64) * 8];
    u16* lB1 = &Bs[(256 + w * 64) * 8];

    f32x4 acc[4][4];
#pragma unroll
    for (int i = 0; i < 4; ++i)
#pragma unroll
        for (int j = 0; j < 4; ++j) acc[i][j] = (f32x4){0.f, 0.f, 0.f, 0.f};

    const int nk = (mi + 1) * 4;
    for (int kk = 0; kk < nk; ++kk) {
        load_lds16(gA0, lA0); load_lds16(gA1, lA1);
        load_lds16(gB0, lB0); load_lds16(gB1, lB1);
        gA0 += 32; gA1 += 32; gB0 += 32; gB1 += 32;
        __syncthreads();
        bf16x8 af[4], bfr[4];
#pragma unroll
        for (int i = 0; i < 4; ++i)
            af[i] = *(const bf16x8*)&As[(wm * 64 + i * 16 + l15) * 32 + quad * 8];
#pragma unroll
        for (int j = 0; j < 4; ++j)
            bfr[j] = *(const bf16x8*)&Bs[(wn * 64 + j * 16 + l15) * 32 + quad * 8];
#pragma unroll
        for (int i = 0; i < 4; ++i)
#pragma unroll
            for (int j = 0; j < 4; ++j)
                acc[i][j] = mfma16(af[i], bfr[j], acc[i][j]);
        __syncthreads();
    }

    const int r0 = quad * 4;
#pragma unroll
    for (int j = 0; j < 4; ++j) {
        int col = n0 + wn * 64 + j * 16 + l15;
#pragma unroll
        for (int i = 0; i < 4; ++i) {
            int rowb = m0 + wm * 64 + i * 16 + r0;
#pragma unroll
            for (int r = 0; r < 4; ++r)
                C[(size_t)(rowb + r) * DH + col] = f2b(acc[i][j][r]);
        }
    }
}

// ---------------------------------------------------------------------------
// SYNC-staged GEMM (tier-C fallback only; A may be f32)
// ---------------------------------------------------------------------------
template<bool AF32>
__global__ __launch_bounds__(256) void gemm_bt_bias_relu(
    const void* __restrict__ A, const u16* __restrict__ Bt,
    const float* __restrict__ bias, u16* __restrict__ C,
    int M, int N, int K, int do_relu)
{
    __shared__ __attribute__((aligned(16))) u16 As[128 * 32];
    __shared__ __attribute__((aligned(16))) u16 Bs[128 * 32];

    const int tid  = threadIdx.x;
    const int lane = tid & 63;
    const int w    = tid >> 6;
    const int wm   = w >> 1, wn = w & 1;
    const int quad = lane >> 4, l15 = lane & 15;

    const int m0 = blockIdx.x * 128;
    const int n0 = blockIdx.y * 128;

    const int c0 = tid, c1 = tid + 256;
    size_t eA0 = (size_t)(m0 + (c0 >> 2)) * K + (c0 & 3) * 8;
    size_t eA1 = (size_t)(m0 + (c1 >> 2)) * K + (c1 & 3) * 8;
    size_t eB0 = (size_t)(n0 + (c0 >> 2)) * K + (c0 & 3) * 8;
    size_t eB1 = (size_t)(n0 + (c1 >> 2)) * K + (c1 & 3) * 8;

    f32x4 acc[4][4];
#pragma unroll
    for (int i = 0; i < 4; ++i)
#pragma unroll
        for (int j = 0; j < 4; ++j) acc[i][j] = (f32x4){0.f, 0.f, 0.f, 0.f};

    uint4 va0 = ld8<AF32>(A, eA0), va1 = ld8<AF32>(A, eA1);
    uint4 vb0 = ld8<false>(Bt, eB0), vb1 = ld8<false>(Bt, eB1);

    const int nk = K >> 5;
    for (int kk = 0; kk < nk; ++kk) {
        __syncthreads();
        *(uint4*)&As[c0 * 8] = va0;
        *(uint4*)&As[c1 * 8] = va1;
        *(uint4*)&Bs[c0 * 8] = vb0;
        *(uint4*)&Bs[c1 * 8] = vb1;
        if (kk + 1 < nk) {
            eA0 += 32; eA1 += 32; eB0 += 32; eB1 += 32;
            va0 = ld8<AF32>(A, eA0); va1 = ld8<AF32>(A, eA1);
            vb0 = ld8<false>(Bt, eB0); vb1 = ld8<false>(Bt, eB1);
        }
        __syncthreads();
        bf16x8 af[4], bfr[4];
#pragma unroll
        for (int i = 0; i < 4; ++i)
            af[i] = *(const bf16x8*)&As[(wm * 64 + i * 16 + l15) * 32 + quad * 8];
#pragma unroll
        for (int j = 0; j < 4; ++j)
            bfr[j] = *(const bf16x8*)&Bs[(wn * 64 + j * 16 + l15) * 32 + quad * 8];
#pragma unroll
        for (int i = 0; i < 4; ++i)
#pragma unroll
            for (int j = 0; j < 4; ++j)
                acc[i][j] = mfma16(af[i], bfr[j], acc[i][j]);
    }

    const int r0 = quad * 4;
#pragma unroll
    for (int j = 0; j < 4; ++j) {
        int col = n0 + wn * 64 + j * 16 + l15;
        float bv = bias[col];
#pragma unroll
        for (int i = 0; i < 4; ++i) {
            int rowb = m0 + wm * 64 + i * 16 + r0;
#pragma unroll
            for (int r = 0; r < 4; ++r) {
                float v = acc[i][j][r] + bv;
                if (do_relu) v = fmaxf(v, 0.f);
                C[(size_t)(rowb + r) * N + col] = f2b(v);
            }
        }
    }
}

// ---------------------------------------------------------------------------
// transpose_v: vectorized batched bf16 transpose, in [z][R][C] -> out [z][C][R].
// Tile 32 rows x 64 cols, 256 threads, uint4 global loads/stores.
// grid (C/64, R/32, nb). (tier-C only; A-tiers use the merged score8 tail)
// ---------------------------------------------------------------------------
__global__ __launch_bounds__(256) void transpose_v(
    const u16* __restrict__ in, u16* __restrict__ out, int R, int C)
{
    __shared__ u16 st[64][33];
    const u16* ip = in  + (size_t)blockIdx.z * R * C;
    u16*       op = out + (size_t)blockIdx.z * R * C;
    const int c0 = blockIdx.x * 64, r0 = blockIdx.y * 32;
    const int t = threadIdx.x;
    {
        const int row = t >> 3, ch = t & 7;       // 32 rows x 8 chunks
        uint4 v = *(const uint4*)&ip[(size_t)(r0 + row) * C + c0 + ch * 8];
        const u16* pv = (const u16*)&v;
#pragma unroll
        for (int k = 0; k < 8; ++k) st[ch * 8 + k][row] = pv[k];
    }
    __syncthreads();
    {
        const int oc = t >> 2, r4 = t & 3;        // 64 out-rows x 4 chunks
        uint4 v; u16* pv = (u16*)&v;
#pragma unroll
        for (int k = 0; k < 8; ++k) pv[k] = st[oc][r4 * 8 + k];
        *(uint4*)&op[(size_t)(c0 + oc) * R + r0 + r4 * 8] = v;
    }
}

// ---------------------------------------------------------------------------
// head: out[row,:] = log_softmax(o[row,:] @ W4 + b4). One wave per row,
// 4 rows per wave (16 rows/block) to amortize the W4 LDS staging.
// ---------------------------------------------------------------------------
__global__ __launch_bounds__(256) void head_logsoftmax(
    const u16* __restrict__ o, const float* __restrict__ W4,
    const float* __restrict__ b4, float* __restrict__ out)
{
    __shared__ float W4s[DIN * DOUT];
    __shared__ float b4s[DOUT];
    const int tid = threadIdx.x;
    for (int i = tid; i < DIN * DOUT; i += 256) W4s[i] = W4[i];
    if (tid < DOUT) b4s[tid] = b4[tid];
    __syncthreads();
    const int lane = tid & 63, w = tid >> 6;
    for (int rr = 0; rr < 4; ++rr) {
        const size_t row = (size_t)blockIdx.x * 16 + w * 4 + rr;
        const uint4 ov = *(const uint4*)&o[row * DIN + lane * 8];
        const u32* ou = (const u32*)&ov;
        float oc[8];
#pragma unroll
        for (int i = 0; i < 4; ++i) {
            oc[2*i]   = b2f((u16)(ou[i] & 0xFFFFu));
            oc[2*i+1] = b2f((u16)(ou[i] >> 16));
        }
        float acc[DOUT];
#pragma unroll
        for (int c = 0; c < DOUT; ++c) acc[c] = 0.f;
#pragma unroll
        for (int i = 0; i < 8; ++i) {
            int k = lane * 8 + i;
            float x = oc[i];
#pragma unroll
            for (int c = 0; c < DOUT; ++c) acc[c] += x * W4s[k * DOUT + c];
        }
#pragma unroll
        for (int off = 32; off >= 1; off >>= 1)
#pragma unroll
            for (int c = 0; c < DOUT; ++c) acc[c] += __shfl_xor(acc[c], off, 64);
        float mx = -1e30f;
#pragma unroll
        for (int c = 0; c < DOUT; ++c) { acc[c] += b4s[c]; mx = fmaxf(mx, acc[c]); }
        float sum = 0.f;
#pragma unroll
        for (int c = 0; c < DOUT; ++c) sum += __expf(acc[c] - mx);
        float lse = mx + logf(sum);
        if (lane == 0) {
#pragma unroll
            for (int c = 0; c < DOUT; ++c) out[row * DOUT + c] = acc[c] - lse;
        }
    }
}

// ---------------------------------------------------------------------------
extern "C" void kernel_launch(void* const* d_in, const int* in_sizes, int n_in,
                              void* d_out, int out_size, void* d_ws, size_t ws_size,
                              hipStream_t stream) {
    const float* x  = (const float*)d_in[0];
    const float* gv = (const float*)d_in[1];
    const float* uv = (const float*)d_in[2];
    const float* W1 = (const float*)d_in[3];
    const float* b1 = (const float*)d_in[4];
    const float* W2 = (const float*)d_in[5];
    const float* b2 = (const float*)d_in[6];
    const float* W3 = (const float*)d_in[7];
    const float* b3 = (const float*)d_in[8];
    const float* W4 = (const float*)d_in[9];
    const float* b4 = (const float*)d_in[10];
    float* out = (float*)d_out;

    char* ws = (char*)d_ws;
    const size_t MB64 = (size_t)67108864;
    const size_t MiB  = (size_t)1048576;
    const size_t TIER_A3 = 2 * MB64 + 80 * MiB + 4 * MiB;   // 212 MiB single-pass
    const size_t TIER_A2 = 2 * MB64 + 72 * MiB + 8 * MiB;   // 208 MiB gate
    const size_t TIER_B  = 3 * MB64 + 5 * MiB;              // 197 MiB

    if (ws_size >= TIER_A3) {
        // Single-pass, alias-packed layout (R5-verified):
        //  [0,64) h1 -> hT ; [64,128) h -> ctx ; [128,208) xb -> P -> o
        u16* h1  = (u16*)(ws);
        u16* hT  = h1;
        u16* h   = (u16*)(ws + MB64);
        u16* ctx = h;
        u16* xb  = (u16*)(ws + 2 * MB64);
        u16* P   = xb;
        u16* o   = xb;
        u16* W1t = (u16*)(ws + 2 * MB64 + 80 * MiB);
        u16* W2t = W1t + 512 * 1024;
        u16* W3t = W2t + 1024 * 1024;

        prep_all<<<10240, 256, 0, stream>>>(x, xb, W1, W2, W3, W1t, W2t, W3t);
        gemm8<<<dim3(128, 4), 512, 0, stream>>>(xb, W1t, b1, h1, 1024, 512, 1);
        gemm8<<<dim3(128, 4), 512, 0, stream>>>(h1, W2t, b2, h,  1024, 1024, 1);

        // merged score + hT transpose: 576 score blocks + 2048 transpose
        // blocks that backfill score's partial 3rd round.
        score8<<<(36 + 128) * 16, 512, 0, stream>>>(h, P, hT, 16);
        softmax_rows<<<8192, 256, 0, stream>>>(P);
        pv8<<<32 * 16, 512, 0, stream>>>(P, hT, ctx, 16); // 512 blocks, LPT

        gemm8<<<dim3(128, 2), 512, 0, stream>>>(ctx, W3t, b3, o, 512, 1024, 1);
        head_logsoftmax<<<2048, 256, 0, stream>>>(o, W4, b4, out);
    } else if (ws_size >= TIER_A2) {
        u16* h1   = (u16*)(ws);
        u16* ctx  = h1;
        u16* h    = (u16*)(ws + MB64);
        u16* o    = h;
        u16* xb   = (u16*)(ws + 2 * MB64);
        u16* hT_c = xb;
        u16* P_c  = (u16*)(ws + 2 * MB64 + 32 * MiB);
        u16* W1t  = (u16*)(ws + 2 * MB64 + 72 * MiB);
        u16* W2t  = W1t + 512 * 1024;
        u16* W3t  = W2t + 1024 * 1024;

        prep_all<<<10240, 256, 0, stream>>>(x, xb, W1, W2, W3, W1t, W2t, W3t);
        gemm8<<<dim3(128, 4), 512, 0, stream>>>(xb, W1t, b1, h1, 1024, 512, 1);
        gemm8<<<dim3(128, 4), 512, 0, stream>>>(h1, W2t, b2, h,  1024, 1024, 1);

        for (int c = 0; c < 2; ++c) {
            const u16* hc  = h   + (size_t)c * 8 * S_ * DH;
            u16*       cxc = ctx + (size_t)c * 8 * S_ * DH;
            score8<<<(36 + 128) * 8, 512, 0, stream>>>(hc, P_c, hT_c, 8);
            softmax_rows<<<4096, 256, 0, stream>>>(P_c);
            pv_a<<<16 * 8 * 8, 256, 0, stream>>>(P_c, hT_c, cxc, 8);
        }

        gemm8<<<dim3(128, 2), 512, 0, stream>>>(ctx, W3t, b3, o, 512, 1024, 1);
        head_logsoftmax<<<2048, 256, 0, stream>>>(o, W4, b4, out);
    } else if (ws_size >= TIER_B) {
        u16* h1   = (u16*)(ws);
        u16* ctx  = h1;
        u16* h    = (u16*)(ws + MB64);
        u16* xb   = (u16*)(ws + 2 * MB64);
        u16* hT_c = xb;
        u16* P_c  = (u16*)(ws + 2 * MB64 + 16 * MiB);
        u16* o    = (u16*)(ws + 2 * MB64);
        u16* W1t  = (u16*)(ws + 3 * MB64);
        u16* W2t  = W1t + 512 * 1024;
        u16* W3t  = W2t + 1024 * 1024;

        prep_all<<<10240, 256, 0, stream>>>(x, xb, W1, W2, W3, W1t, W2t, W3t);
        gemm8<<<dim3(128, 4), 512, 0, stream>>>(xb, W1t, b1, h1, 1024, 512, 1);
        gemm8<<<dim3(128, 4), 512, 0, stream>>>(h1, W2t, b2, h,  1024, 1024, 1);

        for (int c = 0; c < 4; ++c) {
            const u16* hc  = h   + (size_t)c * 4 * S_ * DH;
            u16*       cxc = ctx + (size_t)c * 4 * S_ * DH;
            score8<<<(36 + 128) * 4, 512, 0, stream>>>(hc, P_c, hT_c, 4);
            softmax_rows<<<2048, 256, 0, stream>>>(P_c);
            pv_a<<<16 * 8 * 4, 256, 0, stream>>>(P_c, hT_c, cxc, 4);
        }

        gemm8<<<dim3(128, 2), 512, 0, stream>>>(ctx, W3t, b3, o, 512, 1024, 1);
        head_logsoftmax<<<2048, 256, 0, stream>>>(o, W4, b4, out);
    } else {
        u16* h    = (u16*)(ws);
        u16* hT_b = (u16*)(ws + MB64);
        u16* P_b  = (u16*)(ws + MB64 + 4 * MiB);
        u16* ctx_b= (u16*)(ws + MB64 + 12 * MiB);
        u16* o_b  = (u16*)(ws + MB64 + 16 * MiB);
        u16* W1t  = (u16*)(ws + MB64 + 18 * MiB);
        u16* W2t  = W1t + 512 * 1024;
        u16* W3t  = W2t + 1024 * 1024;
        u16* h1_b = P_b;

        wprep<<<2048, dim3(32, 8), 0, stream>>>(W1, W2, W3, W1t, W2t, W3t);

        for (int c = 0; c < 8; ++c) {
            const float* xc = x + (size_t)c * 4096 * DIN;
            u16*         hc = h + (size_t)c * 4096 * DH;
            gemm_bt_bias_relu<true ><<<dim3(32, 8), 256, 0, stream>>>(xc, W1t, b1, h1_b,
                                                                      4096, 1024, 512, 1);
            gemm_bt_bias_relu<false><<<dim3(32, 8), 256, 0, stream>>>(h1_b, W2t, b2, hc,
                                                                      4096, 1024, 1024, 1);
        }
        for (int b = 0; b < B_; ++b) {
            const u16* hb = h + (size_t)b * S_ * DH;
            transpose_v<<<dim3(16, 64, 1), 256, 0, stream>>>(hb, hT_b, 2048, 1024);
            score_a<<<dim3(16, 16, 1), 256, 0, stream>>>(hb, P_b);
            softmax_rows<<<512, 256, 0, stream>>>(P_b);
            pv_a<<<16 * 8, 256, 0, stream>>>(P_b, hT_b, ctx_b, 1);
            gemm_bt_bias_relu<false><<<dim3(16, 4), 256, 0, stream>>>(ctx_b, W3t, b3, o_b,
                                                                      2048, 512, 1024, 1);
            head_logsoftmax<<<128, 256, 0, stream>>>(o_b, W4, b4,
                                                     out + (size_t)b * S_ * DOUT);
        }
    }

    // pass-throughs (f32)
    size_t n_gv = (size_t)in_sizes[1], n_uv = (size_t)in_sizes[2];
    size_t o0 = (size_t)out_size - n_gv - n_uv;
    hipMemcpyAsync(out + o0,        gv, n_gv * 4, hipMemcpyDeviceToDevice, stream);
    hipMemcpyAsync(out + o0 + n_gv, uv, n_uv * 4, hipMemcpyDeviceToDevice, stream);
}